// Round 13
// baseline (407.127 us; speedup 1.0000x reference)
//
#include <hip/hip_runtime.h>
#include <hip/hip_bf16.h>
#include <math.h>

using short8 = __attribute__((ext_vector_type(8))) short;
using f32x16 = __attribute__((ext_vector_type(16))) float;
using f32x2  = __attribute__((ext_vector_type(2))) float;

#define AS3 __attribute__((address_space(3)))
#define AS1 __attribute__((address_space(1)))

constexpr int B  = 1024;
constexpr int NN = 128;   // nodes per tree
constexpr int F  = 318;   // raw features

__device__ inline float bf2f(unsigned short u) {
    union { unsigned int i; float f; } x; x.i = ((unsigned int)u) << 16; return x.f;
}
__device__ inline unsigned short f2bf(float f) {
    union { float f; unsigned int i; } x; x.f = f;
    unsigned int r = x.i + 0x7fff + ((x.i >> 16) & 1);
    return (unsigned short)(r >> 16);
}

// ---------- encoder prepack: 32x32x16 B-frag order ----------
__global__ __launch_bounds__(256) void prepack_w32(const float* __restrict__ w,
                                                   unsigned short* __restrict__ wp,
                                                   int kmul, int OREAL, int CREAL,
                                                   int CC, int COUT, int KS, int NCC, int KTOT)
{
    int t = blockIdx.x * 256 + threadIdx.x;
    if (t >= KTOT * COUT) return;
    int j = t & 7;
    int lane = (t >> 3) & 63;
    int rest = t >> 9;
    int obn = COUT / 32;
    int ob = rest % obn;
    int kbg = rest / obn;
    int ks = kbg % KS;
    int t2 = kbg / KS;
    int cc = t2 % NCC;
    int k  = t2 / NCC;
    int c = cc * CC + ks * 16 + (lane >> 5) * 8 + j;
    int o = ob * 32 + (lane & 31);
    float v = 0.f;
    if (c < CREAL && o < OREAL)
        v = (kmul == 3) ? w[((size_t)o * CREAL + c) * 3 + k] : w[(size_t)o * CREAL + c];
    wp[t] = f2bf(v);
}

// ---------- conv prepack: chunk-contiguous [oy][ci][k][ks][obp][lane][j], CC=64, KS=4 ----------
__global__ __launch_bounds__(256) void prepack_wB(const float* __restrict__ w,
                                                  unsigned short* __restrict__ wp,
                                                  int OREAL, int CREAL, int CIN, int COUT)
{
    const int NCC = CIN / 64;
    int t = blockIdx.x * 256 + threadIdx.x;
    if (t >= 3 * CIN * COUT) return;
    int j = t & 7;
    int lane = (t >> 3) & 63;
    int r = t >> 9;
    int obp = r & 1; r >>= 1;
    int ks = r & 3; r >>= 2;
    int k = r % 3; r /= 3;
    int ci = r % NCC;
    int oy = r / NCC;
    int c = ci * 64 + ks * 16 + (lane >> 5) * 8 + j;
    int o = oy * 64 + obp * 32 + (lane & 31);
    float v = 0.f;
    if (c < CREAL && o < OREAL) v = w[((size_t)o * CREAL + c) * 3 + k];
    wp[t] = f2bf(v);
}

// ---------- encoder, fused transpose: trees [B][F][NN] f32 -> x0 [B][NN][128] bf16 ----------
__global__ __launch_bounds__(256, 2) void enc_fused(const float* __restrict__ trees,
                                                    const unsigned short* __restrict__ wp,
                                                    const float* __restrict__ bias,
                                                    unsigned short* __restrict__ x0)
{
    constexpr int CC = 64, NCH = 5, KS = 4, NB = 4, OT = 128;
    constexpr int BUFB = NN * CC * 2;       // 16 KB
    __shared__ __align__(16) char gbuf[2 * BUFB];

    const int b = blockIdx.x;
    const int tid = threadIdx.x;
    const int lane = tid & 63;
    const int wm = tid >> 6;
    const int l31 = lane & 31, lh2 = lane >> 5;

    const int cl = tid >> 2;
    const int nq = tid & 3;

    float4 vv[8];
    auto load = [&](int ch) {
        const int c = ch * CC + cl;
        const bool ok = (c < F);
        const float* src = trees + ((size_t)b * F + c) * NN + nq * 32;
#pragma unroll
        for (int j = 0; j < 8; ++j)
            vv[j] = ok ? *reinterpret_cast<const float4*>(src + j * 4) : make_float4(0.f, 0.f, 0.f, 0.f);
    };
    const int gsw = cl >> 3, cby = (cl & 7) * 2;
    auto stor = [&](char* wb) {
#pragma unroll
        for (int j = 0; j < 8; ++j) {
            const int n0 = nq * 32 + j * 4;
            const float f4[4] = {vv[j].x, vv[j].y, vv[j].z, vv[j].w};
#pragma unroll
            for (int r = 0; r < 4; ++r) {
                const int n = n0 + r;
                *reinterpret_cast<unsigned short*>(
                    wb + n * (CC * 2) + (((gsw ^ (n & 7)) << 4) + cby)) = f2bf(f4[r]);
            }
        }
    };

    f32x16 acc[NB];
#pragma unroll
    for (int ob = 0; ob < NB; ++ob) acc[ob] = (f32x16)0.f;

    const int nrow = wm * 32 + l31;
    const unsigned abyte = (unsigned)(nrow * (CC * 2));
    const unsigned axor = (unsigned)((nrow & 7) << 4);

    load(0); stor(gbuf);
    __syncthreads();

    int p = 0;
#pragma unroll
    for (int ch = 0; ch < NCH; ++ch) {
        if (ch + 1 < NCH) load(ch + 1);
        const char* base = gbuf + p * BUFB;
        __builtin_amdgcn_s_setprio(1);
#pragma unroll
        for (int ks = 0; ks < KS; ++ks) {
            const int kbg = ch * KS + ks;
            short8 a = *reinterpret_cast<const short8*>(
                base + abyte + (((unsigned)((ks * 2 + lh2) << 4)) ^ axor));
            const unsigned short* wb_ = wp + ((size_t)(kbg * 4) * 64 + lane) * 8;
#pragma unroll
            for (int ob = 0; ob < NB; ++ob) {
                short8 bf_ = *reinterpret_cast<const short8*>(wb_ + ob * 512);
                acc[ob] = __builtin_amdgcn_mfma_f32_32x32x16_bf16(a, bf_, acc[ob], 0, 0, 0);
            }
        }
        __builtin_amdgcn_s_setprio(0);
        if (ch + 1 < NCH) stor(gbuf + (p ^ 1) * BUFB);
        __syncthreads();
        p ^= 1;
    }

    unsigned short* xs = reinterpret_cast<unsigned short*>(gbuf);
    float bs[NB];
#pragma unroll
    for (int ob = 0; ob < NB; ++ob) {
        int o = ob * 32 + l31;
        bs[ob] = (o < 109) ? bias[o] : 0.f;
    }
#pragma unroll
    for (int ob = 0; ob < NB; ++ob)
#pragma unroll
        for (int r = 0; r < 16; ++r) {
            float val = acc[ob][r] + bs[ob];
            int row = wm * 32 + (r & 3) + 8 * (r >> 2) + 4 * lh2;
            xs[row * OT + ob * 32 + l31] = f2bf(val);
        }
    __syncthreads();
#pragma unroll
    for (int i = 0; i < 8; ++i) {
        int e = i * 256 + tid;
        int n = e >> 4, g = e & 15;
        *reinterpret_cast<uint4*>(x0 + ((size_t)b * NN + n) * 128 + g * 8)
            = *reinterpret_cast<const uint4*>(xs + n * OT + g * 8);
    }
}

// ---------- tree conv: DENSE GEMM, all-LDS operands, CC=64, counted-vmcnt raw-barrier pipeline ----------
// Z_k = T(x) @ W_k^T dense; y[n][o] = bias[o] + sum_k Z_k[idx[3n+k]][o]
template <int CIN, int OTN, int COUT, bool NORM, bool COLMAX, bool GLLA>
__global__ __launch_bounds__(256, 2) void conv_gemm(const unsigned short* __restrict__ xin, // [B][NN][CIN]
                                                    const int* __restrict__ idx,            // [B][3*NN]
                                                    const unsigned short* __restrict__ wp,  // [oy][ci][k][ks][obp] frags
                                                    const float* __restrict__ bias,
                                                    const float* __restrict__ stats,
                                                    unsigned short* __restrict__ yout,      // [B][NN][COUT]
                                                    float* __restrict__ colmax,             // [B][COUT]
                                                    float* __restrict__ partials)
{
    constexpr int CC    = 64;
    constexpr int NCC   = CIN / CC;
    constexpr int KS    = 4;
    constexpr int AIT   = 4;                  // A granules/thread
    constexpr int ABUF  = NN * CC * 2;        // 16 KB
    constexpr int BFR   = KS * 3 * 2;         // 24 frags
    constexpr int BBUF  = BFR * 1024;         // 24 KB
    constexpr int BIT   = BBUF / 4096;        // 6 B-granules/thread
    constexpr int BUFB  = ABUF + BBUF;        // 40 KB
    constexpr int SMEM  = 2 * BUFB;           // 80 KB (Z, rbuf, cmax alias inside)

    __shared__ __align__(16) char gbuf[SMEM];
    float* rbuf = reinterpret_cast<float*>(gbuf + 81408);          // 32 B
    float (*cmax)[2][16] = reinterpret_cast<float (*)[2][16]>(gbuf + 80640); // 512 B

    // XCD-grouping decode
    const int f  = blockIdx.x;
    const int s  = f >> 3;
    const int b  = (f & 7) + 8 * (s / OTN);
    const int oy = s % OTN;                   // o-tile base = oy*64

    const int tid = threadIdx.x;
    const int lane = tid & 63;
    const int wv = tid >> 6;
    const int wm = wv >> 1, wn = wv & 1;
    const int l31 = lane & 31, lh2 = lane >> 5;

    float inv = 1.f, nmi = 0.f;
    if (NORM) { float mu = stats[0]; inv = stats[1]; nmi = -mu * inv; }

    const unsigned short* xb = xin + (size_t)b * NN * CIN;

    // epilogue gather rows
    const int en = tid >> 1, eh = tid & 1;
    int sk[3];
#pragma unroll
    for (int k = 0; k < 3; ++k) sk[k] = idx[b * 3 * NN + 3 * en + k];

    f32x16 acc[2][3];
#pragma unroll
    for (int nf = 0; nf < 2; ++nf)
#pragma unroll
        for (int k = 0; k < 3; ++k) acc[nf][k] = (f32x16)0.f;

    // ---- staging ----
    auto issueB = [&](int ci, char* dst) {
        const unsigned short* src = wp + ((size_t)(oy * NCC + ci)) * (BFR * 512);
#pragma unroll
        for (int i = 0; i < BIT; ++i)
            __builtin_amdgcn_global_load_lds(
                (const AS1 void*)(src + (i * 256 + tid) * 8),
                (AS3 void*)(dst + (i * 256 + wv * 64) * 16),
                16, 0, 0);
    };
    auto issueA = [&](int cc, char* dst) {    // GLLA path (no transform)
#pragma unroll
        for (int i = 0; i < AIT; ++i) {
            int it = i * 256 + tid;
            int n = it >> 3, g = it & 7;
            const unsigned short* src = xb + cc * CC + n * CIN + ((g ^ (n & 7)) * 8);
            __builtin_amdgcn_global_load_lds(
                (const AS1 void*)src,
                (AS3 void*)(dst + (i * 256 + wv * 64) * 16),
                16, 0, 0);
        }
    };
    unsigned ngoff[AIT], lby[AIT];
#pragma unroll
    for (int i = 0; i < AIT; ++i) {
        int it = i * 256 + tid;
        int n = it >> 3, g = it & 7;
        ngoff[i] = (unsigned)(n * CIN + g * 8);
        lby[i]   = (unsigned)(n * 128 + ((g ^ (n & 7)) << 4));
    }
    auto loadA = [&](int cc, uint4* vv) {
#pragma unroll
        for (int i = 0; i < AIT; ++i)
            vv[i] = *reinterpret_cast<const uint4*>(xb + cc * CC + ngoff[i]);
    };
    const f32x2 iv2 = {inv, inv}, nm2 = {nmi, nmi};
    auto storA = [&](char* wb, const uint4* vv) {
#pragma unroll
        for (int i = 0; i < AIT; ++i) {
            uint4 t = vv[i];
            if (NORM) {
                unsigned int* pw = reinterpret_cast<unsigned int*>(&t);
#pragma unroll
                for (int q = 0; q < 4; ++q) {
                    unsigned int u = pw[q];
                    f32x2 sv, d;
                    sv[0] = __uint_as_float(u << 16);
                    sv[1] = __uint_as_float(u & 0xffff0000u);
                    asm("v_pk_fma_f32 %0, %1, %2, %3" : "=v"(d) : "v"(sv), "v"(iv2), "v"(nm2));
                    float f0 = fmaxf(d[0], 0.f);
                    float f1 = fmaxf(d[1], 0.f);
                    unsigned int r;
                    asm("v_cvt_pk_bf16_f32 %0, %1, %2" : "=v"(r) : "v"(f0), "v"(f1));
                    pw[q] = r;
                }
            }
            *reinterpret_cast<uint4*>(wb + lby[i]) = t;
        }
    };

    // A-read bases (dense rows)
    const int n0 = wm * 64 + l31;
    const int n1 = n0 + 32;
    const unsigned a0b = (unsigned)(n0 * 128), a0x = (unsigned)((n0 & 7) << 4);
    const unsigned a1b = (unsigned)(n1 * 128), a1x = (unsigned)((n1 & 7) << 4);

    uint4 v0[AIT], v1[AIT];

    // ---------------- prologue ----------------
    if (GLLA) {
        issueB(0, gbuf + ABUF);
        issueA(0, gbuf);
        asm volatile("s_waitcnt vmcnt(0)" ::: "memory");
        __builtin_amdgcn_s_barrier();
        __builtin_amdgcn_sched_barrier(0);
    } else {
        issueB(0, gbuf + ABUF);                 // 6 in flight
        loadA(0, v0);                           // +4
        if (NCC > 1) loadA(1, v1);              // +4
        storA(gbuf, v0);                        // compiler waits v0 -> B(0)+A(0) retired (FIFO)
        asm volatile("s_waitcnt lgkmcnt(0)" ::: "memory");
        __builtin_amdgcn_s_barrier();
        __builtin_amdgcn_sched_barrier(0);
        // in flight across barrier: A(1) only (4)
    }

    // ---------------- main loop: counted-vmcnt raw barriers ----------------
#pragma unroll
    for (int cc = 0; cc < NCC; ++cc) {
        const int p = cc & 1;
        if (cc + 1 < NCC) {
            issueB(cc + 1, gbuf + (p ^ 1) * BUFB + ABUF);     // 6
            if (GLLA) issueA(cc + 1, gbuf + (p ^ 1) * BUFB);  // 4
            else if (cc + 2 < NCC) loadA(cc + 2, (cc & 1) ? v1 : v0);  // 4 (2-deep)
        }
        const char* ab = gbuf + p * BUFB;
        const char* bb = ab + ABUF;
        __builtin_amdgcn_s_setprio(1);
#pragma unroll
        for (int ks = 0; ks < KS; ++ks) {
            const unsigned so = (unsigned)((ks * 2 + lh2) << 4);
            short8 a0 = *reinterpret_cast<const short8*>(ab + a0b + (so ^ a0x));
            short8 a1 = *reinterpret_cast<const short8*>(ab + a1b + (so ^ a1x));
#pragma unroll
            for (int k = 0; k < 3; ++k) {
                short8 bf_ = *reinterpret_cast<const short8*>(
                    bb + (((k * KS + ks) * 2 + wn) << 10) + lane * 16);
                acc[0][k] = __builtin_amdgcn_mfma_f32_32x32x16_bf16(a0, bf_, acc[0][k], 0, 0, 0);
                acc[1][k] = __builtin_amdgcn_mfma_f32_32x32x16_bf16(a1, bf_, acc[1][k], 0, 0, 0);
            }
        }
        __builtin_amdgcn_s_setprio(0);
        if (!GLLA && cc + 1 < NCC) storA(gbuf + (p ^ 1) * BUFB, (cc & 1) ? v0 : v1);

        // end-of-iteration sync: require next chunk's B (and A if GLLA) landed,
        // leave the 2-deep A prefetch in flight (non-GLLA).
        if (cc + 1 < NCC) {
            if (GLLA) {
                asm volatile("s_waitcnt vmcnt(0)" ::: "memory");
            } else if (cc + 2 < NCC) {
                asm volatile("s_waitcnt vmcnt(4) lgkmcnt(0)" ::: "memory");
            } else {
                asm volatile("s_waitcnt vmcnt(0) lgkmcnt(0)" ::: "memory");
            }
            __builtin_amdgcn_s_barrier();
            __builtin_amdgcn_sched_barrier(0);
        } else {
            asm volatile("s_waitcnt lgkmcnt(0)" ::: "memory");
            __builtin_amdgcn_s_barrier();
            __builtin_amdgcn_sched_barrier(0);
        }
    }

    // ---------------- epilogue: Z -> LDS (ds_write2, quad-coarse swizzle), gather ----------------
    float* Z = reinterpret_cast<float*>(gbuf);
    float tsum = 0.f, tss = 0.f;
#pragma unroll
    for (int oh = 0; oh < 2; ++oh) {
        if (oh) __syncthreads();
        if (wn == oh) {
#pragma unroll
            for (int k = 0; k < 3; ++k)
#pragma unroll
                for (int nf = 0; nf < 2; ++nf)
#pragma unroll
                    for (int q = 0; q < 4; ++q) {
                        int X = wm * 64 + nf * 32 + 8 * q + 4 * lh2;   // quad base row
                        unsigned zoff = (unsigned)(uintptr_t)(AS3 float*)(
                            Z + ((size_t)(k * NN + X) * 32 + (l31 ^ (X & 28))));
                        asm volatile("ds_write2_b32 %0, %1, %2 offset0:0 offset1:32"
                                     :: "v"(zoff), "v"(acc[nf][k][4 * q + 0]), "v"(acc[nf][k][4 * q + 1]));
                        asm volatile("ds_write2_b32 %0, %1, %2 offset0:64 offset1:96"
                                     :: "v"(zoff), "v"(acc[nf][k][4 * q + 2]), "v"(acc[nf][k][4 * q + 3]));
                    }
        }
        asm volatile("s_waitcnt lgkmcnt(0)" ::: "memory");
        __syncthreads();

        f32x2 val2[8];
        float* vp = reinterpret_cast<float*>(val2);
        {
            const float* bp = bias + oy * 64 + oh * 32 + eh * 16;
#pragma unroll
            for (int j = 0; j < 16; ++j) vp[j] = bp[j];
        }
#pragma unroll
        for (int k = 0; k < 3; ++k) {
            const float* zr = Z + (k * NN + sk[k]) * 32;
            const int sw = (sk[k] >> 2) & 7;
#pragma unroll
            for (int q4 = 0; q4 < 4; ++q4) {
                const int q = eh * 4 + q4;
                float4 z = *reinterpret_cast<const float4*>(zr + ((q ^ sw) << 2));
                f32x2 zlo = {z.x, z.y}, zhi = {z.z, z.w};
                val2[q4 * 2 + 0] += zlo;
                val2[q4 * 2 + 1] += zhi;
            }
        }
#pragma unroll
        for (int j = 0; j < 16; ++j) { tsum += vp[j]; tss += vp[j] * vp[j]; }

        if (COLMAX) {
#pragma unroll
            for (int m = 2; m <= 32; m <<= 1)
#pragma unroll
                for (int j = 0; j < 16; ++j) vp[j] = fmaxf(vp[j], __shfl_xor(vp[j], m));
            if ((lane >> 1) == 0) {
#pragma unroll
                for (int j = 0; j < 16; ++j) cmax[wv][lane & 1][j] = vp[j];
            }
            __syncthreads();
            if (tid < 32) {
                float m = fmaxf(fmaxf(cmax[0][tid >> 4][tid & 15], cmax[1][tid >> 4][tid & 15]),
                                fmaxf(cmax[2][tid >> 4][tid & 15], cmax[3][tid >> 4][tid & 15]));
                colmax[b * COUT + oy * 64 + oh * 32 + tid] = m;
            }
        } else {
            unsigned int pk[8];
#pragma unroll
            for (int j = 0; j < 8; ++j)
                asm("v_cvt_pk_bf16_f32 %0, %1, %2" : "=v"(pk[j]) : "v"(vp[2 * j]), "v"(vp[2 * j + 1]));
            unsigned short* dst = yout + ((size_t)b * NN + en) * COUT + oy * 64 + oh * 32 + eh * 16;
            reinterpret_cast<uint4*>(dst)[0] = make_uint4(pk[0], pk[1], pk[2], pk[3]);
            reinterpret_cast<uint4*>(dst)[1] = make_uint4(pk[4], pk[5], pk[6], pk[7]);
        }
    }

    // block stats reduction
#pragma unroll
    for (int ss = 32; ss; ss >>= 1) { tsum += __shfl_down(tsum, ss); tss += __shfl_down(tss, ss); }
    if (lane == 0) { rbuf[wv * 2] = tsum; rbuf[wv * 2 + 1] = tss; }
    __syncthreads();
    if (tid == 0) {
        float sm = rbuf[0] + rbuf[2] + rbuf[4] + rbuf[6];
        float q = rbuf[1] + rbuf[3] + rbuf[5] + rbuf[7];
        int gid = oy * B + b;
        partials[2 * gid] = sm;
        partials[2 * gid + 1] = q;
    }
}

// ---------- finalize global layernorm stats ----------
__global__ __launch_bounds__(256) void stats_kernel(const float* __restrict__ partials,
                                                    float* __restrict__ stats,
                                                    int npart, double ntot)
{
    __shared__ double sd[256], sd2[256];
    double s = 0.0, s2 = 0.0;
    for (int i = threadIdx.x; i < npart; i += 256) { s += (double)partials[2 * i]; s2 += (double)partials[2 * i + 1]; }
    sd[threadIdx.x] = s; sd2[threadIdx.x] = s2;
    __syncthreads();
    for (int k = 128; k > 0; k >>= 1) {
        if (threadIdx.x < k) { sd[threadIdx.x] += sd[threadIdx.x + k]; sd2[threadIdx.x] += sd2[threadIdx.x + k]; }
        __syncthreads();
    }
    if (threadIdx.x == 0) {
        double mu = sd[0] / ntot;
        double var = (sd2[0] - sd[0] * sd[0] / ntot) / (ntot - 1.0);
        double sdv = sqrt(var > 0.0 ? var : 0.0);
        stats[0] = (float)mu;
        stats[1] = (float)(1.0 / (sdv + 1e-5));
    }
}

// ---------- heads from per-column max (raw) ----------
__global__ __launch_bounds__(128) void pool_head_kernel(const float* __restrict__ colmax,  // [B][128]
                                                        const float* __restrict__ stats,
                                                        const float* __restrict__ latw,
                                                        const float* __restrict__ latb,
                                                        const float* __restrict__ costw,
                                                        const float* __restrict__ costb,
                                                        float* __restrict__ out)
{
    const int b = blockIdx.x, t = threadIdx.x;
    const float mu = stats[0], inv = stats[1];
    const float pooled = fmaxf((colmax[b * 128 + t] - mu) * inv, 0.f);
    __shared__ float pl[128];
    pl[t] = pooled;
    __syncthreads();
    const float* w = (t < 64) ? latw : costw;
    const int l = t & 63;
    float v = pl[l] * w[l] + pl[l + 64] * w[l + 64];
#pragma unroll
    for (int s = 32; s > 0; s >>= 1) v += __shfl_down(v, s);
    if (l == 0) {
        const float bb = (t < 64) ? latb[0] : costb[0];
        out[(t < 64 ? 0 : B) + b] = 1.f / (1.f + expf(-(v + bb)));
    }
}

// ---------- launch ----------
extern "C" void kernel_launch(void* const* d_in, const int* in_sizes, int n_in,
                              void* d_out, int out_size, void* d_ws, size_t ws_size,
                              hipStream_t stream)
{
    (void)in_sizes; (void)n_in; (void)out_size; (void)ws_size;
    const float* trees   = (const float*)d_in[0];
    const int*   indexes = (const int*)  d_in[1];
    const float* enc_w   = (const float*)d_in[2];
    const float* enc_b   = (const float*)d_in[3];
    const float* w1 = (const float*)d_in[4];
    const float* b1 = (const float*)d_in[5];
    const float* w2 = (const float*)d_in[6];
    const float* b2 = (const float*)d_in[7];
    const float* w3 = (const float*)d_in[8];
    const float* b3 = (const float*)d_in[9];
    const float* lat_w  = (const float*)d_in[10];
    const float* lat_b  = (const float*)d_in[11];
    const float* cost_w = (const float*)d_in[12];
    const float* cost_b = (const float*)d_in[13];
    float* out = (float*)d_out;

    char* ws = (char*)d_ws;
    size_t off = 0;
    auto alloc = [&](size_t bytes) -> char* {
        char* p = ws + off;
        off += (bytes + 255) & ~(size_t)255;
        return p;
    };
    unsigned short* wpe = (unsigned short*)alloc((size_t)320 * 128 * 2);
    unsigned short* wp1 = (unsigned short*)alloc((size_t)3 * 128 * 512 * 2);
    unsigned short* wp2 = (unsigned short*)alloc((size_t)3 * 512 * 256 * 2);
    unsigned short* wp3 = (unsigned short*)alloc((size_t)3 * 256 * 128 * 2);
    unsigned short* x0  = (unsigned short*)alloc((size_t)B * NN * 128 * 2);
    unsigned short* y1  = (unsigned short*)alloc((size_t)B * NN * 512 * 2);
    unsigned short* y2  = (unsigned short*)alloc((size_t)B * NN * 256 * 2);
    float* colmax   = (float*)alloc((size_t)B * 128 * 4);
    float* partials = (float*)alloc((size_t)8192 * 2 * 4);
    float* stats    = (float*)alloc(8 * 4);

    prepack_w32<<<dim3((320 * 128 + 255) / 256), dim3(256), 0, stream>>>(enc_w, wpe, 1, 109, 318, 64, 128, 4, 5, 320);
    prepack_wB<<<dim3((3 * 128 * 512) / 256), dim3(256), 0, stream>>>(w1, wp1, 512, 109, 128, 512);
    prepack_wB<<<dim3((3 * 512 * 256) / 256), dim3(256), 0, stream>>>(w2, wp2, 256, 512, 512, 256);
    prepack_wB<<<dim3((3 * 256 * 128) / 256), dim3(256), 0, stream>>>(w3, wp3, 128, 256, 256, 128);

    // encoder (fused transpose): trees -> x0 [B][NN][128]
    enc_fused<<<dim3(B), dim3(256), 0, stream>>>(trees, wpe, enc_b, x0);

    // conv1: all-LDS operands, full GLL staging (NCC=2)
    conv_gemm<128, 8, 512, false, false, true>
        <<<dim3(B * 8), dim3(256), 0, stream>>>(x0, indexes, wp1, b1, stats, y1, colmax, partials);
    stats_kernel<<<dim3(1), dim3(256), 0, stream>>>(partials, stats + 0, 8192, (double)((size_t)B * 512 * NN));

    // conv2: B via GLL, A via VGPR+norm transform, 2-deep A prefetch (NCC=8)
    conv_gemm<512, 4, 256, true, false, false>
        <<<dim3(B * 4), dim3(256), 0, stream>>>(y1, indexes, wp2, b2, stats + 0, y2, colmax, partials);
    stats_kernel<<<dim3(1), dim3(256), 0, stream>>>(partials, stats + 2, 4096, (double)((size_t)B * 256 * NN));

    // conv3: per-column raw max (pool fused, NCC=4)
    conv_gemm<256, 2, 128, true, true, false>
        <<<dim3(B * 2), dim3(256), 0, stream>>>(y2, indexes, wp3, b3, stats + 2, nullptr, colmax, partials);
    stats_kernel<<<dim3(1), dim3(256), 0, stream>>>(partials, stats + 4, 2048, (double)((size_t)B * 128 * NN));

    pool_head_kernel<<<dim3(B), dim3(128), 0, stream>>>(colmax, stats + 4, lat_w, lat_b, cost_w, cost_b, out);
}

// Round 14
// 363.497 us; speedup vs baseline: 1.1200x; 1.1200x over previous
//
#include <hip/hip_runtime.h>
#include <hip/hip_bf16.h>
#include <math.h>

using short8 = __attribute__((ext_vector_type(8))) short;
using f32x16 = __attribute__((ext_vector_type(16))) float;
using f32x2  = __attribute__((ext_vector_type(2))) float;

#define AS3 __attribute__((address_space(3)))
#define AS1 __attribute__((address_space(1)))

constexpr int B  = 1024;
constexpr int NN = 128;   // nodes per tree
constexpr int F  = 318;   // raw features

__device__ inline float bf2f(unsigned short u) {
    union { unsigned int i; float f; } x; x.i = ((unsigned int)u) << 16; return x.f;
}
__device__ inline unsigned short f2bf(float f) {
    union { float f; unsigned int i; } x; x.f = f;
    unsigned int r = x.i + 0x7fff + ((x.i >> 16) & 1);
    return (unsigned short)(r >> 16);
}

// ---------- encoder prepack: 32x32x16 B-frag order ----------
__global__ __launch_bounds__(256) void prepack_w32(const float* __restrict__ w,
                                                   unsigned short* __restrict__ wp,
                                                   int kmul, int OREAL, int CREAL,
                                                   int CC, int COUT, int KS, int NCC, int KTOT)
{
    int t = blockIdx.x * 256 + threadIdx.x;
    if (t >= KTOT * COUT) return;
    int j = t & 7;
    int lane = (t >> 3) & 63;
    int rest = t >> 9;
    int obn = COUT / 32;
    int ob = rest % obn;
    int kbg = rest / obn;
    int ks = kbg % KS;
    int t2 = kbg / KS;
    int cc = t2 % NCC;
    int k  = t2 / NCC;
    int c = cc * CC + ks * 16 + (lane >> 5) * 8 + j;
    int o = ob * 32 + (lane & 31);
    float v = 0.f;
    if (c < CREAL && o < OREAL)
        v = (kmul == 3) ? w[((size_t)o * CREAL + c) * 3 + k] : w[(size_t)o * CREAL + c];
    wp[t] = f2bf(v);
}

// ---------- conv1-fused prepack: [oy8][f48][lane][j8], f=(k*8+ks)*2+obp ----------
__global__ __launch_bounds__(256) void prepack_w1f(const float* __restrict__ w,
                                                   unsigned short* __restrict__ wp)
{
    int t = blockIdx.x * 256 + threadIdx.x;
    if (t >= 196608) return;
    int j = t & 7;
    int lane = (t >> 3) & 63;
    int r = t >> 9;            // 0..383
    int f = r % 48;
    int oy = r / 48;
    int obp = f & 1;
    int t2 = f >> 1;
    int ks = t2 & 7;
    int k  = t2 >> 3;
    int c = ks * 16 + (lane >> 5) * 8 + j;
    int o = oy * 64 + obp * 32 + (lane & 31);
    float v = (c < 109) ? w[((size_t)o * 109 + c) * 3 + k] : 0.f;
    wp[t] = f2bf(v);
}

// ---------- conv2/3 prepack: chunk-contiguous [oy][ci][k][ks][obp][lane][j], CC=64, KS=4 ----------
__global__ __launch_bounds__(256) void prepack_wB(const float* __restrict__ w,
                                                  unsigned short* __restrict__ wp,
                                                  int OREAL, int CREAL, int CIN, int COUT)
{
    const int NCC = CIN / 64;
    int t = blockIdx.x * 256 + threadIdx.x;
    if (t >= 3 * CIN * COUT) return;
    int j = t & 7;
    int lane = (t >> 3) & 63;
    int r = t >> 9;
    int obp = r & 1; r >>= 1;
    int ks = r & 3; r >>= 2;
    int k = r % 3; r /= 3;
    int ci = r % NCC;
    int oy = r / NCC;
    int c = ci * 64 + ks * 16 + (lane >> 5) * 8 + j;
    int o = oy * 64 + obp * 32 + (lane & 31);
    float v = 0.f;
    if (c < CREAL && o < OREAL) v = w[((size_t)o * CREAL + c) * 3 + k];
    wp[t] = f2bf(v);
}

// ---------- FUSED encoder + conv1 : one block per batch b ----------
// Phase 1: x0[b] = enc(trees[b]) -> LDS tile X (32KB, 16-granule XOR swizzle), never global.
// Phase 2: for each of 8 o-tiles (64 outs): B via GLL (48KB), dense Z = X @ W_k^T,
//          3 k-phases of Z_k (32KB f32) -> all-wave write + gather-add -> y1.
__global__ __launch_bounds__(256, 2) void enc_conv1(const float* __restrict__ trees,
                                                    const int* __restrict__ idx,
                                                    const unsigned short* __restrict__ wpe,
                                                    const float* __restrict__ encb,
                                                    const unsigned short* __restrict__ wp1,
                                                    const float* __restrict__ b1,
                                                    unsigned short* __restrict__ y1,   // [B][NN][512]
                                                    float* __restrict__ partials)
{
    __shared__ __align__(16) char gbuf[81920];
    char* Xt = gbuf;               // 32KB x0 tile (persistent in phase 2)
    char* W  = gbuf + 32768;       // 48KB: enc staging dbuf / conv1 B / Z_k

    const int b = blockIdx.x;
    const int tid = threadIdx.x;
    const int lane = tid & 63;
    const int wv = tid >> 6;
    const int l31 = lane & 31, lh2 = lane >> 5;

    // ---------------- phase 1: encoder ----------------
    {
        constexpr int CC = 64, NCH = 5, KS = 4, NB = 4;
        constexpr int BUFB = NN * CC * 2;   // 16 KB
        const int cl = tid >> 2;
        const int nq = tid & 3;

        float4 vv[8];
        auto load = [&](int ch) {
            const int c = ch * CC + cl;
            const bool ok = (c < F);
            const float* src = trees + ((size_t)b * F + c) * NN + nq * 32;
#pragma unroll
            for (int j = 0; j < 8; ++j)
                vv[j] = ok ? *reinterpret_cast<const float4*>(src + j * 4) : make_float4(0.f, 0.f, 0.f, 0.f);
        };
        const int gsw = cl >> 3, cby = (cl & 7) * 2;
        auto stor = [&](char* wb) {
#pragma unroll
            for (int j = 0; j < 8; ++j) {
                const int n0 = nq * 32 + j * 4;
                const float f4[4] = {vv[j].x, vv[j].y, vv[j].z, vv[j].w};
#pragma unroll
                for (int r = 0; r < 4; ++r) {
                    const int n = n0 + r;
                    *reinterpret_cast<unsigned short*>(
                        wb + n * (CC * 2) + (((gsw ^ (n & 7)) << 4) + cby)) = f2bf(f4[r]);
                }
            }
        };

        f32x16 acc[NB];
#pragma unroll
        for (int ob = 0; ob < NB; ++ob) acc[ob] = (f32x16)0.f;

        const int nrow = wv * 32 + l31;
        const unsigned abyte = (unsigned)(nrow * (CC * 2));
        const unsigned axor = (unsigned)((nrow & 7) << 4);

        load(0); stor(W);
        __syncthreads();

        int p = 0;
#pragma unroll
        for (int ch = 0; ch < NCH; ++ch) {
            if (ch + 1 < NCH) load(ch + 1);
            const char* base = W + p * BUFB;
            __builtin_amdgcn_s_setprio(1);
#pragma unroll
            for (int ks = 0; ks < KS; ++ks) {
                const int kbg = ch * KS + ks;
                short8 a = *reinterpret_cast<const short8*>(
                    base + abyte + (((unsigned)((ks * 2 + lh2) << 4)) ^ axor));
                const unsigned short* wb_ = wpe + ((size_t)(kbg * 4) * 64 + lane) * 8;
#pragma unroll
                for (int ob = 0; ob < NB; ++ob) {
                    short8 bf_ = *reinterpret_cast<const short8*>(wb_ + ob * 512);
                    acc[ob] = __builtin_amdgcn_mfma_f32_32x32x16_bf16(a, bf_, acc[ob], 0, 0, 0);
                }
            }
            __builtin_amdgcn_s_setprio(0);
            if (ch + 1 < NCH) stor(W + (p ^ 1) * BUFB);
            __syncthreads();
            p ^= 1;
        }

        // epilogue -> X tile, 16-granule XOR swizzle (write side of phase-2 reads)
#pragma unroll
        for (int ob = 0; ob < NB; ++ob) {
            const int c = ob * 32 + l31;
            const float bs = (c < 109) ? encb[c] : 0.f;
#pragma unroll
            for (int r = 0; r < 16; ++r) {
                float val = acc[ob][r] + bs;
                int row = wv * 32 + (r & 3) + 8 * (r >> 2) + 4 * lh2;
                int byte = row * 256 + ((((c >> 3) ^ (row & 15)) << 4) | ((c & 7) * 2));
                *reinterpret_cast<unsigned short*>(Xt + byte) = f2bf(val);
            }
        }
        __syncthreads();
    }

    // ---------------- phase 2: conv1 over 8 o-tiles ----------------
    const int en = tid >> 1, eh = tid & 1;
    int sk[3];
#pragma unroll
    for (int k = 0; k < 3; ++k) sk[k] = idx[b * 3 * NN + 3 * en + k];

    const int nA = wv * 32 + l31;                 // A row for this lane
    const unsigned arow = (unsigned)(nA * 256);
    const unsigned axm = (unsigned)(nA & 15);

    float tsum = 0.f, tss = 0.f;
    float* Z = reinterpret_cast<float*>(W);

    for (int oy = 0; oy < 8; ++oy) {
        // stage B(oy): 48KB linear
        const unsigned short* srcB = wp1 + (size_t)oy * 48 * 512;
#pragma unroll
        for (int i = 0; i < 12; ++i)
            __builtin_amdgcn_global_load_lds(
                (const AS1 void*)(srcB + (i * 256 + tid) * 8),
                (AS3 void*)(W + (i * 256 + wv * 64) * 16),
                16, 0, 0);
        asm volatile("s_waitcnt vmcnt(0)" ::: "memory");
        __builtin_amdgcn_s_barrier();
        __builtin_amdgcn_sched_barrier(0);

        f32x16 acc[3][2];
#pragma unroll
        for (int k = 0; k < 3; ++k)
#pragma unroll
            for (int obp = 0; obp < 2; ++obp) acc[k][obp] = (f32x16)0.f;

        __builtin_amdgcn_s_setprio(1);
#pragma unroll
        for (int ks = 0; ks < 8; ++ks) {
            short8 a = *reinterpret_cast<const short8*>(
                Xt + arow + ((((unsigned)(ks * 2 + lh2)) ^ axm) << 4));
#pragma unroll
            for (int k = 0; k < 3; ++k)
#pragma unroll
                for (int obp = 0; obp < 2; ++obp) {
                    short8 bf_ = *reinterpret_cast<const short8*>(
                        W + (((k * 8 + ks) * 2 + obp) << 10) + lane * 16);
                    acc[k][obp] = __builtin_amdgcn_mfma_f32_32x32x16_bf16(a, bf_, acc[k][obp], 0, 0, 0);
                }
        }
        __builtin_amdgcn_s_setprio(0);
        __syncthreads();   // all B reads done; W free for Z

        float val[32];
        {
            const float* bp = b1 + oy * 64 + eh * 32;
#pragma unroll
            for (int j = 0; j < 32; ++j) val[j] = bp[j];
        }

#pragma unroll
        for (int k = 0; k < 3; ++k) {
            // all-wave write Z_k [128 rows][64 cols] f32, word-XOR swizzle (4-bit)
#pragma unroll
            for (int obp = 0; obp < 2; ++obp)
#pragma unroll
                for (int q = 0; q < 4; ++q) {
                    int Xr = wv * 32 + 8 * q + 4 * lh2;          // rows Xr..Xr+3, Xr%4==0
                    int sw4 = (Xr >> 2) & 15;
                    unsigned w0 = (unsigned)(Xr * 64 + ((obp * 32 + l31) ^ (sw4 << 2)));
                    unsigned zaddr = (unsigned)(uintptr_t)(AS3 char*)(W + w0 * 4);
                    asm volatile("ds_write2_b32 %0, %1, %2 offset0:0 offset1:64"
                                 :: "v"(zaddr), "v"(acc[k][obp][4 * q + 0]), "v"(acc[k][obp][4 * q + 1]));
                    asm volatile("ds_write2_b32 %0, %1, %2 offset0:128 offset1:192"
                                 :: "v"(zaddr), "v"(acc[k][obp][4 * q + 2]), "v"(acc[k][obp][4 * q + 3]));
                }
            asm volatile("s_waitcnt lgkmcnt(0)" ::: "memory");
            __syncthreads();

            // gather-add: row sk[k], 32 cols (eh half)
            {
                const int row = sk[k];
                const int sw4 = (row >> 2) & 15;
                const char* zr = reinterpret_cast<const char*>(Z) + row * 256;
#pragma unroll
                for (int g = 0; g < 8; ++g) {
                    int G = eh * 8 + g;
                    float4 z = *reinterpret_cast<const float4*>(zr + ((G ^ sw4) << 4));
                    val[4 * g + 0] += z.x;
                    val[4 * g + 1] += z.y;
                    val[4 * g + 2] += z.z;
                    val[4 * g + 3] += z.w;
                }
            }
            __syncthreads();
        }

        // stats + pack + store
#pragma unroll
        for (int j = 0; j < 32; ++j) { tsum += val[j]; tss += val[j] * val[j]; }
        unsigned int pk[16];
#pragma unroll
        for (int j = 0; j < 16; ++j)
            asm("v_cvt_pk_bf16_f32 %0, %1, %2" : "=v"(pk[j]) : "v"(val[2 * j]), "v"(val[2 * j + 1]));
        unsigned short* dst = y1 + ((size_t)b * NN + en) * 512 + oy * 64 + eh * 32;
        reinterpret_cast<uint4*>(dst)[0] = make_uint4(pk[0], pk[1], pk[2], pk[3]);
        reinterpret_cast<uint4*>(dst)[1] = make_uint4(pk[4], pk[5], pk[6], pk[7]);
        reinterpret_cast<uint4*>(dst)[2] = make_uint4(pk[8], pk[9], pk[10], pk[11]);
        reinterpret_cast<uint4*>(dst)[3] = make_uint4(pk[12], pk[13], pk[14], pk[15]);
    }

    // block stats reduction (W region dead; alias rbuf there)
    float* rbuf = reinterpret_cast<float*>(W);
#pragma unroll
    for (int ss = 32; ss; ss >>= 1) { tsum += __shfl_down(tsum, ss); tss += __shfl_down(tss, ss); }
    if (lane == 0) { rbuf[wv * 2] = tsum; rbuf[wv * 2 + 1] = tss; }
    __syncthreads();
    if (tid == 0) {
        float sm = rbuf[0] + rbuf[2] + rbuf[4] + rbuf[6];
        float q = rbuf[1] + rbuf[3] + rbuf[5] + rbuf[7];
        partials[2 * b] = sm;
        partials[2 * b + 1] = q;
    }
}

// ---------- tree conv (conv2/conv3): DENSE GEMM, all-LDS operands, CC=64 ----------
template <int CIN, int OTN, int COUT, bool NORM, bool COLMAX, bool GLLA>
__global__ __launch_bounds__(256, 2) void conv_gemm(const unsigned short* __restrict__ xin, // [B][NN][CIN]
                                                    const int* __restrict__ idx,            // [B][3*NN]
                                                    const unsigned short* __restrict__ wp,  // [oy][ci][k][ks][obp] frags
                                                    const float* __restrict__ bias,
                                                    const float* __restrict__ stats,
                                                    unsigned short* __restrict__ yout,      // [B][NN][COUT]
                                                    float* __restrict__ colmax,             // [B][COUT]
                                                    float* __restrict__ partials)
{
    constexpr int CC    = 64;
    constexpr int NCC   = CIN / CC;
    constexpr int KS    = 4;
    constexpr int AIT   = 4;                  // A granules/thread
    constexpr int ABUF  = NN * CC * 2;        // 16 KB
    constexpr int BFR   = KS * 3 * 2;         // 24 frags
    constexpr int BBUF  = BFR * 1024;         // 24 KB
    constexpr int BIT   = BBUF / 4096;        // 6 B-granules/thread
    constexpr int BUFB  = ABUF + BBUF;        // 40 KB
    constexpr int SMEM  = 2 * BUFB;           // 80 KB

    __shared__ __align__(16) char gbuf[SMEM];
    float* rbuf = reinterpret_cast<float*>(gbuf + 81408);
    float (*cmax)[2][16] = reinterpret_cast<float (*)[2][16]>(gbuf + 80640);

    const int f  = blockIdx.x;
    const int s  = f >> 3;
    const int b  = (f & 7) + 8 * (s / OTN);
    const int oy = s % OTN;

    const int tid = threadIdx.x;
    const int lane = tid & 63;
    const int wv = tid >> 6;
    const int wm = wv >> 1, wn = wv & 1;
    const int l31 = lane & 31, lh2 = lane >> 5;

    float inv = 1.f, nmi = 0.f;
    if (NORM) { float mu = stats[0]; inv = stats[1]; nmi = -mu * inv; }

    const unsigned short* xb = xin + (size_t)b * NN * CIN;

    const int en = tid >> 1, eh = tid & 1;
    int sk[3];
#pragma unroll
    for (int k = 0; k < 3; ++k) sk[k] = idx[b * 3 * NN + 3 * en + k];

    f32x16 acc[2][3];
#pragma unroll
    for (int nf = 0; nf < 2; ++nf)
#pragma unroll
        for (int k = 0; k < 3; ++k) acc[nf][k] = (f32x16)0.f;

    auto issueB = [&](int ci, char* dst) {
        const unsigned short* src = wp + ((size_t)(oy * NCC + ci)) * (BFR * 512);
#pragma unroll
        for (int i = 0; i < BIT; ++i)
            __builtin_amdgcn_global_load_lds(
                (const AS1 void*)(src + (i * 256 + tid) * 8),
                (AS3 void*)(dst + (i * 256 + wv * 64) * 16),
                16, 0, 0);
    };
    auto issueA = [&](int cc, char* dst) {
#pragma unroll
        for (int i = 0; i < AIT; ++i) {
            int it = i * 256 + tid;
            int n = it >> 3, g = it & 7;
            const unsigned short* src = xb + cc * CC + n * CIN + ((g ^ (n & 7)) * 8);
            __builtin_amdgcn_global_load_lds(
                (const AS1 void*)src,
                (AS3 void*)(dst + (i * 256 + wv * 64) * 16),
                16, 0, 0);
        }
    };
    unsigned ngoff[AIT], lby[AIT];
#pragma unroll
    for (int i = 0; i < AIT; ++i) {
        int it = i * 256 + tid;
        int n = it >> 3, g = it & 7;
        ngoff[i] = (unsigned)(n * CIN + g * 8);
        lby[i]   = (unsigned)(n * 128 + ((g ^ (n & 7)) << 4));
    }
    auto loadA = [&](int cc, uint4* vv) {
#pragma unroll
        for (int i = 0; i < AIT; ++i)
            vv[i] = *reinterpret_cast<const uint4*>(xb + cc * CC + ngoff[i]);
    };
    const f32x2 iv2 = {inv, inv}, nm2 = {nmi, nmi};
    auto storA = [&](char* wb, const uint4* vv) {
#pragma unroll
        for (int i = 0; i < AIT; ++i) {
            uint4 t = vv[i];
            if (NORM) {
                unsigned int* pw = reinterpret_cast<unsigned int*>(&t);
#pragma unroll
                for (int q = 0; q < 4; ++q) {
                    unsigned int u = pw[q];
                    f32x2 sv, d;
                    sv[0] = __uint_as_float(u << 16);
                    sv[1] = __uint_as_float(u & 0xffff0000u);
                    asm("v_pk_fma_f32 %0, %1, %2, %3" : "=v"(d) : "v"(sv), "v"(iv2), "v"(nm2));
                    float f0 = fmaxf(d[0], 0.f);
                    float f1 = fmaxf(d[1], 0.f);
                    unsigned int r;
                    asm("v_cvt_pk_bf16_f32 %0, %1, %2" : "=v"(r) : "v"(f0), "v"(f1));
                    pw[q] = r;
                }
            }
            *reinterpret_cast<uint4*>(wb + lby[i]) = t;
        }
    };

    const int n0 = wm * 64 + l31;
    const int n1 = n0 + 32;
    const unsigned a0b = (unsigned)(n0 * 128), a0x = (unsigned)((n0 & 7) << 4);
    const unsigned a1b = (unsigned)(n1 * 128), a1x = (unsigned)((n1 & 7) << 4);

    uint4 v0[AIT], v1[AIT];

    if (GLLA) {
        issueB(0, gbuf + ABUF);
        issueA(0, gbuf);
        asm volatile("s_waitcnt vmcnt(0)" ::: "memory");
        __builtin_amdgcn_s_barrier();
        __builtin_amdgcn_sched_barrier(0);
    } else {
        issueB(0, gbuf + ABUF);
        loadA(0, v0);
        if (NCC > 1) loadA(1, v1);
        storA(gbuf, v0);
        asm volatile("s_waitcnt lgkmcnt(0)" ::: "memory");
        __builtin_amdgcn_s_barrier();
        __builtin_amdgcn_sched_barrier(0);
    }

#pragma unroll
    for (int cc = 0; cc < NCC; ++cc) {
        const int p = cc & 1;
        if (cc + 1 < NCC) {
            issueB(cc + 1, gbuf + (p ^ 1) * BUFB + ABUF);
            if (GLLA) issueA(cc + 1, gbuf + (p ^ 1) * BUFB);
            else if (cc + 2 < NCC) loadA(cc + 2, (cc & 1) ? v1 : v0);
        }
        const char* ab = gbuf + p * BUFB;
        const char* bb = ab + ABUF;
        __builtin_amdgcn_s_setprio(1);
#pragma unroll
        for (int ks = 0; ks < KS; ++ks) {
            const unsigned so = (unsigned)((ks * 2 + lh2) << 4);
            short8 a0 = *reinterpret_cast<const short8*>(ab + a0b + (so ^ a0x));
            short8 a1 = *reinterpret_cast<const short8*>(ab + a1b + (so ^ a1x));
#pragma unroll
            for (int k = 0; k < 3; ++k) {
                short8 bf_ = *reinterpret_cast<const short8*>(
                    bb + (((k * KS + ks) * 2 + wn) << 10) + lane * 16);
                acc[0][k] = __builtin_amdgcn_mfma_f32_32x32x16_bf16(a0, bf_, acc[0][k], 0, 0, 0);
                acc[1][k] = __builtin_amdgcn_mfma_f32_32x32x16_bf16(a1, bf_, acc[1][k], 0, 0, 0);
            }
        }
        __builtin_amdgcn_s_setprio(0);
        if (!GLLA && cc + 1 < NCC) storA(gbuf + (p ^ 1) * BUFB, (cc & 1) ? v0 : v1);

        if (cc + 1 < NCC) {
            if (GLLA) {
                asm volatile("s_waitcnt vmcnt(0)" ::: "memory");
            } else if (cc + 2 < NCC) {
                asm volatile("s_waitcnt vmcnt(4) lgkmcnt(0)" ::: "memory");
            } else {
                asm volatile("s_waitcnt vmcnt(0) lgkmcnt(0)" ::: "memory");
            }
            __builtin_amdgcn_s_barrier();
            __builtin_amdgcn_sched_barrier(0);
        } else {
            asm volatile("s_waitcnt lgkmcnt(0)" ::: "memory");
            __builtin_amdgcn_s_barrier();
            __builtin_amdgcn_sched_barrier(0);
        }
    }

    // epilogue: Z -> LDS (ds_write2, quad-coarse swizzle), gather
    float* Z = reinterpret_cast<float*>(gbuf);
    float tsum = 0.f, tss = 0.f;
#pragma unroll
    for (int oh = 0; oh < 2; ++oh) {
        if (oh) __syncthreads();
        if (wn == oh) {
#pragma unroll
            for (int k = 0; k < 3; ++k)
#pragma unroll
                for (int nf = 0; nf < 2; ++nf)
#pragma unroll
                    for (int q = 0; q < 4; ++q) {
                        int X = wm * 64 + nf * 32 + 8 * q + 4 * lh2;
                        unsigned zoff = (unsigned)(uintptr_t)(AS3 float*)(
                            Z + ((size_t)(k * NN + X) * 32 + (l31 ^ (X & 28))));
                        asm volatile("ds_write2_b32 %0, %1, %2 offset0:0 offset1:32"
                                     :: "v"(zoff), "v"(acc[nf][k][4 * q + 0]), "v"(acc[nf][k][4 * q + 1]));
                        asm volatile("ds_write2_b32 %0, %1, %2 offset0:64 offset1:96"
                                     :: "v"(zoff), "v"(acc[nf][k][4 * q + 2]), "v"(acc[nf][k][4 * q + 3]));
                    }
        }
        asm volatile("s_waitcnt lgkmcnt(0)" ::: "memory");
        __syncthreads();

        f32x2 val2[8];
        float* vp = reinterpret_cast<float*>(val2);
        {
            const float* bp = bias + oy * 64 + oh * 32 + eh * 16;
#pragma unroll
            for (int j = 0; j < 16; ++j) vp[j] = bp[j];
        }
#pragma unroll
        for (int k = 0; k < 3; ++k) {
            const float* zr = Z + (k * NN + sk[k]) * 32;
            const int sw = (sk[k] >> 2) & 7;
#pragma unroll
            for (int q4 = 0; q4 < 4; ++q4) {
                const int q = eh * 4 + q4;
                float4 z = *reinterpret_cast<const float4*>(zr + ((q ^ sw) << 2));
                f32x2 zlo = {z.x, z.y}, zhi = {z.z, z.w};
                val2[q4 * 2 + 0] += zlo;
                val2[q4 * 2 + 1] += zhi;
            }
        }
#pragma unroll
        for (int j = 0; j < 16; ++j) { tsum += vp[j]; tss += vp[j] * vp[j]; }

        if (COLMAX) {
#pragma unroll
            for (int m = 2; m <= 32; m <<= 1)
#pragma unroll
                for (int j = 0; j < 16; ++j) vp[j] = fmaxf(vp[j], __shfl_xor(vp[j], m));
            if ((lane >> 1) == 0) {
#pragma unroll
                for (int j = 0; j < 16; ++j) cmax[wv][lane & 1][j] = vp[j];
            }
            __syncthreads();
            if (tid < 32) {
                float m = fmaxf(fmaxf(cmax[0][tid >> 4][tid & 15], cmax[1][tid >> 4][tid & 15]),
                                fmaxf(cmax[2][tid >> 4][tid & 15], cmax[3][tid >> 4][tid & 15]));
                colmax[b * COUT + oy * 64 + oh * 32 + tid] = m;
            }
        } else {
            unsigned int pk[8];
#pragma unroll
            for (int j = 0; j < 8; ++j)
                asm("v_cvt_pk_bf16_f32 %0, %1, %2" : "=v"(pk[j]) : "v"(vp[2 * j]), "v"(vp[2 * j + 1]));
            unsigned short* dst = yout + ((size_t)b * NN + en) * COUT + oy * 64 + oh * 32 + eh * 16;
            reinterpret_cast<uint4*>(dst)[0] = make_uint4(pk[0], pk[1], pk[2], pk[3]);
            reinterpret_cast<uint4*>(dst)[1] = make_uint4(pk[4], pk[5], pk[6], pk[7]);
        }
    }

#pragma unroll
    for (int ss = 32; ss; ss >>= 1) { tsum += __shfl_down(tsum, ss); tss += __shfl_down(tss, ss); }
    if (lane == 0) { rbuf[wv * 2] = tsum; rbuf[wv * 2 + 1] = tss; }
    __syncthreads();
    if (tid == 0) {
        float sm = rbuf[0] + rbuf[2] + rbuf[4] + rbuf[6];
        float q = rbuf[1] + rbuf[3] + rbuf[5] + rbuf[7];
        int gid = oy * B + b;
        partials[2 * gid] = sm;
        partials[2 * gid + 1] = q;
    }
}

// ---------- finalize global layernorm stats ----------
__global__ __launch_bounds__(256) void stats_kernel(const float* __restrict__ partials,
                                                    float* __restrict__ stats,
                                                    int npart, double ntot)
{
    __shared__ double sd[256], sd2[256];
    double s = 0.0, s2 = 0.0;
    for (int i = threadIdx.x; i < npart; i += 256) { s += (double)partials[2 * i]; s2 += (double)partials[2 * i + 1]; }
    sd[threadIdx.x] = s; sd2[threadIdx.x] = s2;
    __syncthreads();
    for (int k = 128; k > 0; k >>= 1) {
        if (threadIdx.x < k) { sd[threadIdx.x] += sd[threadIdx.x + k]; sd2[threadIdx.x] += sd2[threadIdx.x + k]; }
        __syncthreads();
    }
    if (threadIdx.x == 0) {
        double mu = sd[0] / ntot;
        double var = (sd2[0] - sd[0] * sd[0] / ntot) / (ntot - 1.0);
        double sdv = sqrt(var > 0.0 ? var : 0.0);
        stats[0] = (float)mu;
        stats[1] = (float)(1.0 / (sdv + 1e-5));
    }
}

// ---------- heads from per-column max (raw) ----------
__global__ __launch_bounds__(128) void pool_head_kernel(const float* __restrict__ colmax,  // [B][128]
                                                        const float* __restrict__ stats,
                                                        const float* __restrict__ latw,
                                                        const float* __restrict__ latb,
                                                        const float* __restrict__ costw,
                                                        const float* __restrict__ costb,
                                                        float* __restrict__ out)
{
    const int b = blockIdx.x, t = threadIdx.x;
    const float mu = stats[0], inv = stats[1];
    const float pooled = fmaxf((colmax[b * 128 + t] - mu) * inv, 0.f);
    __shared__ float pl[128];
    pl[t] = pooled;
    __syncthreads();
    const float* w = (t < 64) ? latw : costw;
    const int l = t & 63;
    float v = pl[l] * w[l] + pl[l + 64] * w[l + 64];
#pragma unroll
    for (int s = 32; s > 0; s >>= 1) v += __shfl_down(v, s);
    if (l == 0) {
        const float bb = (t < 64) ? latb[0] : costb[0];
        out[(t < 64 ? 0 : B) + b] = 1.f / (1.f + expf(-(v + bb)));
    }
}

// ---------- launch ----------
extern "C" void kernel_launch(void* const* d_in, const int* in_sizes, int n_in,
                              void* d_out, int out_size, void* d_ws, size_t ws_size,
                              hipStream_t stream)
{
    (void)in_sizes; (void)n_in; (void)out_size; (void)ws_size;
    const float* trees   = (const float*)d_in[0];
    const int*   indexes = (const int*)  d_in[1];
    const float* enc_w   = (const float*)d_in[2];
    const float* enc_b   = (const float*)d_in[3];
    const float* w1 = (const float*)d_in[4];
    const float* b1 = (const float*)d_in[5];
    const float* w2 = (const float*)d_in[6];
    const float* b2 = (const float*)d_in[7];
    const float* w3 = (const float*)d_in[8];
    const float* b3 = (const float*)d_in[9];
    const float* lat_w  = (const float*)d_in[10];
    const float* lat_b  = (const float*)d_in[11];
    const float* cost_w = (const float*)d_in[12];
    const float* cost_b = (const float*)d_in[13];
    float* out = (float*)d_out;

    char* ws = (char*)d_ws;
    size_t off = 0;
    auto alloc = [&](size_t bytes) -> char* {
        char* p = ws + off;
        off += (bytes + 255) & ~(size_t)255;
        return p;
    };
    unsigned short* wpe  = (unsigned short*)alloc((size_t)320 * 128 * 2);
    unsigned short* wp1f = (unsigned short*)alloc((size_t)196608 * 2);
    unsigned short* wp2  = (unsigned short*)alloc((size_t)3 * 512 * 256 * 2);
    unsigned short* wp3  = (unsigned short*)alloc((size_t)3 * 256 * 128 * 2);
    unsigned short* y1   = (unsigned short*)alloc((size_t)B * NN * 512 * 2);
    unsigned short* y2   = (unsigned short*)alloc((size_t)B * NN * 256 * 2);
    float* colmax   = (float*)alloc((size_t)B * 128 * 4);
    float* partials = (float*)alloc((size_t)8192 * 2 * 4);
    float* stats    = (float*)alloc(8 * 4);

    prepack_w32<<<dim3((320 * 128 + 255) / 256), dim3(256), 0, stream>>>(enc_w, wpe, 1, 109, 318, 64, 128, 4, 5, 320);
    prepack_w1f<<<dim3(196608 / 256), dim3(256), 0, stream>>>(w1, wp1f);
    prepack_wB<<<dim3((3 * 512 * 256) / 256), dim3(256), 0, stream>>>(w2, wp2, 256, 512, 512, 256);
    prepack_wB<<<dim3((3 * 256 * 128) / 256), dim3(256), 0, stream>>>(w3, wp3, 128, 256, 256, 128);

    // FUSED encoder + conv1: trees -> y1 (x0 never leaves LDS)
    enc_conv1<<<dim3(B), dim3(256), 0, stream>>>(trees, indexes, wpe, enc_b, wp1f, b1, y1, partials);
    stats_kernel<<<dim3(1), dim3(256), 0, stream>>>(partials, stats + 0, 1024, (double)((size_t)B * 512 * NN));

    // conv2: B via GLL, A via VGPR+norm transform (NCC=8)
    conv_gemm<512, 4, 256, true, false, false>
        <<<dim3(B * 4), dim3(256), 0, stream>>>(y1, indexes, wp2, b2, stats + 0, y2, colmax, partials);
    stats_kernel<<<dim3(1), dim3(256), 0, stream>>>(partials, stats + 2, 4096, (double)((size_t)B * 256 * NN));

    // conv3: per-column raw max (pool fused, NCC=4)
    conv_gemm<256, 2, 128, true, true, false>
        <<<dim3(B * 2), dim3(256), 0, stream>>>(y2, indexes, wp3, b3, stats + 2, nullptr, colmax, partials);
    stats_kernel<<<dim3(1), dim3(256), 0, stream>>>(partials, stats + 4, 2048, (double)((size_t)B * 128 * NN));

    pool_head_kernel<<<dim3(B), dim3(128), 0, stream>>>(colmax, stats + 4, lat_w, lat_b, cost_w, cost_b, out);
}

// Round 15
// 359.419 us; speedup vs baseline: 1.1327x; 1.0113x over previous
//
#include <hip/hip_runtime.h>
#include <hip/hip_bf16.h>
#include <math.h>

using short8 = __attribute__((ext_vector_type(8))) short;
using f32x16 = __attribute__((ext_vector_type(16))) float;
using f32x2  = __attribute__((ext_vector_type(2))) float;

#define AS3 __attribute__((address_space(3)))
#define AS1 __attribute__((address_space(1)))

constexpr int B  = 1024;
constexpr int NN = 128;   // nodes per tree
constexpr int F  = 318;   // raw features

__device__ inline float bf2f(unsigned short u) {
    union { unsigned int i; float f; } x; x.i = ((unsigned int)u) << 16; return x.f;
}
__device__ inline unsigned short f2bf(float f) {
    union { float f; unsigned int i; } x; x.f = f;
    unsigned int r = x.i + 0x7fff + ((x.i >> 16) & 1);
    return (unsigned short)(r >> 16);
}

// ---------- encoder prepack: 32x32x16 B-frag order ----------
__global__ __launch_bounds__(256) void prepack_w32(const float* __restrict__ w,
                                                   unsigned short* __restrict__ wp,
                                                   int kmul, int OREAL, int CREAL,
                                                   int CC, int COUT, int KS, int NCC, int KTOT)
{
    int t = blockIdx.x * 256 + threadIdx.x;
    if (t >= KTOT * COUT) return;
    int j = t & 7;
    int lane = (t >> 3) & 63;
    int rest = t >> 9;
    int obn = COUT / 32;
    int ob = rest % obn;
    int kbg = rest / obn;
    int ks = kbg % KS;
    int t2 = kbg / KS;
    int cc = t2 % NCC;
    int k  = t2 / NCC;
    int c = cc * CC + ks * 16 + (lane >> 5) * 8 + j;
    int o = ob * 32 + (lane & 31);
    float v = 0.f;
    if (c < CREAL && o < OREAL)
        v = (kmul == 3) ? w[((size_t)o * CREAL + c) * 3 + k] : w[(size_t)o * CREAL + c];
    wp[t] = f2bf(v);
}

// ---------- conv1-fused prepack: [oy8][f48][lane][j8], f=(k*8+ks)*2+obp ----------
__global__ __launch_bounds__(256) void prepack_w1f(const float* __restrict__ w,
                                                   unsigned short* __restrict__ wp)
{
    int t = blockIdx.x * 256 + threadIdx.x;
    if (t >= 196608) return;
    int j = t & 7;
    int lane = (t >> 3) & 63;
    int r = t >> 9;            // 0..383
    int f = r % 48;
    int oy = r / 48;
    int obp = f & 1;
    int t2 = f >> 1;
    int ks = t2 & 7;
    int k  = t2 >> 3;
    int c = ks * 16 + (lane >> 5) * 8 + j;
    int o = oy * 64 + obp * 32 + (lane & 31);
    float v = (c < 109) ? w[((size_t)o * 109 + c) * 3 + k] : 0.f;
    wp[t] = f2bf(v);
}

// ---------- conv2/3 prepack: chunk-contiguous [oy][ci][k][ks][obp][lane][j], CC=64, KS=4 ----------
__global__ __launch_bounds__(256) void prepack_wB(const float* __restrict__ w,
                                                  unsigned short* __restrict__ wp,
                                                  int OREAL, int CREAL, int CIN, int COUT)
{
    const int NCC = CIN / 64;
    int t = blockIdx.x * 256 + threadIdx.x;
    if (t >= 3 * CIN * COUT) return;
    int j = t & 7;
    int lane = (t >> 3) & 63;
    int r = t >> 9;
    int obp = r & 1; r >>= 1;
    int ks = r & 3; r >>= 2;
    int k = r % 3; r /= 3;
    int ci = r % NCC;
    int oy = r / NCC;
    int c = ci * 64 + ks * 16 + (lane >> 5) * 8 + j;
    int o = oy * 64 + obp * 32 + (lane & 31);
    float v = 0.f;
    if (c < CREAL && o < OREAL) v = w[((size_t)o * CREAL + c) * 3 + k];
    wp[t] = f2bf(v);
}

// ---------- FUSED encoder + conv1 : one block per batch b ----------
// Phase 1: x0[b] = enc(trees[b]) -> LDS tile X (32KB, 16-granule XOR swizzle).
// Phase 2: conv1 OUTPUT-STATIONARY: per oy (8 x 64 outs), B via GLL (48KB);
//          MFMA A-frag read = LDS-side gather of Xt rows idx[3n+k]; acc init = bias;
//          y-tile (16KB bf16) bounce for coalesced stores. 4 barriers/oy.
__global__ __launch_bounds__(256, 2) void enc_conv1(const float* __restrict__ trees,
                                                    const int* __restrict__ idx,
                                                    const unsigned short* __restrict__ wpe,
                                                    const float* __restrict__ encb,
                                                    const unsigned short* __restrict__ wp1,
                                                    const float* __restrict__ b1,
                                                    unsigned short* __restrict__ y1,   // [B][NN][512]
                                                    float* __restrict__ partials)
{
    __shared__ __align__(16) char gbuf[81920];
    char* Xt = gbuf;               // 32KB x0 tile (persistent in phase 2)
    char* W  = gbuf + 32768;       // 48KB: enc staging dbuf / conv1 B / y-tile

    const int b = blockIdx.x;
    const int tid = threadIdx.x;
    const int lane = tid & 63;
    const int wv = tid >> 6;
    const int l31 = lane & 31, lh2 = lane >> 5;

    // ---------------- phase 1: encoder ----------------
    {
        constexpr int CC = 64, NCH = 5, KS = 4, NB = 4;
        constexpr int BUFB = NN * CC * 2;   // 16 KB
        const int cl = tid >> 2;
        const int nq = tid & 3;

        float4 vv[8];
        auto load = [&](int ch) {
            const int c = ch * CC + cl;
            const bool ok = (c < F);
            const float* src = trees + ((size_t)b * F + c) * NN + nq * 32;
#pragma unroll
            for (int j = 0; j < 8; ++j)
                vv[j] = ok ? *reinterpret_cast<const float4*>(src + j * 4) : make_float4(0.f, 0.f, 0.f, 0.f);
        };
        const int gsw = cl >> 3, cby = (cl & 7) * 2;
        auto stor = [&](char* wb) {
#pragma unroll
            for (int j = 0; j < 8; ++j) {
                const int n0 = nq * 32 + j * 4;
                const float f4[4] = {vv[j].x, vv[j].y, vv[j].z, vv[j].w};
#pragma unroll
                for (int r = 0; r < 4; ++r) {
                    const int n = n0 + r;
                    *reinterpret_cast<unsigned short*>(
                        wb + n * (CC * 2) + (((gsw ^ (n & 7)) << 4) + cby)) = f2bf(f4[r]);
                }
            }
        };

        f32x16 acc[NB];
#pragma unroll
        for (int ob = 0; ob < NB; ++ob) acc[ob] = (f32x16)0.f;

        const int nrow = wv * 32 + l31;
        const unsigned abyte = (unsigned)(nrow * (CC * 2));
        const unsigned axor = (unsigned)((nrow & 7) << 4);

        load(0); stor(W);
        __syncthreads();

        int p = 0;
#pragma unroll
        for (int ch = 0; ch < NCH; ++ch) {
            if (ch + 1 < NCH) load(ch + 1);
            const char* base = W + p * BUFB;
            __builtin_amdgcn_s_setprio(1);
#pragma unroll
            for (int ks = 0; ks < KS; ++ks) {
                const int kbg = ch * KS + ks;
                short8 a = *reinterpret_cast<const short8*>(
                    base + abyte + (((unsigned)((ks * 2 + lh2) << 4)) ^ axor));
                const unsigned short* wb_ = wpe + ((size_t)(kbg * 4) * 64 + lane) * 8;
#pragma unroll
                for (int ob = 0; ob < NB; ++ob) {
                    short8 bf_ = *reinterpret_cast<const short8*>(wb_ + ob * 512);
                    acc[ob] = __builtin_amdgcn_mfma_f32_32x32x16_bf16(a, bf_, acc[ob], 0, 0, 0);
                }
            }
            __builtin_amdgcn_s_setprio(0);
            if (ch + 1 < NCH) stor(W + (p ^ 1) * BUFB);
            __syncthreads();
            p ^= 1;
        }

        // epilogue -> X tile, 16-granule XOR swizzle (matches phase-2 reads)
#pragma unroll
        for (int ob = 0; ob < NB; ++ob) {
            const int c = ob * 32 + l31;
            const float bs = (c < 109) ? encb[c] : 0.f;
#pragma unroll
            for (int r = 0; r < 16; ++r) {
                float val = acc[ob][r] + bs;
                int row = wv * 32 + (r & 3) + 8 * (r >> 2) + 4 * lh2;
                int byte = row * 256 + ((((c >> 3) ^ (row & 15)) << 4) | ((c & 7) * 2));
                *reinterpret_cast<unsigned short*>(Xt + byte) = f2bf(val);
            }
        }
        __syncthreads();
    }

    // ---------------- phase 2: conv1, output-stationary A-side gather ----------------
    // per-lane A gather rows (depend on l31 only; shared across lh2)
    const int nrowA = wv * 32 + l31;
    unsigned aab[3], axm[3];
#pragma unroll
    for (int k = 0; k < 3; ++k) {
        int s_ = idx[b * 3 * NN + 3 * nrowA + k];
        aab[k] = (unsigned)(s_ * 256);
        axm[k] = (unsigned)(s_ & 15);
    }

    auto issueB = [&](int oy, int i0, int i1) {
        const unsigned short* srcB = wp1 + (size_t)oy * 48 * 512;
        for (int i = i0; i < i1; ++i)
            __builtin_amdgcn_global_load_lds(
                (const AS1 void*)(srcB + (i * 256 + tid) * 8),
                (AS3 void*)(W + (i * 256 + wv * 64) * 16),
                16, 0, 0);
    };

    float tsum = 0.f, tss = 0.f;

    // prologue: stage B(0) fully
    issueB(0, 0, 12);
    asm volatile("s_waitcnt vmcnt(0)" ::: "memory");
    __builtin_amdgcn_s_barrier();
    __builtin_amdgcn_sched_barrier(0);

    for (int oy = 0; oy < 8; ++oy) {
        f32x16 acc[2];
#pragma unroll
        for (int obp = 0; obp < 2; ++obp) {
            const float bv = b1[oy * 64 + obp * 32 + l31];
#pragma unroll
            for (int r = 0; r < 16; ++r) acc[obp][r] = bv;
        }

        __builtin_amdgcn_s_setprio(1);
#pragma unroll
        for (int ks = 0; ks < 8; ++ks) {
#pragma unroll
            for (int k = 0; k < 3; ++k) {
                short8 a = *reinterpret_cast<const short8*>(
                    Xt + aab[k] + ((((unsigned)(ks * 2 + lh2)) ^ axm[k]) << 4));
#pragma unroll
                for (int obp = 0; obp < 2; ++obp) {
                    short8 bf_ = *reinterpret_cast<const short8*>(
                        W + (((k * 8 + ks) * 2 + obp) << 10) + lane * 16);
                    acc[obp] = __builtin_amdgcn_mfma_f32_32x32x16_bf16(a, bf_, acc[obp], 0, 0, 0);
                }
            }
        }
        __builtin_amdgcn_s_setprio(0);
        __syncthreads();                         // B reads done; W[0:16K] free

        // write y-tile [128 rows][64 cols] bf16 at W[0:16K], granule swizzle ^(row&7)
#pragma unroll
        for (int obp = 0; obp < 2; ++obp)
#pragma unroll
            for (int r = 0; r < 16; ++r) {
                float val = acc[obp][r];
                tsum += val; tss += val * val;
                int row = wv * 32 + (r & 3) + 8 * (r >> 2) + 4 * lh2;
                int col = obp * 32 + l31;
                int byte = row * 128 + ((col * 2) ^ ((row & 7) << 4));
                *reinterpret_cast<unsigned short*>(W + byte) = f2bf(val);
            }
        asm volatile("s_waitcnt lgkmcnt(0)" ::: "memory");
        __syncthreads();                         // y-tile visible

        // prefetch B(oy+1) upper 32KB (frags 16..47) into W[16K:48K]
        if (oy + 1 < 8) issueB(oy + 1, 4, 12);

        // read y-tile (conflict-free), store to y1
        {
            const int row = tid >> 1, h = tid & 1;
            unsigned short* dst = y1 + ((size_t)b * NN + row) * 512 + oy * 64;
#pragma unroll
            for (int j = 0; j < 4; ++j) {
                int cg = h * 4 + j;
                uint4 v = *reinterpret_cast<const uint4*>(W + row * 128 + ((cg ^ (row & 7)) << 4));
                *reinterpret_cast<uint4*>(dst + cg * 8) = v;
            }
        }
        __syncthreads();                         // y reads done

        if (oy + 1 < 8) {
            issueB(oy + 1, 0, 4);                // lower 16KB into W[0:16K]
            asm volatile("s_waitcnt vmcnt(0)" ::: "memory");
            __builtin_amdgcn_s_barrier();
            __builtin_amdgcn_sched_barrier(0);
        }
    }

    // block stats reduction (W free; alias rbuf there)
    float* rbuf = reinterpret_cast<float*>(W);
#pragma unroll
    for (int ss = 32; ss; ss >>= 1) { tsum += __shfl_down(tsum, ss); tss += __shfl_down(tss, ss); }
    if (lane == 0) { rbuf[wv * 2] = tsum; rbuf[wv * 2 + 1] = tss; }
    __syncthreads();
    if (tid == 0) {
        float sm = rbuf[0] + rbuf[2] + rbuf[4] + rbuf[6];
        float q = rbuf[1] + rbuf[3] + rbuf[5] + rbuf[7];
        partials[2 * b] = sm;
        partials[2 * b + 1] = q;
    }
}

// ---------- tree conv (conv2/conv3): DENSE GEMM, all-LDS operands, CC=64 ----------
template <int CIN, int OTN, int COUT, bool NORM, bool COLMAX, bool GLLA>
__global__ __launch_bounds__(256, 2) void conv_gemm(const unsigned short* __restrict__ xin, // [B][NN][CIN]
                                                    const int* __restrict__ idx,            // [B][3*NN]
                                                    const unsigned short* __restrict__ wp,  // [oy][ci][k][ks][obp] frags
                                                    const float* __restrict__ bias,
                                                    const float* __restrict__ stats,
                                                    unsigned short* __restrict__ yout,      // [B][NN][COUT]
                                                    float* __restrict__ colmax,             // [B][COUT]
                                                    float* __restrict__ partials)
{
    constexpr int CC    = 64;
    constexpr int NCC   = CIN / CC;
    constexpr int KS    = 4;
    constexpr int AIT   = 4;
    constexpr int ABUF  = NN * CC * 2;        // 16 KB
    constexpr int BFR   = KS * 3 * 2;         // 24 frags
    constexpr int BBUF  = BFR * 1024;         // 24 KB
    constexpr int BIT   = BBUF / 4096;        // 6
    constexpr int BUFB  = ABUF + BBUF;        // 40 KB
    constexpr int SMEM  = 2 * BUFB;           // 80 KB

    __shared__ __align__(16) char gbuf[SMEM];
    float* rbuf = reinterpret_cast<float*>(gbuf + 81408);
    float (*cmax)[2][16] = reinterpret_cast<float (*)[2][16]>(gbuf + 80640);

    const int f  = blockIdx.x;
    const int s  = f >> 3;
    const int b  = (f & 7) + 8 * (s / OTN);
    const int oy = s % OTN;

    const int tid = threadIdx.x;
    const int lane = tid & 63;
    const int wv = tid >> 6;
    const int wm = wv >> 1, wn = wv & 1;
    const int l31 = lane & 31, lh2 = lane >> 5;

    float inv = 1.f, nmi = 0.f;
    if (NORM) { float mu = stats[0]; inv = stats[1]; nmi = -mu * inv; }

    const unsigned short* xb = xin + (size_t)b * NN * CIN;

    const int en = tid >> 1, eh = tid & 1;
    int sk[3];
#pragma unroll
    for (int k = 0; k < 3; ++k) sk[k] = idx[b * 3 * NN + 3 * en + k];

    f32x16 acc[2][3];
#pragma unroll
    for (int nf = 0; nf < 2; ++nf)
#pragma unroll
        for (int k = 0; k < 3; ++k) acc[nf][k] = (f32x16)0.f;

    auto issueB = [&](int ci, char* dst) {
        const unsigned short* src = wp + ((size_t)(oy * NCC + ci)) * (BFR * 512);
#pragma unroll
        for (int i = 0; i < BIT; ++i)
            __builtin_amdgcn_global_load_lds(
                (const AS1 void*)(src + (i * 256 + tid) * 8),
                (AS3 void*)(dst + (i * 256 + wv * 64) * 16),
                16, 0, 0);
    };
    auto issueA = [&](int cc, char* dst) {
#pragma unroll
        for (int i = 0; i < AIT; ++i) {
            int it = i * 256 + tid;
            int n = it >> 3, g = it & 7;
            const unsigned short* src = xb + cc * CC + n * CIN + ((g ^ (n & 7)) * 8);
            __builtin_amdgcn_global_load_lds(
                (const AS1 void*)src,
                (AS3 void*)(dst + (i * 256 + wv * 64) * 16),
                16, 0, 0);
        }
    };
    unsigned ngoff[AIT], lby[AIT];
#pragma unroll
    for (int i = 0; i < AIT; ++i) {
        int it = i * 256 + tid;
        int n = it >> 3, g = it & 7;
        ngoff[i] = (unsigned)(n * CIN + g * 8);
        lby[i]   = (unsigned)(n * 128 + ((g ^ (n & 7)) << 4));
    }
    auto loadA = [&](int cc, uint4* vv) {
#pragma unroll
        for (int i = 0; i < AIT; ++i)
            vv[i] = *reinterpret_cast<const uint4*>(xb + cc * CC + ngoff[i]);
    };
    const f32x2 iv2 = {inv, inv}, nm2 = {nmi, nmi};
    auto storA = [&](char* wb, const uint4* vv) {
#pragma unroll
        for (int i = 0; i < AIT; ++i) {
            uint4 t = vv[i];
            if (NORM) {
                unsigned int* pw = reinterpret_cast<unsigned int*>(&t);
#pragma unroll
                for (int q = 0; q < 4; ++q) {
                    unsigned int u = pw[q];
                    f32x2 sv, d;
                    sv[0] = __uint_as_float(u << 16);
                    sv[1] = __uint_as_float(u & 0xffff0000u);
                    asm("v_pk_fma_f32 %0, %1, %2, %3" : "=v"(d) : "v"(sv), "v"(iv2), "v"(nm2));
                    float f0 = fmaxf(d[0], 0.f);
                    float f1 = fmaxf(d[1], 0.f);
                    unsigned int r;
                    asm("v_cvt_pk_bf16_f32 %0, %1, %2" : "=v"(r) : "v"(f0), "v"(f1));
                    pw[q] = r;
                }
            }
            *reinterpret_cast<uint4*>(wb + lby[i]) = t;
        }
    };

    const int n0 = wm * 64 + l31;
    const int n1 = n0 + 32;
    const unsigned a0b = (unsigned)(n0 * 128), a0x = (unsigned)((n0 & 7) << 4);
    const unsigned a1b = (unsigned)(n1 * 128), a1x = (unsigned)((n1 & 7) << 4);

    uint4 v0[AIT], v1[AIT];

    if (GLLA) {
        issueB(0, gbuf + ABUF);
        issueA(0, gbuf);
        asm volatile("s_waitcnt vmcnt(0)" ::: "memory");
        __builtin_amdgcn_s_barrier();
        __builtin_amdgcn_sched_barrier(0);
    } else {
        issueB(0, gbuf + ABUF);
        loadA(0, v0);
        if (NCC > 1) loadA(1, v1);
        storA(gbuf, v0);
        asm volatile("s_waitcnt lgkmcnt(0)" ::: "memory");
        __builtin_amdgcn_s_barrier();
        __builtin_amdgcn_sched_barrier(0);
    }

#pragma unroll
    for (int cc = 0; cc < NCC; ++cc) {
        const int p = cc & 1;
        if (cc + 1 < NCC) {
            issueB(cc + 1, gbuf + (p ^ 1) * BUFB + ABUF);
            if (GLLA) issueA(cc + 1, gbuf + (p ^ 1) * BUFB);
            else if (cc + 2 < NCC) loadA(cc + 2, (cc & 1) ? v1 : v0);
        }
        const char* ab = gbuf + p * BUFB;
        const char* bb = ab + ABUF;
        __builtin_amdgcn_s_setprio(1);
#pragma unroll
        for (int ks = 0; ks < KS; ++ks) {
            const unsigned so = (unsigned)((ks * 2 + lh2) << 4);
            short8 a0 = *reinterpret_cast<const short8*>(ab + a0b + (so ^ a0x));
            short8 a1 = *reinterpret_cast<const short8*>(ab + a1b + (so ^ a1x));
#pragma unroll
            for (int k = 0; k < 3; ++k) {
                short8 bf_ = *reinterpret_cast<const short8*>(
                    bb + (((k * KS + ks) * 2 + wn) << 10) + lane * 16);
                acc[0][k] = __builtin_amdgcn_mfma_f32_32x32x16_bf16(a0, bf_, acc[0][k], 0, 0, 0);
                acc[1][k] = __builtin_amdgcn_mfma_f32_32x32x16_bf16(a1, bf_, acc[1][k], 0, 0, 0);
            }
        }
        __builtin_amdgcn_s_setprio(0);
        if (!GLLA && cc + 1 < NCC) storA(gbuf + (p ^ 1) * BUFB, (cc & 1) ? v0 : v1);

        if (cc + 1 < NCC) {
            if (GLLA) {
                asm volatile("s_waitcnt vmcnt(0)" ::: "memory");
            } else if (cc + 2 < NCC) {
                asm volatile("s_waitcnt vmcnt(4) lgkmcnt(0)" ::: "memory");
            } else {
                asm volatile("s_waitcnt vmcnt(0) lgkmcnt(0)" ::: "memory");
            }
            __builtin_amdgcn_s_barrier();
            __builtin_amdgcn_sched_barrier(0);
        } else {
            asm volatile("s_waitcnt lgkmcnt(0)" ::: "memory");
            __builtin_amdgcn_s_barrier();
            __builtin_amdgcn_sched_barrier(0);
        }
    }

    // epilogue: Z -> LDS (ds_write2, quad-coarse swizzle), gather
    float* Z = reinterpret_cast<float*>(gbuf);
    float tsum = 0.f, tss = 0.f;
#pragma unroll
    for (int oh = 0; oh < 2; ++oh) {
        if (oh) __syncthreads();
        if (wn == oh) {
#pragma unroll
            for (int k = 0; k < 3; ++k)
#pragma unroll
                for (int nf = 0; nf < 2; ++nf)
#pragma unroll
                    for (int q = 0; q < 4; ++q) {
                        int X = wm * 64 + nf * 32 + 8 * q + 4 * lh2;
                        unsigned zoff = (unsigned)(uintptr_t)(AS3 float*)(
                            Z + ((size_t)(k * NN + X) * 32 + (l31 ^ (X & 28))));
                        asm volatile("ds_write2_b32 %0, %1, %2 offset0:0 offset1:32"
                                     :: "v"(zoff), "v"(acc[nf][k][4 * q + 0]), "v"(acc[nf][k][4 * q + 1]));
                        asm volatile("ds_write2_b32 %0, %1, %2 offset0:64 offset1:96"
                                     :: "v"(zoff), "v"(acc[nf][k][4 * q + 2]), "v"(acc[nf][k][4 * q + 3]));
                    }
        }
        asm volatile("s_waitcnt lgkmcnt(0)" ::: "memory");
        __syncthreads();

        f32x2 val2[8];
        float* vp = reinterpret_cast<float*>(val2);
        {
            const float* bp = bias + oy * 64 + oh * 32 + eh * 16;
#pragma unroll
            for (int j = 0; j < 16; ++j) vp[j] = bp[j];
        }
#pragma unroll
        for (int k = 0; k < 3; ++k) {
            const float* zr = Z + (k * NN + sk[k]) * 32;
            const int sw = (sk[k] >> 2) & 7;
#pragma unroll
            for (int q4 = 0; q4 < 4; ++q4) {
                const int q = eh * 4 + q4;
                float4 z = *reinterpret_cast<const float4*>(zr + ((q ^ sw) << 2));
                f32x2 zlo = {z.x, z.y}, zhi = {z.z, z.w};
                val2[q4 * 2 + 0] += zlo;
                val2[q4 * 2 + 1] += zhi;
            }
        }
#pragma unroll
        for (int j = 0; j < 16; ++j) { tsum += vp[j]; tss += vp[j] * vp[j]; }

        if (COLMAX) {
#pragma unroll
            for (int m = 2; m <= 32; m <<= 1)
#pragma unroll
                for (int j = 0; j < 16; ++j) vp[j] = fmaxf(vp[j], __shfl_xor(vp[j], m));
            if ((lane >> 1) == 0) {
#pragma unroll
                for (int j = 0; j < 16; ++j) cmax[wv][lane & 1][j] = vp[j];
            }
            __syncthreads();
            if (tid < 32) {
                float m = fmaxf(fmaxf(cmax[0][tid >> 4][tid & 15], cmax[1][tid >> 4][tid & 15]),
                                fmaxf(cmax[2][tid >> 4][tid & 15], cmax[3][tid >> 4][tid & 15]));
                colmax[b * COUT + oy * 64 + oh * 32 + tid] = m;
            }
        } else {
            unsigned int pk[8];
#pragma unroll
            for (int j = 0; j < 8; ++j)
                asm("v_cvt_pk_bf16_f32 %0, %1, %2" : "=v"(pk[j]) : "v"(vp[2 * j]), "v"(vp[2 * j + 1]));
            unsigned short* dst = yout + ((size_t)b * NN + en) * COUT + oy * 64 + oh * 32 + eh * 16;
            reinterpret_cast<uint4*>(dst)[0] = make_uint4(pk[0], pk[1], pk[2], pk[3]);
            reinterpret_cast<uint4*>(dst)[1] = make_uint4(pk[4], pk[5], pk[6], pk[7]);
        }
    }

#pragma unroll
    for (int ss = 32; ss; ss >>= 1) { tsum += __shfl_down(tsum, ss); tss += __shfl_down(tss, ss); }
    if (lane == 0) { rbuf[wv * 2] = tsum; rbuf[wv * 2 + 1] = tss; }
    __syncthreads();
    if (tid == 0) {
        float sm = rbuf[0] + rbuf[2] + rbuf[4] + rbuf[6];
        float q = rbuf[1] + rbuf[3] + rbuf[5] + rbuf[7];
        int gid = oy * B + b;
        partials[2 * gid] = sm;
        partials[2 * gid + 1] = q;
    }
}

// ---------- finalize global layernorm stats ----------
__global__ __launch_bounds__(256) void stats_kernel(const float* __restrict__ partials,
                                                    float* __restrict__ stats,
                                                    int npart, double ntot)
{
    __shared__ double sd[256], sd2[256];
    double s = 0.0, s2 = 0.0;
    for (int i = threadIdx.x; i < npart; i += 256) { s += (double)partials[2 * i]; s2 += (double)partials[2 * i + 1]; }
    sd[threadIdx.x] = s; sd2[threadIdx.x] = s2;
    __syncthreads();
    for (int k = 128; k > 0; k >>= 1) {
        if (threadIdx.x < k) { sd[threadIdx.x] += sd[threadIdx.x + k]; sd2[threadIdx.x] += sd2[threadIdx.x + k]; }
        __syncthreads();
    }
    if (threadIdx.x == 0) {
        double mu = sd[0] / ntot;
        double var = (sd2[0] - sd[0] * sd[0] / ntot) / (ntot - 1.0);
        double sdv = sqrt(var > 0.0 ? var : 0.0);
        stats[0] = (float)mu;
        stats[1] = (float)(1.0 / (sdv + 1e-5));
    }
}

// ---------- heads from per-column max (raw) ----------
__global__ __launch_bounds__(128) void pool_head_kernel(const float* __restrict__ colmax,  // [B][128]
                                                        const float* __restrict__ stats,
                                                        const float* __restrict__ latw,
                                                        const float* __restrict__ latb,
                                                        const float* __restrict__ costw,
                                                        const float* __restrict__ costb,
                                                        float* __restrict__ out)
{
    const int b = blockIdx.x, t = threadIdx.x;
    const float mu = stats[0], inv = stats[1];
    const float pooled = fmaxf((colmax[b * 128 + t] - mu) * inv, 0.f);
    __shared__ float pl[128];
    pl[t] = pooled;
    __syncthreads();
    const float* w = (t < 64) ? latw : costw;
    const int l = t & 63;
    float v = pl[l] * w[l] + pl[l + 64] * w[l + 64];
#pragma unroll
    for (int s = 32; s > 0; s >>= 1) v += __shfl_down(v, s);
    if (l == 0) {
        const float bb = (t < 64) ? latb[0] : costb[0];
        out[(t < 64 ? 0 : B) + b] = 1.f / (1.f + expf(-(v + bb)));
    }
}

// ---------- launch ----------
extern "C" void kernel_launch(void* const* d_in, const int* in_sizes, int n_in,
                              void* d_out, int out_size, void* d_ws, size_t ws_size,
                              hipStream_t stream)
{
    (void)in_sizes; (void)n_in; (void)out_size; (void)ws_size;
    const float* trees   = (const float*)d_in[0];
    const int*   indexes = (const int*)  d_in[1];
    const float* enc_w   = (const float*)d_in[2];
    const float* enc_b   = (const float*)d_in[3];
    const float* w1 = (const float*)d_in[4];
    const float* b1 = (const float*)d_in[5];
    const float* w2 = (const float*)d_in[6];
    const float* b2 = (const float*)d_in[7];
    const float* w3 = (const float*)d_in[8];
    const float* b3 = (const float*)d_in[9];
    const float* lat_w  = (const float*)d_in[10];
    const float* lat_b  = (const float*)d_in[11];
    const float* cost_w = (const float*)d_in[12];
    const float* cost_b = (const float*)d_in[13];
    float* out = (float*)d_out;

    char* ws = (char*)d_ws;
    size_t off = 0;
    auto alloc = [&](size_t bytes) -> char* {
        char* p = ws + off;
        off += (bytes + 255) & ~(size_t)255;
        return p;
    };
    unsigned short* wpe  = (unsigned short*)alloc((size_t)320 * 128 * 2);
    unsigned short* wp1f = (unsigned short*)alloc((size_t)196608 * 2);
    unsigned short* wp2  = (unsigned short*)alloc((size_t)3 * 512 * 256 * 2);
    unsigned short* wp3  = (unsigned short*)alloc((size_t)3 * 256 * 128 * 2);
    unsigned short* y1   = (unsigned short*)alloc((size_t)B * NN * 512 * 2);
    unsigned short* y2   = (unsigned short*)alloc((size_t)B * NN * 256 * 2);
    float* colmax   = (float*)alloc((size_t)B * 128 * 4);
    float* partials = (float*)alloc((size_t)8192 * 2 * 4);
    float* stats    = (float*)alloc(8 * 4);

    prepack_w32<<<dim3((320 * 128 + 255) / 256), dim3(256), 0, stream>>>(enc_w, wpe, 1, 109, 318, 64, 128, 4, 5, 320);
    prepack_w1f<<<dim3(196608 / 256), dim3(256), 0, stream>>>(w1, wp1f);
    prepack_wB<<<dim3((3 * 512 * 256) / 256), dim3(256), 0, stream>>>(w2, wp2, 256, 512, 512, 256);
    prepack_wB<<<dim3((3 * 256 * 128) / 256), dim3(256), 0, stream>>>(w3, wp3, 128, 256, 256, 128);

    // FUSED encoder + conv1: trees -> y1 (x0 never leaves LDS; output-stationary gather)
    enc_conv1<<<dim3(B), dim3(256), 0, stream>>>(trees, indexes, wpe, enc_b, wp1f, b1, y1, partials);
    stats_kernel<<<dim3(1), dim3(256), 0, stream>>>(partials, stats + 0, 1024, (double)((size_t)B * 512 * NN));

    // conv2: B via GLL, A via VGPR+norm transform (NCC=8)
    conv_gemm<512, 4, 256, true, false, false>
        <<<dim3(B * 4), dim3(256), 0, stream>>>(y1, indexes, wp2, b2, stats + 0, y2, colmax, partials);
    stats_kernel<<<dim3(1), dim3(256), 0, stream>>>(partials, stats + 2, 4096, (double)((size_t)B * 256 * NN));

    // conv3: per-column raw max (pool fused, NCC=4)
    conv_gemm<256, 2, 128, true, true, false>
        <<<dim3(B * 2), dim3(256), 0, stream>>>(y2, indexes, wp3, b3, stats + 2, nullptr, colmax, partials);
    stats_kernel<<<dim3(1), dim3(256), 0, stream>>>(partials, stats + 4, 2048, (double)((size_t)B * 128 * NN));

    pool_head_kernel<<<dim3(B), dim3(128), 0, stream>>>(colmax, stats + 4, lat_w, lat_b, cost_w, cost_b, out);
}

// Round 16
// 325.107 us; speedup vs baseline: 1.2523x; 1.1055x over previous
//
#include <hip/hip_runtime.h>
#include <hip/hip_bf16.h>
#include <math.h>

using short8 = __attribute__((ext_vector_type(8))) short;
using f32x16 = __attribute__((ext_vector_type(16))) float;
using f32x2  = __attribute__((ext_vector_type(2))) float;

#define AS3 __attribute__((address_space(3)))
#define AS1 __attribute__((address_space(1)))

constexpr int B  = 1024;
constexpr int NN = 128;   // nodes per tree
constexpr int F  = 318;   // raw features

__device__ inline float bf2f(unsigned short u) {
    union { unsigned int i; float f; } x; x.i = ((unsigned int)u) << 16; return x.f;
}
__device__ inline unsigned short f2bf(float f) {
    union { float f; unsigned int i; } x; x.f = f;
    unsigned int r = x.i + 0x7fff + ((x.i >> 16) & 1);
    return (unsigned short)(r >> 16);
}

// ---------- encoder prepack: 32x32x16 B-frag order ----------
__global__ __launch_bounds__(256) void prepack_w32(const float* __restrict__ w,
                                                   unsigned short* __restrict__ wp,
                                                   int kmul, int OREAL, int CREAL,
                                                   int CC, int COUT, int KS, int NCC, int KTOT)
{
    int t = blockIdx.x * 256 + threadIdx.x;
    if (t >= KTOT * COUT) return;
    int j = t & 7;
    int lane = (t >> 3) & 63;
    int rest = t >> 9;
    int obn = COUT / 32;
    int ob = rest % obn;
    int kbg = rest / obn;
    int ks = kbg % KS;
    int t2 = kbg / KS;
    int cc = t2 % NCC;
    int k  = t2 / NCC;
    int c = cc * CC + ks * 16 + (lane >> 5) * 8 + j;
    int o = ob * 32 + (lane & 31);
    float v = 0.f;
    if (c < CREAL && o < OREAL)
        v = (kmul == 3) ? w[((size_t)o * CREAL + c) * 3 + k] : w[(size_t)o * CREAL + c];
    wp[t] = f2bf(v);
}

// ---------- conv1-fused prepack: [oy8][f48][lane][j8], f=(k*8+ks)*2+obp ----------
__global__ __launch_bounds__(256) void prepack_w1f(const float* __restrict__ w,
                                                   unsigned short* __restrict__ wp)
{
    int t = blockIdx.x * 256 + threadIdx.x;
    if (t >= 196608) return;
    int j = t & 7;
    int lane = (t >> 3) & 63;
    int r = t >> 9;            // 0..383
    int f = r % 48;
    int oy = r / 48;
    int obp = f & 1;
    int t2 = f >> 1;
    int ks = t2 & 7;
    int k  = t2 >> 3;
    int c = ks * 16 + (lane >> 5) * 8 + j;
    int o = oy * 64 + obp * 32 + (lane & 31);
    float v = (c < 109) ? w[((size_t)o * 109 + c) * 3 + k] : 0.f;
    wp[t] = f2bf(v);
}

// ---------- conv2/3 prepack: [oy][ci][k][ks][cb][lane][j], CC=32, KS=2, OT=128 ----------
__global__ __launch_bounds__(256) void prepack_wB32(const float* __restrict__ w,
                                                    unsigned short* __restrict__ wp,
                                                    int OREAL, int CREAL, int CIN, int COUT)
{
    const int NCC = CIN / 32;
    int t = blockIdx.x * 256 + threadIdx.x;
    if (t >= 3 * CIN * COUT) return;
    int j = t & 7;
    int lane = (t >> 3) & 63;
    int r = t >> 9;
    int cb = r & 3; r >>= 2;
    int ks = r & 1; r >>= 1;
    int k = r % 3; r /= 3;
    int ci = r % NCC;
    int oy = r / NCC;
    int c = ci * 32 + ks * 16 + (lane >> 5) * 8 + j;
    int o = oy * 128 + cb * 32 + (lane & 31);
    float v = 0.f;
    if (c < CREAL && o < OREAL) v = w[((size_t)o * CREAL + c) * 3 + k];
    wp[t] = f2bf(v);
}

// ---------- FUSED encoder + conv1 : one block per batch b (unchanged from R15) ----------
__global__ __launch_bounds__(256, 2) void enc_conv1(const float* __restrict__ trees,
                                                    const int* __restrict__ idx,
                                                    const unsigned short* __restrict__ wpe,
                                                    const float* __restrict__ encb,
                                                    const unsigned short* __restrict__ wp1,
                                                    const float* __restrict__ b1,
                                                    unsigned short* __restrict__ y1,   // [B][NN][512]
                                                    float* __restrict__ partials)
{
    __shared__ __align__(16) char gbuf[81920];
    char* Xt = gbuf;               // 32KB x0 tile (persistent in phase 2)
    char* W  = gbuf + 32768;       // 48KB: enc staging dbuf / conv1 B / y-tile

    const int b = blockIdx.x;
    const int tid = threadIdx.x;
    const int lane = tid & 63;
    const int wv = tid >> 6;
    const int l31 = lane & 31, lh2 = lane >> 5;

    // ---------------- phase 1: encoder ----------------
    {
        constexpr int CC = 64, NCH = 5, KS = 4, NB = 4;
        constexpr int BUFB = NN * CC * 2;   // 16 KB
        const int cl = tid >> 2;
        const int nq = tid & 3;

        float4 vv[8];
        auto load = [&](int ch) {
            const int c = ch * CC + cl;
            const bool ok = (c < F);
            const float* src = trees + ((size_t)b * F + c) * NN + nq * 32;
#pragma unroll
            for (int j = 0; j < 8; ++j)
                vv[j] = ok ? *reinterpret_cast<const float4*>(src + j * 4) : make_float4(0.f, 0.f, 0.f, 0.f);
        };
        const int gsw = cl >> 3, cby = (cl & 7) * 2;
        auto stor = [&](char* wb) {
#pragma unroll
            for (int j = 0; j < 8; ++j) {
                const int n0 = nq * 32 + j * 4;
                const float f4[4] = {vv[j].x, vv[j].y, vv[j].z, vv[j].w};
#pragma unroll
                for (int r = 0; r < 4; ++r) {
                    const int n = n0 + r;
                    *reinterpret_cast<unsigned short*>(
                        wb + n * (CC * 2) + (((gsw ^ (n & 7)) << 4) + cby)) = f2bf(f4[r]);
                }
            }
        };

        f32x16 acc[NB];
#pragma unroll
        for (int ob = 0; ob < NB; ++ob) acc[ob] = (f32x16)0.f;

        const int nrow = wv * 32 + l31;
        const unsigned abyte = (unsigned)(nrow * (CC * 2));
        const unsigned axor = (unsigned)((nrow & 7) << 4);

        load(0); stor(W);
        __syncthreads();

        int p = 0;
#pragma unroll
        for (int ch = 0; ch < NCH; ++ch) {
            if (ch + 1 < NCH) load(ch + 1);
            const char* base = W + p * BUFB;
            __builtin_amdgcn_s_setprio(1);
#pragma unroll
            for (int ks = 0; ks < KS; ++ks) {
                const int kbg = ch * KS + ks;
                short8 a = *reinterpret_cast<const short8*>(
                    base + abyte + (((unsigned)((ks * 2 + lh2) << 4)) ^ axor));
                const unsigned short* wb_ = wpe + ((size_t)(kbg * 4) * 64 + lane) * 8;
#pragma unroll
                for (int ob = 0; ob < NB; ++ob) {
                    short8 bf_ = *reinterpret_cast<const short8*>(wb_ + ob * 512);
                    acc[ob] = __builtin_amdgcn_mfma_f32_32x32x16_bf16(a, bf_, acc[ob], 0, 0, 0);
                }
            }
            __builtin_amdgcn_s_setprio(0);
            if (ch + 1 < NCH) stor(W + (p ^ 1) * BUFB);
            __syncthreads();
            p ^= 1;
        }

        // epilogue -> X tile, 16-granule XOR swizzle (matches phase-2 reads)
#pragma unroll
        for (int ob = 0; ob < NB; ++ob) {
            const int c = ob * 32 + l31;
            const float bs = (c < 109) ? encb[c] : 0.f;
#pragma unroll
            for (int r = 0; r < 16; ++r) {
                float val = acc[ob][r] + bs;
                int row = wv * 32 + (r & 3) + 8 * (r >> 2) + 4 * lh2;
                int byte = row * 256 + ((((c >> 3) ^ (row & 15)) << 4) | ((c & 7) * 2));
                *reinterpret_cast<unsigned short*>(Xt + byte) = f2bf(val);
            }
        }
        __syncthreads();
    }

    // ---------------- phase 2: conv1, output-stationary A-side gather ----------------
    const int nrowA = wv * 32 + l31;
    unsigned aab[3], axm[3];
#pragma unroll
    for (int k = 0; k < 3; ++k) {
        int s_ = idx[b * 3 * NN + 3 * nrowA + k];
        aab[k] = (unsigned)(s_ * 256);
        axm[k] = (unsigned)(s_ & 15);
    }

    auto issueB = [&](int oy, int i0, int i1) {
        const unsigned short* srcB = wp1 + (size_t)oy * 48 * 512;
        for (int i = i0; i < i1; ++i)
            __builtin_amdgcn_global_load_lds(
                (const AS1 void*)(srcB + (i * 256 + tid) * 8),
                (AS3 void*)(W + (i * 256 + wv * 64) * 16),
                16, 0, 0);
    };

    float tsum = 0.f, tss = 0.f;

    issueB(0, 0, 12);
    asm volatile("s_waitcnt vmcnt(0)" ::: "memory");
    __builtin_amdgcn_s_barrier();
    __builtin_amdgcn_sched_barrier(0);

    for (int oy = 0; oy < 8; ++oy) {
        f32x16 acc[2];
#pragma unroll
        for (int obp = 0; obp < 2; ++obp) {
            const float bv = b1[oy * 64 + obp * 32 + l31];
#pragma unroll
            for (int r = 0; r < 16; ++r) acc[obp][r] = bv;
        }

        __builtin_amdgcn_s_setprio(1);
#pragma unroll
        for (int ks = 0; ks < 8; ++ks) {
#pragma unroll
            for (int k = 0; k < 3; ++k) {
                short8 a = *reinterpret_cast<const short8*>(
                    Xt + aab[k] + ((((unsigned)(ks * 2 + lh2)) ^ axm[k]) << 4));
#pragma unroll
                for (int obp = 0; obp < 2; ++obp) {
                    short8 bf_ = *reinterpret_cast<const short8*>(
                        W + (((k * 8 + ks) * 2 + obp) << 10) + lane * 16);
                    acc[obp] = __builtin_amdgcn_mfma_f32_32x32x16_bf16(a, bf_, acc[obp], 0, 0, 0);
                }
            }
        }
        __builtin_amdgcn_s_setprio(0);
        __syncthreads();                         // B reads done; W[0:16K] free

#pragma unroll
        for (int obp = 0; obp < 2; ++obp)
#pragma unroll
            for (int r = 0; r < 16; ++r) {
                float val = acc[obp][r];
                tsum += val; tss += val * val;
                int row = wv * 32 + (r & 3) + 8 * (r >> 2) + 4 * lh2;
                int col = obp * 32 + l31;
                int byte = row * 128 + ((col * 2) ^ ((row & 7) << 4));
                *reinterpret_cast<unsigned short*>(W + byte) = f2bf(val);
            }
        asm volatile("s_waitcnt lgkmcnt(0)" ::: "memory");
        __syncthreads();                         // y-tile visible

        if (oy + 1 < 8) issueB(oy + 1, 4, 12);

        {
            const int row = tid >> 1, h = tid & 1;
            unsigned short* dst = y1 + ((size_t)b * NN + row) * 512 + oy * 64;
#pragma unroll
            for (int j = 0; j < 4; ++j) {
                int cg = h * 4 + j;
                uint4 v = *reinterpret_cast<const uint4*>(W + row * 128 + ((cg ^ (row & 7)) << 4));
                *reinterpret_cast<uint4*>(dst + cg * 8) = v;
            }
        }
        __syncthreads();                         // y reads done

        if (oy + 1 < 8) {
            issueB(oy + 1, 0, 4);
            asm volatile("s_waitcnt vmcnt(0)" ::: "memory");
            __builtin_amdgcn_s_barrier();
            __builtin_amdgcn_sched_barrier(0);
        }
    }

    float* rbuf = reinterpret_cast<float*>(W);
#pragma unroll
    for (int ss = 32; ss; ss >>= 1) { tsum += __shfl_down(tsum, ss); tss += __shfl_down(tss, ss); }
    if (lane == 0) { rbuf[wv * 2] = tsum; rbuf[wv * 2 + 1] = tss; }
    __syncthreads();
    if (tid == 0) {
        float sm = rbuf[0] + rbuf[2] + rbuf[4] + rbuf[6];
        float q = rbuf[1] + rbuf[3] + rbuf[5] + rbuf[7];
        partials[2 * b] = sm;
        partials[2 * b + 1] = q;
    }
}

// ---------- conv2/conv3: output-stationary, A-side LDS gather, OT=128, CC=32 ----------
// y[n][o] = bias[o] + sum_{k,c} W[o][c][k] * T(x[idx[3n+k]][c]) ; acc holds y directly.
template <int CIN, int OTN, int COUT, bool COLMAX>
__global__ __launch_bounds__(256, 2) void conv_gemm(const unsigned short* __restrict__ xin, // [B][NN][CIN]
                                                    const int* __restrict__ idx,            // [B][3*NN]
                                                    const unsigned short* __restrict__ wp,  // [oy][ci][k][ks][cb] frags
                                                    const float* __restrict__ bias,
                                                    const float* __restrict__ stats,
                                                    unsigned short* __restrict__ yout,      // [B][NN][COUT]
                                                    float* __restrict__ colmax,             // [B][COUT]
                                                    float* __restrict__ partials)
{
    constexpr int CC    = 32;
    constexpr int NCC   = CIN / CC;
    constexpr int KS    = 2;
    constexpr int AIT   = 2;                  // A granules/thread (128 rows * 4 gr / 256)
    constexpr int ABUF  = NN * 128;           // 16 KB (rows padded to 128B, 8 slots)
    constexpr int BFR   = KS * 3 * 4;         // 24 frags
    constexpr int BBUF  = BFR * 1024;         // 24 KB
    constexpr int BIT   = 6;
    constexpr int BUFB  = ABUF + BBUF;        // 40 KB

    __shared__ __align__(16) char gbuf[81920];
    float (*cmax)[2][32] = reinterpret_cast<float (*)[2][32]>(gbuf + 79872); // 1KB
    float* rbuf = reinterpret_cast<float*>(gbuf + 81408);                    // 32B

    // XCD-grouping decode
    const int f  = blockIdx.x;
    const int s  = f >> 3;
    const int b  = (f & 7) + 8 * (s / OTN);
    const int oy = s % OTN;                   // o-tile base = oy*128

    const int tid = threadIdx.x;
    const int lane = tid & 63;
    const int wv = tid >> 6;
    const int wm = wv >> 1, wn = wv & 1;      // wave = 64 rows x 64 cols
    const int l31 = lane & 31, lh2 = lane >> 5;

    const float mu = stats[0], inv = stats[1];
    const float nmi = -mu * inv;

    const unsigned short* xb = xin + (size_t)b * NN * CIN;

    // gathered A rows for this lane: output rows wm*64 + nf*32 + l31
    unsigned aab[2][3], axm[2][3];
#pragma unroll
    for (int nf = 0; nf < 2; ++nf) {
        const int n = wm * 64 + nf * 32 + l31;
#pragma unroll
        for (int k = 0; k < 3; ++k) {
            int s_ = idx[b * 3 * NN + 3 * n + k];
            aab[nf][k] = (unsigned)(s_ * 128);
            axm[nf][k] = (unsigned)(s_ & 7);
        }
    }

    f32x16 acc[2][2];                          // [nf rows][nc cols]
#pragma unroll
    for (int nf = 0; nf < 2; ++nf)
#pragma unroll
        for (int nc = 0; nc < 2; ++nc) {
            const float bv = bias[oy * 128 + wn * 64 + nc * 32 + l31];
#pragma unroll
            for (int r = 0; r < 16; ++r) acc[nf][nc][r] = bv;
        }

    // ---- staging ----
    auto issueB = [&](int ci, char* dst) {
        const unsigned short* src = wp + ((size_t)(oy * NCC + ci)) * (BFR * 512);
#pragma unroll
        for (int i = 0; i < BIT; ++i)
            __builtin_amdgcn_global_load_lds(
                (const AS1 void*)(src + (i * 256 + tid) * 8),
                (AS3 void*)(dst + (i * 256 + wv * 64) * 16),
                16, 0, 0);
    };
    unsigned ngoff[AIT], lby[AIT];
#pragma unroll
    for (int i = 0; i < AIT; ++i) {
        int it = i * 256 + tid;
        int n = it >> 2, g = it & 3;
        ngoff[i] = (unsigned)(n * CIN + g * 8);
        lby[i]   = (unsigned)(n * 128 + ((g ^ (n & 7)) << 4));
    }
    auto loadA = [&](int cc, uint4* vv) {
#pragma unroll
        for (int i = 0; i < AIT; ++i)
            vv[i] = *reinterpret_cast<const uint4*>(xb + cc * CC + ngoff[i]);
    };
    const f32x2 iv2 = {inv, inv}, nm2 = {nmi, nmi};
    auto storA = [&](char* wb, const uint4* vv) {
#pragma unroll
        for (int i = 0; i < AIT; ++i) {
            uint4 t = vv[i];
            unsigned int* pw = reinterpret_cast<unsigned int*>(&t);
#pragma unroll
            for (int q = 0; q < 4; ++q) {
                unsigned int u = pw[q];
                f32x2 sv, d;
                sv[0] = __uint_as_float(u << 16);
                sv[1] = __uint_as_float(u & 0xffff0000u);
                asm("v_pk_fma_f32 %0, %1, %2, %3" : "=v"(d) : "v"(sv), "v"(iv2), "v"(nm2));
                float f0 = fmaxf(d[0], 0.f);
                float f1 = fmaxf(d[1], 0.f);
                unsigned int r;
                asm("v_cvt_pk_bf16_f32 %0, %1, %2" : "=v"(r) : "v"(f0), "v"(f1));
                pw[q] = r;
            }
            *reinterpret_cast<uint4*>(wb + lby[i]) = t;
        }
    };

    uint4 v0[AIT], v1[AIT];

    // prologue
    issueB(0, gbuf + ABUF);
    loadA(0, v0);
    loadA(1, v1);
    storA(gbuf, v0);
    asm volatile("s_waitcnt lgkmcnt(0)" ::: "memory");
    __builtin_amdgcn_s_barrier();
    __builtin_amdgcn_sched_barrier(0);

    // main loop: counted-vmcnt raw barriers
#pragma unroll
    for (int cc = 0; cc < NCC; ++cc) {
        const int p = cc & 1;
        if (cc + 1 < NCC) {
            issueB(cc + 1, gbuf + (p ^ 1) * BUFB + ABUF);
            if (cc + 2 < NCC) loadA(cc + 2, (cc & 1) ? v1 : v0);
        }
        const char* ab = gbuf + p * BUFB;
        const char* bb = ab + ABUF;
        __builtin_amdgcn_s_setprio(1);
#pragma unroll
        for (int ks = 0; ks < KS; ++ks) {
            const unsigned s0 = (unsigned)(ks * 2 + lh2);
#pragma unroll
            for (int k = 0; k < 3; ++k) {
                short8 a0 = *reinterpret_cast<const short8*>(ab + aab[0][k] + ((s0 ^ axm[0][k]) << 4));
                short8 a1 = *reinterpret_cast<const short8*>(ab + aab[1][k] + ((s0 ^ axm[1][k]) << 4));
#pragma unroll
                for (int nc = 0; nc < 2; ++nc) {
                    short8 bf_ = *reinterpret_cast<const short8*>(
                        bb + (((k * KS + ks) * 4 + wn * 2 + nc) << 10) + lane * 16);
                    acc[0][nc] = __builtin_amdgcn_mfma_f32_32x32x16_bf16(a0, bf_, acc[0][nc], 0, 0, 0);
                    acc[1][nc] = __builtin_amdgcn_mfma_f32_32x32x16_bf16(a1, bf_, acc[1][nc], 0, 0, 0);
                }
            }
        }
        __builtin_amdgcn_s_setprio(0);
        if (cc + 1 < NCC) storA(gbuf + (p ^ 1) * BUFB, (cc & 1) ? v0 : v1);

        if (cc + 1 < NCC) {
            if (cc + 2 < NCC) {
                asm volatile("s_waitcnt vmcnt(2) lgkmcnt(0)" ::: "memory");
            } else {
                asm volatile("s_waitcnt vmcnt(0) lgkmcnt(0)" ::: "memory");
            }
            __builtin_amdgcn_s_barrier();
            __builtin_amdgcn_sched_barrier(0);
        } else {
            asm volatile("s_waitcnt lgkmcnt(0)" ::: "memory");
            __builtin_amdgcn_s_barrier();
            __builtin_amdgcn_sched_barrier(0);
        }
    }

    // ---------------- epilogue ----------------
    float tsum = 0.f, tss = 0.f;

    if (COLMAX) {
        float m[2] = {-1e30f, -1e30f};
#pragma unroll
        for (int nf = 0; nf < 2; ++nf)
#pragma unroll
            for (int nc = 0; nc < 2; ++nc)
#pragma unroll
                for (int r = 0; r < 16; ++r) {
                    float val = acc[nf][nc][r];
                    tsum += val; tss += val * val;
                    m[nc] = fmaxf(m[nc], val);
                }
#pragma unroll
        for (int nc = 0; nc < 2; ++nc) m[nc] = fmaxf(m[nc], __shfl_xor(m[nc], 32));
        if (lh2 == 0) {
#pragma unroll
            for (int nc = 0; nc < 2; ++nc) cmax[wv][nc][l31] = m[nc];
        }
        __syncthreads();
        if (tid < 128) {
            const int c = tid;
            const int wn_ = (c >> 6) & 1, nc_ = (c >> 5) & 1, l_ = c & 31;
            float mm = fmaxf(cmax[wn_][nc_][l_], cmax[2 + wn_][nc_][l_]);
            colmax[b * COUT + c] = mm;
        }
    } else {
        // y-tile bounce [128][128] bf16 (32KB), 16-granule XOR swizzle
        unsigned short* yt = reinterpret_cast<unsigned short*>(gbuf);
#pragma unroll
        for (int nf = 0; nf < 2; ++nf)
#pragma unroll
            for (int nc = 0; nc < 2; ++nc)
#pragma unroll
                for (int r = 0; r < 16; ++r) {
                    float val = acc[nf][nc][r];
                    tsum += val; tss += val * val;
                    int row = wm * 64 + nf * 32 + (r & 3) + 8 * (r >> 2) + 4 * lh2;
                    int col = wn * 64 + nc * 32 + l31;
                    int byte = row * 256 + ((((col >> 3) ^ (row & 15)) << 4) | ((col & 7) * 2));
                    *reinterpret_cast<unsigned short*>(reinterpret_cast<char*>(yt) + byte) = f2bf(val);
                }
        __syncthreads();
        {
            const int row = tid >> 1, h = tid & 1;
            unsigned short* dst = yout + ((size_t)b * NN + row) * COUT + oy * 128;
#pragma unroll
            for (int j = 0; j < 8; ++j) {
                int g = h * 8 + j;
                uint4 v = *reinterpret_cast<const uint4*>(
                    reinterpret_cast<char*>(yt) + row * 256 + (((g ^ (row & 15))) << 4));
                *reinterpret_cast<uint4*>(dst + g * 8) = v;
            }
        }
    }

    // block stats reduction
#pragma unroll
    for (int ss = 32; ss; ss >>= 1) { tsum += __shfl_down(tsum, ss); tss += __shfl_down(tss, ss); }
    __syncthreads();
    if (lane == 0) { rbuf[wv * 2] = tsum; rbuf[wv * 2 + 1] = tss; }
    __syncthreads();
    if (tid == 0) {
        float sm = rbuf[0] + rbuf[2] + rbuf[4] + rbuf[6];
        float q = rbuf[1] + rbuf[3] + rbuf[5] + rbuf[7];
        int gid = oy * B + b;
        partials[2 * gid] = sm;
        partials[2 * gid + 1] = q;
    }
}

// ---------- finalize global layernorm stats ----------
__global__ __launch_bounds__(256) void stats_kernel(const float* __restrict__ partials,
                                                    float* __restrict__ stats,
                                                    int npart, double ntot)
{
    __shared__ double sd[256], sd2[256];
    double s = 0.0, s2 = 0.0;
    for (int i = threadIdx.x; i < npart; i += 256) { s += (double)partials[2 * i]; s2 += (double)partials[2 * i + 1]; }
    sd[threadIdx.x] = s; sd2[threadIdx.x] = s2;
    __syncthreads();
    for (int k = 128; k > 0; k >>= 1) {
        if (threadIdx.x < k) { sd[threadIdx.x] += sd[threadIdx.x + k]; sd2[threadIdx.x] += sd2[threadIdx.x + k]; }
        __syncthreads();
    }
    if (threadIdx.x == 0) {
        double mu = sd[0] / ntot;
        double var = (sd2[0] - sd[0] * sd[0] / ntot) / (ntot - 1.0);
        double sdv = sqrt(var > 0.0 ? var : 0.0);
        stats[0] = (float)mu;
        stats[1] = (float)(1.0 / (sdv + 1e-5));
    }
}

// ---------- heads from per-column max (raw) ----------
__global__ __launch_bounds__(128) void pool_head_kernel(const float* __restrict__ colmax,  // [B][128]
                                                        const float* __restrict__ stats,
                                                        const float* __restrict__ latw,
                                                        const float* __restrict__ latb,
                                                        const float* __restrict__ costw,
                                                        const float* __restrict__ costb,
                                                        float* __restrict__ out)
{
    const int b = blockIdx.x, t = threadIdx.x;
    const float mu = stats[0], inv = stats[1];
    const float pooled = fmaxf((colmax[b * 128 + t] - mu) * inv, 0.f);
    __shared__ float pl[128];
    pl[t] = pooled;
    __syncthreads();
    const float* w = (t < 64) ? latw : costw;
    const int l = t & 63;
    float v = pl[l] * w[l] + pl[l + 64] * w[l + 64];
#pragma unroll
    for (int s = 32; s > 0; s >>= 1) v += __shfl_down(v, s);
    if (l == 0) {
        const float bb = (t < 64) ? latb[0] : costb[0];
        out[(t < 64 ? 0 : B) + b] = 1.f / (1.f + expf(-(v + bb)));
    }
}

// ---------- launch ----------
extern "C" void kernel_launch(void* const* d_in, const int* in_sizes, int n_in,
                              void* d_out, int out_size, void* d_ws, size_t ws_size,
                              hipStream_t stream)
{
    (void)in_sizes; (void)n_in; (void)out_size; (void)ws_size;
    const float* trees   = (const float*)d_in[0];
    const int*   indexes = (const int*)  d_in[1];
    const float* enc_w   = (const float*)d_in[2];
    const float* enc_b   = (const float*)d_in[3];
    const float* w1 = (const float*)d_in[4];
    const float* b1 = (const float*)d_in[5];
    const float* w2 = (const float*)d_in[6];
    const float* b2 = (const float*)d_in[7];
    const float* w3 = (const float*)d_in[8];
    const float* b3 = (const float*)d_in[9];
    const float* lat_w  = (const float*)d_in[10];
    const float* lat_b  = (const float*)d_in[11];
    const float* cost_w = (const float*)d_in[12];
    const float* cost_b = (const float*)d_in[13];
    float* out = (float*)d_out;

    char* ws = (char*)d_ws;
    size_t off = 0;
    auto alloc = [&](size_t bytes) -> char* {
        char* p = ws + off;
        off += (bytes + 255) & ~(size_t)255;
        return p;
    };
    unsigned short* wpe  = (unsigned short*)alloc((size_t)320 * 128 * 2);
    unsigned short* wp1f = (unsigned short*)alloc((size_t)196608 * 2);
    unsigned short* wp2  = (unsigned short*)alloc((size_t)3 * 512 * 256 * 2);
    unsigned short* wp3  = (unsigned short*)alloc((size_t)3 * 256 * 128 * 2);
    unsigned short* y1   = (unsigned short*)alloc((size_t)B * NN * 512 * 2);
    unsigned short* y2   = (unsigned short*)alloc((size_t)B * NN * 256 * 2);
    float* colmax   = (float*)alloc((size_t)B * 128 * 4);
    float* partials = (float*)alloc((size_t)8192 * 2 * 4);
    float* stats    = (float*)alloc(8 * 4);

    prepack_w32<<<dim3((320 * 128 + 255) / 256), dim3(256), 0, stream>>>(enc_w, wpe, 1, 109, 318, 64, 128, 4, 5, 320);
    prepack_w1f<<<dim3(196608 / 256), dim3(256), 0, stream>>>(w1, wp1f);
    prepack_wB32<<<dim3((3 * 512 * 256) / 256), dim3(256), 0, stream>>>(w2, wp2, 256, 512, 512, 256);
    prepack_wB32<<<dim3((3 * 256 * 128) / 256), dim3(256), 0, stream>>>(w3, wp3, 128, 256, 256, 128);

    // FUSED encoder + conv1: trees -> y1 (x0 never leaves LDS; A-side gather)
    enc_conv1<<<dim3(B), dim3(256), 0, stream>>>(trees, indexes, wpe, enc_b, wp1f, b1, y1, partials);
    stats_kernel<<<dim3(1), dim3(256), 0, stream>>>(partials, stats + 0, 1024, (double)((size_t)B * 512 * NN));

    // conv2: output-stationary, OT=128, 2 o-tiles
    conv_gemm<512, 2, 256, false>
        <<<dim3(B * 2), dim3(256), 0, stream>>>(y1, indexes, wp2, b2, stats + 0, y2, colmax, partials);
    stats_kernel<<<dim3(1), dim3(256), 0, stream>>>(partials, stats + 2, 2048, (double)((size_t)B * 256 * NN));

    // conv3: output-stationary, OT=128, colmax fused
    conv_gemm<256, 1, 128, true>
        <<<dim3(B), dim3(256), 0, stream>>>(y2, indexes, wp3, b3, stats + 2, nullptr, colmax, partials);
    stats_kernel<<<dim3(1), dim3(256), 0, stream>>>(partials, stats + 4, 1024, (double)((size_t)B * 128 * NN));

    pool_head_kernel<<<dim3(B), dim3(128), 0, stream>>>(colmax, stats + 4, lat_w, lat_b, cost_w, cost_b, out);
}

// Round 17
// 311.090 us; speedup vs baseline: 1.3087x; 1.0451x over previous
//
#include <hip/hip_runtime.h>
#include <hip/hip_bf16.h>
#include <math.h>

using short8 = __attribute__((ext_vector_type(8))) short;
using f32x16 = __attribute__((ext_vector_type(16))) float;
using f32x2  = __attribute__((ext_vector_type(2))) float;

#define AS3 __attribute__((address_space(3)))
#define AS1 __attribute__((address_space(1)))

constexpr int B  = 1024;
constexpr int NN = 128;   // nodes per tree
constexpr int F  = 318;   // raw features

__device__ inline float bf2f(unsigned short u) {
    union { unsigned int i; float f; } x; x.i = ((unsigned int)u) << 16; return x.f;
}
__device__ inline unsigned short f2bf(float f) {
    union { float f; unsigned int i; } x; x.f = f;
    unsigned int r = x.i + 0x7fff + ((x.i >> 16) & 1);
    return (unsigned short)(r >> 16);
}

// ---------- encoder prepack: 32x32x16 B-frag order ----------
__global__ __launch_bounds__(256) void prepack_w32(const float* __restrict__ w,
                                                   unsigned short* __restrict__ wp,
                                                   int kmul, int OREAL, int CREAL,
                                                   int CC, int COUT, int KS, int NCC, int KTOT)
{
    int t = blockIdx.x * 256 + threadIdx.x;
    if (t >= KTOT * COUT) return;
    int j = t & 7;
    int lane = (t >> 3) & 63;
    int rest = t >> 9;
    int obn = COUT / 32;
    int ob = rest % obn;
    int kbg = rest / obn;
    int ks = kbg % KS;
    int t2 = kbg / KS;
    int cc = t2 % NCC;
    int k  = t2 / NCC;
    int c = cc * CC + ks * 16 + (lane >> 5) * 8 + j;
    int o = ob * 32 + (lane & 31);
    float v = 0.f;
    if (c < CREAL && o < OREAL)
        v = (kmul == 3) ? w[((size_t)o * CREAL + c) * 3 + k] : w[(size_t)o * CREAL + c];
    wp[t] = f2bf(v);
}

// ---------- conv1-fused prepack, HALF-ordered: [oy8][h2][(k*4+ks2)*2+obp][lane][j8] ----------
__global__ __launch_bounds__(256) void prepack_w1f(const float* __restrict__ w,
                                                   unsigned short* __restrict__ wp)
{
    int t = blockIdx.x * 256 + threadIdx.x;
    if (t >= 196608) return;
    int j = t & 7;
    int lane = (t >> 3) & 63;
    int r = t >> 9;            // 0..383
    int fp = r % 48;
    int oy = r / 48;
    int h   = fp / 24;
    int rem = fp % 24;
    int obp = rem & 1;
    int q   = rem >> 1;        // 0..11
    int ks2 = q & 3;
    int k   = q >> 2;
    int ks  = h * 4 + ks2;
    int c = ks * 16 + (lane >> 5) * 8 + j;
    int o = oy * 64 + obp * 32 + (lane & 31);
    float v = (c < 109) ? w[((size_t)o * 109 + c) * 3 + k] : 0.f;
    wp[t] = f2bf(v);
}

// ---------- conv2/3 prepack: [oy][ci][k][ks][cb][lane][j], CC=32, KS=2, OT=128 ----------
// Input channel positions are PERMUTED (producer stores pairs): c = perm(pos).
__global__ __launch_bounds__(256) void prepack_wB32(const float* __restrict__ w,
                                                    unsigned short* __restrict__ wp,
                                                    int OREAL, int CREAL, int CIN, int COUT)
{
    const int NCC = CIN / 32;
    int t = blockIdx.x * 256 + threadIdx.x;
    if (t >= 3 * CIN * COUT) return;
    int j = t & 7;
    int lane = (t >> 3) & 63;
    int r = t >> 9;
    int cb = r & 3; r >>= 2;
    int ks = r & 1; r >>= 1;
    int k = r % 3; r /= 3;
    int ci = r % NCC;
    int oy = r / NCC;
    int pos = ci * 32 + ks * 16 + (lane >> 5) * 8 + j;
    int c = (pos & ~63) | ((pos & 1) << 5) | ((pos >> 1) & 31);   // unified producer perm
    int o = oy * 128 + cb * 32 + (lane & 31);
    float v = 0.f;
    if (c < CREAL && o < OREAL) v = w[((size_t)o * CREAL + c) * 3 + k];
    wp[t] = f2bf(v);
}

// ---------- FUSED encoder + conv1 ----------
// Phase 1: x0[b] -> LDS tile X (32KB swizzled). Phase 2: output-stationary conv1,
// B in 24KB half-tiles (1 barrier/half, counted vmcnt), PERMUTED direct dword stores.
__global__ __launch_bounds__(256, 2) void enc_conv1(const float* __restrict__ trees,
                                                    const int* __restrict__ idx,
                                                    const unsigned short* __restrict__ wpe,
                                                    const float* __restrict__ encb,
                                                    const unsigned short* __restrict__ wp1,
                                                    const float* __restrict__ b1,
                                                    unsigned short* __restrict__ y1,   // [B][NN][512] permuted
                                                    float* __restrict__ partials)
{
    __shared__ __align__(16) char gbuf[81920];
    char* Xt = gbuf;               // 32KB x0 tile (persistent in phase 2)
    char* W  = gbuf + 32768;       // 48KB: enc staging dbuf / conv1 B halves

    const int b = blockIdx.x;
    const int tid = threadIdx.x;
    const int lane = tid & 63;
    const int wv = tid >> 6;
    const int l31 = lane & 31, lh2 = lane >> 5;

    // ---------------- phase 1: encoder ----------------
    {
        constexpr int CC = 64, NCH = 5, KS = 4, NB = 4;
        constexpr int BUFB = NN * CC * 2;   // 16 KB
        const int cl = tid >> 2;
        const int nq = tid & 3;

        float4 vv[8];
        auto load = [&](int ch) {
            const int c = ch * CC + cl;
            const bool ok = (c < F);
            const float* src = trees + ((size_t)b * F + c) * NN + nq * 32;
#pragma unroll
            for (int j = 0; j < 8; ++j)
                vv[j] = ok ? *reinterpret_cast<const float4*>(src + j * 4) : make_float4(0.f, 0.f, 0.f, 0.f);
        };
        const int gsw = cl >> 3, cby = (cl & 7) * 2;
        auto stor = [&](char* wb) {
#pragma unroll
            for (int j = 0; j < 8; ++j) {
                const int n0 = nq * 32 + j * 4;
                const float f4[4] = {vv[j].x, vv[j].y, vv[j].z, vv[j].w};
#pragma unroll
                for (int r = 0; r < 4; ++r) {
                    const int n = n0 + r;
                    *reinterpret_cast<unsigned short*>(
                        wb + n * (CC * 2) + (((gsw ^ (n & 7)) << 4) + cby)) = f2bf(f4[r]);
                }
            }
        };

        f32x16 acc[NB];
#pragma unroll
        for (int ob = 0; ob < NB; ++ob) acc[ob] = (f32x16)0.f;

        const int nrow = wv * 32 + l31;
        const unsigned abyte = (unsigned)(nrow * (CC * 2));
        const unsigned axor = (unsigned)((nrow & 7) << 4);

        load(0); stor(W);
        __syncthreads();

        int p = 0;
#pragma unroll
        for (int ch = 0; ch < NCH; ++ch) {
            if (ch + 1 < NCH) load(ch + 1);
            const char* base = W + p * BUFB;
            __builtin_amdgcn_s_setprio(1);
#pragma unroll
            for (int ks = 0; ks < KS; ++ks) {
                const int kbg = ch * KS + ks;
                short8 a = *reinterpret_cast<const short8*>(
                    base + abyte + (((unsigned)((ks * 2 + lh2) << 4)) ^ axor));
                const unsigned short* wb_ = wpe + ((size_t)(kbg * 4) * 64 + lane) * 8;
#pragma unroll
                for (int ob = 0; ob < NB; ++ob) {
                    short8 bf_ = *reinterpret_cast<const short8*>(wb_ + ob * 512);
                    acc[ob] = __builtin_amdgcn_mfma_f32_32x32x16_bf16(a, bf_, acc[ob], 0, 0, 0);
                }
            }
            __builtin_amdgcn_s_setprio(0);
            if (ch + 1 < NCH) stor(W + (p ^ 1) * BUFB);
            __syncthreads();
            p ^= 1;
        }

        // epilogue -> X tile, 16-granule XOR swizzle (matches phase-2 reads)
#pragma unroll
        for (int ob = 0; ob < NB; ++ob) {
            const int c = ob * 32 + l31;
            const float bs = (c < 109) ? encb[c] : 0.f;
#pragma unroll
            for (int r = 0; r < 16; ++r) {
                float val = acc[ob][r] + bs;
                int row = wv * 32 + (r & 3) + 8 * (r >> 2) + 4 * lh2;
                int byte = row * 256 + ((((c >> 3) ^ (row & 15)) << 4) | ((c & 7) * 2));
                *reinterpret_cast<unsigned short*>(Xt + byte) = f2bf(val);
            }
        }
        __syncthreads();
    }

    // ---------------- phase 2: conv1, half-tile pipelined, permuted direct store ----------------
    const int nrowA = wv * 32 + l31;
    unsigned aab[3], axm[3];
#pragma unroll
    for (int k = 0; k < 3; ++k) {
        int s_ = idx[b * 3 * NN + 3 * nrowA + k];
        aab[k] = (unsigned)(s_ * 256);
        axm[k] = (unsigned)(s_ & 15);
    }

    char* bufs[2] = {W, W + 24576};
    auto issueBh = [&](int ht) {
        const unsigned short* src = wp1 + (size_t)ht * 24 * 512;
        char* dst = bufs[ht & 1];
#pragma unroll
        for (int i = 0; i < 6; ++i)
            __builtin_amdgcn_global_load_lds(
                (const AS1 void*)(src + (i * 256 + tid) * 8),
                (AS3 void*)(dst + (i * 256 + wv * 64) * 16),
                16, 0, 0);
    };

    unsigned int* y1w = reinterpret_cast<unsigned int*>(y1);
    float tsum = 0.f, tss = 0.f;

    issueBh(0);
    issueBh(1);
    asm volatile("s_waitcnt vmcnt(6)" ::: "memory");
    __builtin_amdgcn_s_barrier();
    __builtin_amdgcn_sched_barrier(0);

    f32x16 acc[2];
#pragma unroll 1
    for (int ht = 0; ht < 16; ++ht) {
        const int h = ht & 1, oy = ht >> 1;
        const char* bp = bufs[h];
        if (h == 0) {
#pragma unroll
            for (int obp = 0; obp < 2; ++obp) {
                const float bv = b1[oy * 64 + obp * 32 + l31];
#pragma unroll
                for (int r = 0; r < 16; ++r) acc[obp][r] = bv;
            }
        }
        __builtin_amdgcn_s_setprio(1);
#pragma unroll
        for (int ks2 = 0; ks2 < 4; ++ks2) {
#pragma unroll
            for (int k = 0; k < 3; ++k) {
                const unsigned slot = ((unsigned)((h * 4 + ks2) * 2 + lh2)) ^ axm[k];
                short8 a = *reinterpret_cast<const short8*>(Xt + aab[k] + (slot << 4));
#pragma unroll
                for (int obp = 0; obp < 2; ++obp) {
                    short8 bf_ = *reinterpret_cast<const short8*>(
                        bp + (((k * 4 + ks2) * 2 + obp) << 10) + lane * 16);
                    acc[obp] = __builtin_amdgcn_mfma_f32_32x32x16_bf16(a, bf_, acc[obp], 0, 0, 0);
                }
            }
        }
        __builtin_amdgcn_s_setprio(0);

        if (h == 1) {
            // stats + permuted dword stores (pair (c, c+32) packed per row)
#pragma unroll
            for (int r = 0; r < 16; ++r) {
                float v0_ = acc[0][r], v1_ = acc[1][r];
                tsum += v0_ + v1_;
                tss  += v0_ * v0_ + v1_ * v1_;
                unsigned int pk;
                asm("v_cvt_pk_bf16_f32 %0, %1, %2" : "=v"(pk) : "v"(v0_), "v"(v1_));
                int row = wv * 32 + (r & 3) + 8 * (r >> 2) + 4 * lh2;
                y1w[((size_t)b * NN + row) * 256 + oy * 32 + l31] = pk;
            }
        }

        if (ht + 1 < 16) {
            if (h == 1) { asm volatile("s_waitcnt vmcnt(16)" ::: "memory"); }
            else        { asm volatile("s_waitcnt vmcnt(0)"  ::: "memory"); }
            __builtin_amdgcn_s_barrier();
            __builtin_amdgcn_sched_barrier(0);
            if (ht + 2 < 16) issueBh(ht + 2);
        }
    }

    __syncthreads();
    float* rbuf = reinterpret_cast<float*>(W);
#pragma unroll
    for (int ss = 32; ss; ss >>= 1) { tsum += __shfl_down(tsum, ss); tss += __shfl_down(tss, ss); }
    if (lane == 0) { rbuf[wv * 2] = tsum; rbuf[wv * 2 + 1] = tss; }
    __syncthreads();
    if (tid == 0) {
        float sm = rbuf[0] + rbuf[2] + rbuf[4] + rbuf[6];
        float q = rbuf[1] + rbuf[3] + rbuf[5] + rbuf[7];
        partials[2 * b] = sm;
        partials[2 * b + 1] = q;
    }
}

// ---------- conv2/conv3: output-stationary, A-side LDS gather, OT=128, CC=32 ----------
// Non-COLMAX output: PERMUTED direct dword stores (pair (c, c+32) per row).
template <int CIN, int OTN, int COUT, bool COLMAX>
__global__ __launch_bounds__(256, 2) void conv_gemm(const unsigned short* __restrict__ xin, // [B][NN][CIN] permuted
                                                    const int* __restrict__ idx,            // [B][3*NN]
                                                    const unsigned short* __restrict__ wp,  // perm-compensated frags
                                                    const float* __restrict__ bias,
                                                    const float* __restrict__ stats,
                                                    unsigned short* __restrict__ yout,      // [B][NN][COUT] permuted
                                                    float* __restrict__ colmax,             // [B][COUT]
                                                    float* __restrict__ partials)
{
    constexpr int CC    = 32;
    constexpr int NCC   = CIN / CC;
    constexpr int AIT   = 2;
    constexpr int ABUF  = NN * 128;           // 16 KB (rows padded to 128B, 8 slots)
    constexpr int BFR   = 2 * 3 * 4;          // 24 frags
    constexpr int BBUF  = BFR * 1024;         // 24 KB
    constexpr int BIT   = 6;
    constexpr int BUFB  = ABUF + BBUF;        // 40 KB

    __shared__ __align__(16) char gbuf[81920];
    float (*cmax)[2][32] = reinterpret_cast<float (*)[2][32]>(gbuf + 79872);
    float* rbuf = reinterpret_cast<float*>(gbuf + 81408);

    const int f  = blockIdx.x;
    const int s  = f >> 3;
    const int b  = (f & 7) + 8 * (s / OTN);
    const int oy = s % OTN;

    const int tid = threadIdx.x;
    const int lane = tid & 63;
    const int wv = tid >> 6;
    const int wm = wv >> 1, wn = wv & 1;
    const int l31 = lane & 31, lh2 = lane >> 5;

    const float mu = stats[0], inv = stats[1];
    const float nmi = -mu * inv;

    const unsigned short* xb = xin + (size_t)b * NN * CIN;

    unsigned aab[2][3], axm[2][3];
#pragma unroll
    for (int nf = 0; nf < 2; ++nf) {
        const int n = wm * 64 + nf * 32 + l31;
#pragma unroll
        for (int k = 0; k < 3; ++k) {
            int s_ = idx[b * 3 * NN + 3 * n + k];
            aab[nf][k] = (unsigned)(s_ * 128);
            axm[nf][k] = (unsigned)(s_ & 7);
        }
    }

    f32x16 acc[2][2];
#pragma unroll
    for (int nf = 0; nf < 2; ++nf)
#pragma unroll
        for (int nc = 0; nc < 2; ++nc) {
            const float bv = bias[oy * 128 + wn * 64 + nc * 32 + l31];
#pragma unroll
            for (int r = 0; r < 16; ++r) acc[nf][nc][r] = bv;
        }

    auto issueB = [&](int ci, char* dst) {
        const unsigned short* src = wp + ((size_t)(oy * NCC + ci)) * (BFR * 512);
#pragma unroll
        for (int i = 0; i < BIT; ++i)
            __builtin_amdgcn_global_load_lds(
                (const AS1 void*)(src + (i * 256 + tid) * 8),
                (AS3 void*)(dst + (i * 256 + wv * 64) * 16),
                16, 0, 0);
    };
    unsigned ngoff[AIT], lby[AIT];
#pragma unroll
    for (int i = 0; i < AIT; ++i) {
        int it = i * 256 + tid;
        int n = it >> 2, g = it & 3;
        ngoff[i] = (unsigned)(n * CIN + g * 8);
        lby[i]   = (unsigned)(n * 128 + ((g ^ (n & 7)) << 4));
    }
    auto loadA = [&](int cc, uint4* vv) {
#pragma unroll
        for (int i = 0; i < AIT; ++i)
            vv[i] = *reinterpret_cast<const uint4*>(xb + cc * CC + ngoff[i]);
    };
    const f32x2 iv2 = {inv, inv}, nm2 = {nmi, nmi};
    auto storA = [&](char* wb, const uint4* vv) {
#pragma unroll
        for (int i = 0; i < AIT; ++i) {
            uint4 t = vv[i];
            unsigned int* pw = reinterpret_cast<unsigned int*>(&t);
#pragma unroll
            for (int q = 0; q < 4; ++q) {
                unsigned int u = pw[q];
                f32x2 sv, d;
                sv[0] = __uint_as_float(u << 16);
                sv[1] = __uint_as_float(u & 0xffff0000u);
                asm("v_pk_fma_f32 %0, %1, %2, %3" : "=v"(d) : "v"(sv), "v"(iv2), "v"(nm2));
                float f0 = fmaxf(d[0], 0.f);
                float f1 = fmaxf(d[1], 0.f);
                unsigned int r;
                asm("v_cvt_pk_bf16_f32 %0, %1, %2" : "=v"(r) : "v"(f0), "v"(f1));
                pw[q] = r;
            }
            *reinterpret_cast<uint4*>(wb + lby[i]) = t;
        }
    };

    uint4 v0[AIT], v1[AIT];

    issueB(0, gbuf + ABUF);
    loadA(0, v0);
    loadA(1, v1);
    storA(gbuf, v0);
    asm volatile("s_waitcnt lgkmcnt(0)" ::: "memory");
    __builtin_amdgcn_s_barrier();
    __builtin_amdgcn_sched_barrier(0);

#pragma unroll
    for (int cc = 0; cc < NCC; ++cc) {
        const int p = cc & 1;
        if (cc + 1 < NCC) {
            issueB(cc + 1, gbuf + (p ^ 1) * BUFB + ABUF);
            if (cc + 2 < NCC) loadA(cc + 2, (cc & 1) ? v1 : v0);
        }
        const char* ab = gbuf + p * BUFB;
        const char* bb = ab + ABUF;
        __builtin_amdgcn_s_setprio(1);
#pragma unroll
        for (int ks = 0; ks < 2; ++ks) {
            const unsigned s0 = (unsigned)(ks * 2 + lh2);
#pragma unroll
            for (int k = 0; k < 3; ++k) {
                short8 a0 = *reinterpret_cast<const short8*>(ab + aab[0][k] + ((s0 ^ axm[0][k]) << 4));
                short8 a1 = *reinterpret_cast<const short8*>(ab + aab[1][k] + ((s0 ^ axm[1][k]) << 4));
#pragma unroll
                for (int nc = 0; nc < 2; ++nc) {
                    short8 bf_ = *reinterpret_cast<const short8*>(
                        bb + (((k * 2 + ks) * 4 + wn * 2 + nc) << 10) + lane * 16);
                    acc[0][nc] = __builtin_amdgcn_mfma_f32_32x32x16_bf16(a0, bf_, acc[0][nc], 0, 0, 0);
                    acc[1][nc] = __builtin_amdgcn_mfma_f32_32x32x16_bf16(a1, bf_, acc[1][nc], 0, 0, 0);
                }
            }
        }
        __builtin_amdgcn_s_setprio(0);
        if (cc + 1 < NCC) storA(gbuf + (p ^ 1) * BUFB, (cc & 1) ? v0 : v1);

        if (cc + 1 < NCC) {
            if (cc + 2 < NCC) {
                asm volatile("s_waitcnt vmcnt(2) lgkmcnt(0)" ::: "memory");
            } else {
                asm volatile("s_waitcnt vmcnt(0) lgkmcnt(0)" ::: "memory");
            }
            __builtin_amdgcn_s_barrier();
            __builtin_amdgcn_sched_barrier(0);
        } else {
            asm volatile("s_waitcnt lgkmcnt(0)" ::: "memory");
            __builtin_amdgcn_s_barrier();
            __builtin_amdgcn_sched_barrier(0);
        }
    }

    // ---------------- epilogue ----------------
    float tsum = 0.f, tss = 0.f;

    if (COLMAX) {
        float m[2] = {-1e30f, -1e30f};
#pragma unroll
        for (int nf = 0; nf < 2; ++nf)
#pragma unroll
            for (int nc = 0; nc < 2; ++nc)
#pragma unroll
                for (int r = 0; r < 16; ++r) {
                    float val = acc[nf][nc][r];
                    tsum += val; tss += val * val;
                    m[nc] = fmaxf(m[nc], val);
                }
#pragma unroll
        for (int nc = 0; nc < 2; ++nc) m[nc] = fmaxf(m[nc], __shfl_xor(m[nc], 32));
        if (lh2 == 0) {
#pragma unroll
            for (int nc = 0; nc < 2; ++nc) cmax[wv][nc][l31] = m[nc];
        }
        __syncthreads();
        if (tid < 128) {
            const int c = tid;
            const int wn_ = (c >> 6) & 1, nc_ = (c >> 5) & 1, l_ = c & 31;
            float mm = fmaxf(cmax[wn_][nc_][l_], cmax[2 + wn_][nc_][l_]);
            colmax[b * COUT + c] = mm;
        }
    } else {
        unsigned int* yw = reinterpret_cast<unsigned int*>(yout);
#pragma unroll
        for (int nf = 0; nf < 2; ++nf)
#pragma unroll
            for (int r = 0; r < 16; ++r) {
                float v0_ = acc[nf][0][r], v1_ = acc[nf][1][r];
                tsum += v0_ + v1_;
                tss  += v0_ * v0_ + v1_ * v1_;
                unsigned int pk;
                asm("v_cvt_pk_bf16_f32 %0, %1, %2" : "=v"(pk) : "v"(v0_), "v"(v1_));
                int row = wm * 64 + nf * 32 + (r & 3) + 8 * (r >> 2) + 4 * lh2;
                yw[((size_t)b * NN + row) * (COUT / 2) + oy * 64 + wn * 32 + l31] = pk;
            }
    }

    // block stats reduction
#pragma unroll
    for (int ss = 32; ss; ss >>= 1) { tsum += __shfl_down(tsum, ss); tss += __shfl_down(tss, ss); }
    __syncthreads();
    if (lane == 0) { rbuf[wv * 2] = tsum; rbuf[wv * 2 + 1] = tss; }
    __syncthreads();
    if (tid == 0) {
        float sm = rbuf[0] + rbuf[2] + rbuf[4] + rbuf[6];
        float q = rbuf[1] + rbuf[3] + rbuf[5] + rbuf[7];
        int gid = oy * B + b;
        partials[2 * gid] = sm;
        partials[2 * gid + 1] = q;
    }
}

// ---------- finalize global layernorm stats ----------
__global__ __launch_bounds__(256) void stats_kernel(const float* __restrict__ partials,
                                                    float* __restrict__ stats,
                                                    int npart, double ntot)
{
    __shared__ double sd[256], sd2[256];
    double s = 0.0, s2 = 0.0;
    for (int i = threadIdx.x; i < npart; i += 256) { s += (double)partials[2 * i]; s2 += (double)partials[2 * i + 1]; }
    sd[threadIdx.x] = s; sd2[threadIdx.x] = s2;
    __syncthreads();
    for (int k = 128; k > 0; k >>= 1) {
        if (threadIdx.x < k) { sd[threadIdx.x] += sd[threadIdx.x + k]; sd2[threadIdx.x] += sd2[threadIdx.x + k]; }
        __syncthreads();
    }
    if (threadIdx.x == 0) {
        double mu = sd[0] / ntot;
        double var = (sd2[0] - sd[0] * sd[0] / ntot) / (ntot - 1.0);
        double sdv = sqrt(var > 0.0 ? var : 0.0);
        stats[0] = (float)mu;
        stats[1] = (float)(1.0 / (sdv + 1e-5));
    }
}

// ---------- heads from per-column max (raw) ----------
__global__ __launch_bounds__(128) void pool_head_kernel(const float* __restrict__ colmax,  // [B][128]
                                                        const float* __restrict__ stats,
                                                        const float* __restrict__ latw,
                                                        const float* __restrict__ latb,
                                                        const float* __restrict__ costw,
                                                        const float* __restrict__ costb,
                                                        float* __restrict__ out)
{
    const int b = blockIdx.x, t = threadIdx.x;
    const float mu = stats[0], inv = stats[1];
    const float pooled = fmaxf((colmax[b * 128 + t] - mu) * inv, 0.f);
    __shared__ float pl[128];
    pl[t] = pooled;
    __syncthreads();
    const float* w = (t < 64) ? latw : costw;
    const int l = t & 63;
    float v = pl[l] * w[l] + pl[l + 64] * w[l + 64];
#pragma unroll
    for (int s = 32; s > 0; s >>= 1) v += __shfl_down(v, s);
    if (l == 0) {
        const float bb = (t < 64) ? latb[0] : costb[0];
        out[(t < 64 ? 0 : B) + b] = 1.f / (1.f + expf(-(v + bb)));
    }
}

// ---------- launch ----------
extern "C" void kernel_launch(void* const* d_in, const int* in_sizes, int n_in,
                              void* d_out, int out_size, void* d_ws, size_t ws_size,
                              hipStream_t stream)
{
    (void)in_sizes; (void)n_in; (void)out_size; (void)ws_size;
    const float* trees   = (const float*)d_in[0];
    const int*   indexes = (const int*)  d_in[1];
    const float* enc_w   = (const float*)d_in[2];
    const float* enc_b   = (const float*)d_in[3];
    const float* w1 = (const float*)d_in[4];
    const float* b1 = (const float*)d_in[5];
    const float* w2 = (const float*)d_in[6];
    const float* b2 = (const float*)d_in[7];
    const float* w3 = (const float*)d_in[8];
    const float* b3 = (const float*)d_in[9];
    const float* lat_w  = (const float*)d_in[10];
    const float* lat_b  = (const float*)d_in[11];
    const float* cost_w = (const float*)d_in[12];
    const float* cost_b = (const float*)d_in[13];
    float* out = (float*)d_out;

    char* ws = (char*)d_ws;
    size_t off = 0;
    auto alloc = [&](size_t bytes) -> char* {
        char* p = ws + off;
        off += (bytes + 255) & ~(size_t)255;
        return p;
    };
    unsigned short* wpe  = (unsigned short*)alloc((size_t)320 * 128 * 2);
    unsigned short* wp1f = (unsigned short*)alloc((size_t)196608 * 2);
    unsigned short* wp2  = (unsigned short*)alloc((size_t)3 * 512 * 256 * 2);
    unsigned short* wp3  = (unsigned short*)alloc((size_t)3 * 256 * 128 * 2);
    unsigned short* y1   = (unsigned short*)alloc((size_t)B * NN * 512 * 2);
    unsigned short* y2   = (unsigned short*)alloc((size_t)B * NN * 256 * 2);
    float* colmax   = (float*)alloc((size_t)B * 128 * 4);
    float* partials = (float*)alloc((size_t)8192 * 2 * 4);
    float* stats    = (float*)alloc(8 * 4);

    prepack_w32<<<dim3((320 * 128 + 255) / 256), dim3(256), 0, stream>>>(enc_w, wpe, 1, 109, 318, 64, 128, 4, 5, 320);
    prepack_w1f<<<dim3(196608 / 256), dim3(256), 0, stream>>>(w1, wp1f);
    prepack_wB32<<<dim3((3 * 512 * 256) / 256), dim3(256), 0, stream>>>(w2, wp2, 256, 512, 512, 256);
    prepack_wB32<<<dim3((3 * 256 * 128) / 256), dim3(256), 0, stream>>>(w3, wp3, 128, 256, 256, 128);

    // FUSED encoder + conv1: trees -> y1 (permuted layout; x0 never leaves LDS)
    enc_conv1<<<dim3(B), dim3(256), 0, stream>>>(trees, indexes, wpe, enc_b, wp1f, b1, y1, partials);
    stats_kernel<<<dim3(1), dim3(256), 0, stream>>>(partials, stats + 0, 1024, (double)((size_t)B * 512 * NN));

    // conv2: output-stationary, OT=128, 2 o-tiles; permuted in/out
    conv_gemm<512, 2, 256, false>
        <<<dim3(B * 2), dim3(256), 0, stream>>>(y1, indexes, wp2, b2, stats + 0, y2, colmax, partials);
    stats_kernel<<<dim3(1), dim3(256), 0, stream>>>(partials, stats + 2, 2048, (double)((size_t)B * 256 * NN));

    // conv3: output-stationary, OT=128, colmax fused; permuted in
    conv_gemm<256, 1, 128, true>
        <<<dim3(B), dim3(256), 0, stream>>>(y2, indexes, wp3, b3, stats + 2, nullptr, colmax, partials);
    stats_kernel<<<dim3(1), dim3(256), 0, stream>>>(partials, stats + 4, 1024, (double)((size_t)B * 128 * NN));

    pool_head_kernel<<<dim3(B), dim3(128), 0, stream>>>(colmax, stats + 4, lat_w, lat_b, cost_w, cost_b, out);
}

// Round 18
// 294.405 us; speedup vs baseline: 1.3829x; 1.0567x over previous
//
#include <hip/hip_runtime.h>
#include <hip/hip_bf16.h>
#include <math.h>

using short8 = __attribute__((ext_vector_type(8))) short;
using f32x16 = __attribute__((ext_vector_type(16))) float;
using f32x2  = __attribute__((ext_vector_type(2))) float;

#define AS3 __attribute__((address_space(3)))
#define AS1 __attribute__((address_space(1)))

constexpr int B  = 1024;
constexpr int NN = 128;   // nodes per tree
constexpr int F  = 318;   // raw features

__device__ inline float bf2f(unsigned short u) {
    union { unsigned int i; float f; } x; x.i = ((unsigned int)u) << 16; return x.f;
}
__device__ inline unsigned short f2bf(float f) {
    union { float f; unsigned int i; } x; x.f = f;
    unsigned int r = x.i + 0x7fff + ((x.i >> 16) & 1);
    return (unsigned short)(r >> 16);
}

// ---------- ONE fused prepack kernel ----------
// seg0: wpe   [0, 40960)        encoder 32x32x16 B-frags (CC=64,KS=4,NCC=5,COUT=128,O=109,C=318)
// seg1: wp1f  [+196608)         conv1 half-ordered, POSITION-mapped channels
// seg2: wp2   [+393216)         conv2 CC=32 frags, perm-compensated input channels
// seg3: wp3   [+98304)          conv3 likewise
__global__ __launch_bounds__(256) void prepack_all(const float* __restrict__ enc_w,
                                                   const float* __restrict__ w1,
                                                   const float* __restrict__ w2,
                                                   const float* __restrict__ w3,
                                                   unsigned short* __restrict__ wpe,
                                                   unsigned short* __restrict__ wp1f,
                                                   unsigned short* __restrict__ wp2,
                                                   unsigned short* __restrict__ wp3)
{
    int t = blockIdx.x * 256 + threadIdx.x;
    if (t < 40960) {
        int j = t & 7;
        int lane = (t >> 3) & 63;
        int rest = t >> 9;                 // 0..79
        int ob = rest % 4;
        int kbg = rest / 4;                // 0..19
        int ks = kbg & 3;
        int cc = kbg >> 2;                 // 0..4
        int c = cc * 64 + ks * 16 + (lane >> 5) * 8 + j;
        int o = ob * 32 + (lane & 31);
        float v = (c < 318 && o < 109) ? enc_w[(size_t)o * 318 + c] : 0.f;
        wpe[t] = f2bf(v);
        return;
    }
    t -= 40960;
    if (t < 196608) {
        int j = t & 7;
        int lane = (t >> 3) & 63;
        int r = t >> 9;                    // 0..383
        int fp = r % 48;
        int oy = r / 48;
        int h   = fp / 24;
        int rem = fp % 24;
        int obp = rem & 1;
        int q   = rem >> 1;                // 0..11
        int ks2 = q & 3;
        int k   = q >> 2;
        int ks  = h * 4 + ks2;
        int p = ks * 16 + (lane >> 5) * 8 + j;                       // position 0..127
        int c = (p & 64) + ((p & 63) >> 1) + ((p & 1) << 5);         // permuted channel
        int o = oy * 64 + obp * 32 + (lane & 31);
        float v = (c < 109) ? w1[((size_t)o * 109 + c) * 3 + k] : 0.f;
        wp1f[t] = f2bf(v);
        return;
    }
    t -= 196608;
    if (t < 393216) {
        const int NCC = 16;                // 512/32
        int j = t & 7;
        int lane = (t >> 3) & 63;
        int r = t >> 9;
        int cb = r & 3; r >>= 2;
        int ks = r & 1; r >>= 1;
        int k = r % 3; r /= 3;
        int ci = r % NCC;
        int oy = r / NCC;
        int pos = ci * 32 + ks * 16 + (lane >> 5) * 8 + j;
        int c = (pos & ~63) | ((pos & 1) << 5) | ((pos >> 1) & 31);
        int o = oy * 128 + cb * 32 + (lane & 31);
        float v = (c < 512 && o < 256) ? w2[((size_t)o * 512 + c) * 3 + k] : 0.f;
        wp2[t] = f2bf(v);
        return;
    }
    t -= 393216;
    if (t < 98304) {
        const int NCC = 8;                 // 256/32
        int j = t & 7;
        int lane = (t >> 3) & 63;
        int r = t >> 9;
        int cb = r & 3; r >>= 2;
        int ks = r & 1; r >>= 1;
        int k = r % 3; r /= 3;
        int ci = r % NCC;
        int oy = r / NCC;
        int pos = ci * 32 + ks * 16 + (lane >> 5) * 8 + j;
        int c = (pos & ~63) | ((pos & 1) << 5) | ((pos >> 1) & 31);
        int o = oy * 128 + cb * 32 + (lane & 31);
        float v = (c < 256 && o < 128) ? w3[((size_t)o * 256 + c) * 3 + k] : 0.f;
        wp3[t] = f2bf(v);
    }
}

// ---------- FUSED encoder + conv1 ----------
__global__ __launch_bounds__(256, 2) void enc_conv1(const float* __restrict__ trees,
                                                    const int* __restrict__ idx,
                                                    const unsigned short* __restrict__ wpe,
                                                    const float* __restrict__ encb,
                                                    const unsigned short* __restrict__ wp1,
                                                    const float* __restrict__ b1,
                                                    unsigned short* __restrict__ y1,   // [B][NN][512] permuted
                                                    float* __restrict__ partials)
{
    __shared__ __align__(16) char gbuf[81920];
    char* Xt = gbuf;               // 32KB x0 tile, PERMUTED positions (persistent in phase 2)
    char* W  = gbuf + 32768;       // 48KB: enc staging dbuf / conv1 B halves

    const int b = blockIdx.x;
    const int tid = threadIdx.x;
    const int lane = tid & 63;
    const int wv = tid >> 6;
    const int l31 = lane & 31, lh2 = lane >> 5;

    // ---------------- phase 1: encoder ----------------
    {
        constexpr int CC = 64, NCH = 5, KS = 4, NB = 4;
        constexpr int BUFB = NN * CC * 2;   // 16 KB
        const int cp = tid >> 3;            // channel pair 0..31
        const int ng = tid & 7;             // node group of 16

        float4 va[4], vb[4];
        auto load = [&](int ch) {
            const int c0 = ch * CC + 2 * cp, c1 = c0 + 1;
            const bool k0 = (c0 < F), k1 = (c1 < F);
            const float* s0 = trees + ((size_t)b * F + c0) * NN + ng * 16;
            const float* s1 = s0 + NN;
#pragma unroll
            for (int j = 0; j < 4; ++j) {
                va[j] = k0 ? *reinterpret_cast<const float4*>(s0 + j * 4) : make_float4(0.f, 0.f, 0.f, 0.f);
                vb[j] = k1 ? *reinterpret_cast<const float4*>(s1 + j * 4) : make_float4(0.f, 0.f, 0.f, 0.f);
            }
        };
        const int gsw = cp >> 2;            // (2cp)>>3
        const int cby = (cp & 3) * 4;       // ((2cp)&7)*2
        auto stor = [&](char* wb) {
            const float* fa = reinterpret_cast<const float*>(va);
            const float* fb = reinterpret_cast<const float*>(vb);
#pragma unroll
            for (int i = 0; i < 16; ++i) {
                const int n = ng * 16 + i;
                unsigned int pk;
                asm("v_cvt_pk_bf16_f32 %0, %1, %2" : "=v"(pk) : "v"(fa[i]), "v"(fb[i]));
                int byte = n * 128 + (((gsw ^ (n & 7) ^ ng) << 4) + cby);
                *reinterpret_cast<unsigned int*>(wb + byte) = pk;
            }
        };

        f32x16 acc[NB];
#pragma unroll
        for (int ob = 0; ob < NB; ++ob) acc[ob] = (f32x16)0.f;

        const int nrow = wv * 32 + l31;
        const unsigned abyte = (unsigned)(nrow * 128);
        const unsigned axor = (unsigned)(((nrow & 7) ^ ((nrow >> 4) & 7)) << 4);

        load(0); stor(W);
        __syncthreads();

        int p = 0;
#pragma unroll
        for (int ch = 0; ch < NCH; ++ch) {
            if (ch + 1 < NCH) load(ch + 1);
            const char* base = W + p * BUFB;
            __builtin_amdgcn_s_setprio(1);
#pragma unroll
            for (int ks = 0; ks < KS; ++ks) {
                const int kbg = ch * KS + ks;
                short8 a = *reinterpret_cast<const short8*>(
                    base + abyte + (((unsigned)((ks * 2 + lh2) << 4)) ^ axor));
                const unsigned short* wb_ = wpe + ((size_t)(kbg * 4) * 64 + lane) * 8;
#pragma unroll
                for (int ob = 0; ob < NB; ++ob) {
                    short8 bf_ = *reinterpret_cast<const short8*>(wb_ + ob * 512);
                    acc[ob] = __builtin_amdgcn_mfma_f32_32x32x16_bf16(a, bf_, acc[ob], 0, 0, 0);
                }
            }
            __builtin_amdgcn_s_setprio(0);
            if (ch + 1 < NCH) stor(W + (p ^ 1) * BUFB);
            __syncthreads();
            p ^= 1;
        }

        // epilogue -> Xt, PERMUTED pair writes (b32, conflict-free)
        float bs[NB];
#pragma unroll
        for (int ob = 0; ob < NB; ++ob) {
            int c = ob * 32 + l31;
            bs[ob] = (c < 109) ? encb[c] : 0.f;
        }
#pragma unroll
        for (int r = 0; r < 16; ++r) {
            const int row = wv * 32 + (r & 3) + 8 * (r >> 2) + 4 * lh2;
            unsigned int pk0, pk1;
            float a0 = acc[0][r] + bs[0], a1 = acc[1][r] + bs[1];
            float a2 = acc[2][r] + bs[2], a3 = acc[3][r] + bs[3];
            asm("v_cvt_pk_bf16_f32 %0, %1, %2" : "=v"(pk0) : "v"(a0), "v"(a1));
            asm("v_cvt_pk_bf16_f32 %0, %1, %2" : "=v"(pk1) : "v"(a2), "v"(a3));
            int by0 = row * 256 + ((((l31 >> 2) ^ (row & 15)) << 4) | ((l31 & 3) * 4));
            int by1 = row * 256 + ((((8 + (l31 >> 2)) ^ (row & 15)) << 4) | ((l31 & 3) * 4));
            *reinterpret_cast<unsigned int*>(Xt + by0) = pk0;
            *reinterpret_cast<unsigned int*>(Xt + by1) = pk1;
        }
        __syncthreads();
    }

    // ---------------- phase 2: conv1, output-stationary, correct counted-vmcnt pipeline ----------------
    const int nrowA = wv * 32 + l31;
    unsigned aab[3], axm[3];
#pragma unroll
    for (int k = 0; k < 3; ++k) {
        int s_ = idx[b * 3 * NN + 3 * nrowA + k];
        aab[k] = (unsigned)(s_ * 256);
        axm[k] = (unsigned)(s_ & 15);
    }

    char* bufs[2] = {W, W + 24576};
    auto issueBh = [&](int ht) {
        const unsigned short* src = wp1 + (size_t)ht * 24 * 512;
        char* dst = bufs[ht & 1];
#pragma unroll
        for (int i = 0; i < 6; ++i)
            __builtin_amdgcn_global_load_lds(
                (const AS1 void*)(src + (i * 256 + tid) * 8),
                (AS3 void*)(dst + (i * 256 + wv * 64) * 16),
                16, 0, 0);
    };

    unsigned int* y1w = reinterpret_cast<unsigned int*>(y1);
    float tsum = 0.f, tss = 0.f;

    issueBh(0);
    issueBh(1);
    asm volatile("s_waitcnt vmcnt(6)" ::: "memory");   // chunk0 ready, chunk1 in flight
    __builtin_amdgcn_s_barrier();
    __builtin_amdgcn_sched_barrier(0);

    f32x16 acc[2];
#pragma unroll 1
    for (int ht = 0; ht < 16; ++ht) {
        const int h = ht & 1, oy = ht >> 1;
        const char* bp = bufs[h];
        if (h == 0) {
#pragma unroll
            for (int obp = 0; obp < 2; ++obp) {
                const float bv = b1[oy * 64 + obp * 32 + l31];
#pragma unroll
                for (int r = 0; r < 16; ++r) acc[obp][r] = bv;
            }
        }
        __builtin_amdgcn_s_setprio(1);
#pragma unroll
        for (int ks2 = 0; ks2 < 4; ++ks2) {
#pragma unroll
            for (int k = 0; k < 3; ++k) {
                const unsigned slot = ((unsigned)((h * 4 + ks2) * 2 + lh2)) ^ axm[k];
                short8 a = *reinterpret_cast<const short8*>(Xt + aab[k] + (slot << 4));
#pragma unroll
                for (int obp = 0; obp < 2; ++obp) {
                    short8 bf_ = *reinterpret_cast<const short8*>(
                        bp + (((k * 4 + ks2) * 2 + obp) << 10) + lane * 16);
                    acc[obp] = __builtin_amdgcn_mfma_f32_32x32x16_bf16(a, bf_, acc[obp], 0, 0, 0);
                }
            }
        }
        __builtin_amdgcn_s_setprio(0);

        if (h == 1) {
            // stats + permuted dword stores (16 global stores)
#pragma unroll
            for (int r = 0; r < 16; ++r) {
                float v0_ = acc[0][r], v1_ = acc[1][r];
                tsum += v0_ + v1_;
                tss  += v0_ * v0_ + v1_ * v1_;
                unsigned int pk;
                asm("v_cvt_pk_bf16_f32 %0, %1, %2" : "=v"(pk) : "v"(v0_), "v"(v1_));
                int row = wv * 32 + (r & 3) + 8 * (r >> 2) + 4 * lh2;
                y1w[((size_t)b * NN + row) * 256 + oy * 32 + l31] = pk;
            }
        }

        if (ht + 1 < 16) {
            __builtin_amdgcn_s_barrier();            // all waves done reading buf[ht&1]
            if (ht + 2 < 16) {
                issueBh(ht + 2);                     // 6 loads into freed buffer
                // wait for chunk ht+1: ops issued after it = (stores if h==1) + 6 new loads
                if (h == 1) { asm volatile("s_waitcnt vmcnt(22)" ::: "memory"); }
                else        { asm volatile("s_waitcnt vmcnt(6)"  ::: "memory"); }
            } else {
                asm volatile("s_waitcnt vmcnt(0)" ::: "memory");
            }
            __builtin_amdgcn_sched_barrier(0);
        }
    }

    __syncthreads();
    float* rbuf = reinterpret_cast<float*>(W);
#pragma unroll
    for (int ss = 32; ss; ss >>= 1) { tsum += __shfl_down(tsum, ss); tss += __shfl_down(tss, ss); }
    if (lane == 0) { rbuf[wv * 2] = tsum; rbuf[wv * 2 + 1] = tss; }
    __syncthreads();
    if (tid == 0) {
        float sm = rbuf[0] + rbuf[2] + rbuf[4] + rbuf[6];
        float q = rbuf[1] + rbuf[3] + rbuf[5] + rbuf[7];
        partials[2 * b] = sm;
        partials[2 * b + 1] = q;
    }
}

// ---------- conv2/conv3: output-stationary, A-side LDS gather, OT=128, CC=32 (R17, unchanged) ----------
template <int CIN, int OTN, int COUT, bool COLMAX>
__global__ __launch_bounds__(256, 2) void conv_gemm(const unsigned short* __restrict__ xin,
                                                    const int* __restrict__ idx,
                                                    const unsigned short* __restrict__ wp,
                                                    const float* __restrict__ bias,
                                                    const float* __restrict__ stats,
                                                    unsigned short* __restrict__ yout,
                                                    float* __restrict__ colmax,
                                                    float* __restrict__ partials)
{
    constexpr int CC    = 32;
    constexpr int NCC   = CIN / CC;
    constexpr int AIT   = 2;
    constexpr int ABUF  = NN * 128;
    constexpr int BFR   = 2 * 3 * 4;
    constexpr int BBUF  = BFR * 1024;
    constexpr int BIT   = 6;
    constexpr int BUFB  = ABUF + BBUF;

    __shared__ __align__(16) char gbuf[81920];
    float (*cmax)[2][32] = reinterpret_cast<float (*)[2][32]>(gbuf + 79872);
    float* rbuf = reinterpret_cast<float*>(gbuf + 81408);

    const int f  = blockIdx.x;
    const int s  = f >> 3;
    const int b  = (f & 7) + 8 * (s / OTN);
    const int oy = s % OTN;

    const int tid = threadIdx.x;
    const int lane = tid & 63;
    const int wv = tid >> 6;
    const int wm = wv >> 1, wn = wv & 1;
    const int l31 = lane & 31, lh2 = lane >> 5;

    const float mu = stats[0], inv = stats[1];
    const float nmi = -mu * inv;

    const unsigned short* xb = xin + (size_t)b * NN * CIN;

    unsigned aab[2][3], axm[2][3];
#pragma unroll
    for (int nf = 0; nf < 2; ++nf) {
        const int n = wm * 64 + nf * 32 + l31;
#pragma unroll
        for (int k = 0; k < 3; ++k) {
            int s_ = idx[b * 3 * NN + 3 * n + k];
            aab[nf][k] = (unsigned)(s_ * 128);
            axm[nf][k] = (unsigned)(s_ & 7);
        }
    }

    f32x16 acc[2][2];
#pragma unroll
    for (int nf = 0; nf < 2; ++nf)
#pragma unroll
        for (int nc = 0; nc < 2; ++nc) {
            const float bv = bias[oy * 128 + wn * 64 + nc * 32 + l31];
#pragma unroll
            for (int r = 0; r < 16; ++r) acc[nf][nc][r] = bv;
        }

    auto issueB = [&](int ci, char* dst) {
        const unsigned short* src = wp + ((size_t)(oy * NCC + ci)) * (BFR * 512);
#pragma unroll
        for (int i = 0; i < BIT; ++i)
            __builtin_amdgcn_global_load_lds(
                (const AS1 void*)(src + (i * 256 + tid) * 8),
                (AS3 void*)(dst + (i * 256 + wv * 64) * 16),
                16, 0, 0);
    };
    unsigned ngoff[AIT], lby[AIT];
#pragma unroll
    for (int i = 0; i < AIT; ++i) {
        int it = i * 256 + tid;
        int n = it >> 2, g = it & 3;
        ngoff[i] = (unsigned)(n * CIN + g * 8);
        lby[i]   = (unsigned)(n * 128 + ((g ^ (n & 7)) << 4));
    }
    auto loadA = [&](int cc, uint4* vv) {
#pragma unroll
        for (int i = 0; i < AIT; ++i)
            vv[i] = *reinterpret_cast<const uint4*>(xb + cc * CC + ngoff[i]);
    };
    const f32x2 iv2 = {inv, inv}, nm2 = {nmi, nmi};
    auto storA = [&](char* wb, const uint4* vv) {
#pragma unroll
        for (int i = 0; i < AIT; ++i) {
            uint4 t = vv[i];
            unsigned int* pw = reinterpret_cast<unsigned int*>(&t);
#pragma unroll
            for (int q = 0; q < 4; ++q) {
                unsigned int u = pw[q];
                f32x2 sv, d;
                sv[0] = __uint_as_float(u << 16);
                sv[1] = __uint_as_float(u & 0xffff0000u);
                asm("v_pk_fma_f32 %0, %1, %2, %3" : "=v"(d) : "v"(sv), "v"(iv2), "v"(nm2));
                float f0 = fmaxf(d[0], 0.f);
                float f1 = fmaxf(d[1], 0.f);
                unsigned int r;
                asm("v_cvt_pk_bf16_f32 %0, %1, %2" : "=v"(r) : "v"(f0), "v"(f1));
                pw[q] = r;
            }
            *reinterpret_cast<uint4*>(wb + lby[i]) = t;
        }
    };

    uint4 v0[AIT], v1[AIT];

    issueB(0, gbuf + ABUF);
    loadA(0, v0);
    loadA(1, v1);
    storA(gbuf, v0);
    asm volatile("s_waitcnt lgkmcnt(0)" ::: "memory");
    __builtin_amdgcn_s_barrier();
    __builtin_amdgcn_sched_barrier(0);

#pragma unroll
    for (int cc = 0; cc < NCC; ++cc) {
        const int p = cc & 1;
        if (cc + 1 < NCC) {
            issueB(cc + 1, gbuf + (p ^ 1) * BUFB + ABUF);
            if (cc + 2 < NCC) loadA(cc + 2, (cc & 1) ? v1 : v0);
        }
        const char* ab = gbuf + p * BUFB;
        const char* bb = ab + ABUF;
        __builtin_amdgcn_s_setprio(1);
#pragma unroll
        for (int ks = 0; ks < 2; ++ks) {
            const unsigned s0 = (unsigned)(ks * 2 + lh2);
#pragma unroll
            for (int k = 0; k < 3; ++k) {
                short8 a0 = *reinterpret_cast<const short8*>(ab + aab[0][k] + ((s0 ^ axm[0][k]) << 4));
                short8 a1 = *reinterpret_cast<const short8*>(ab + aab[1][k] + ((s0 ^ axm[1][k]) << 4));
#pragma unroll
                for (int nc = 0; nc < 2; ++nc) {
                    short8 bf_ = *reinterpret_cast<const short8*>(
                        bb + (((k * 2 + ks) * 4 + wn * 2 + nc) << 10) + lane * 16);
                    acc[0][nc] = __builtin_amdgcn_mfma_f32_32x32x16_bf16(a0, bf_, acc[0][nc], 0, 0, 0);
                    acc[1][nc] = __builtin_amdgcn_mfma_f32_32x32x16_bf16(a1, bf_, acc[1][nc], 0, 0, 0);
                }
            }
        }
        __builtin_amdgcn_s_setprio(0);
        if (cc + 1 < NCC) storA(gbuf + (p ^ 1) * BUFB, (cc & 1) ? v0 : v1);

        if (cc + 1 < NCC) {
            if (cc + 2 < NCC) {
                asm volatile("s_waitcnt vmcnt(2) lgkmcnt(0)" ::: "memory");
            } else {
                asm volatile("s_waitcnt vmcnt(0) lgkmcnt(0)" ::: "memory");
            }
            __builtin_amdgcn_s_barrier();
            __builtin_amdgcn_sched_barrier(0);
        } else {
            asm volatile("s_waitcnt lgkmcnt(0)" ::: "memory");
            __builtin_amdgcn_s_barrier();
            __builtin_amdgcn_sched_barrier(0);
        }
    }

    float tsum = 0.f, tss = 0.f;

    if (COLMAX) {
        float m[2] = {-1e30f, -1e30f};
#pragma unroll
        for (int nf = 0; nf < 2; ++nf)
#pragma unroll
            for (int nc = 0; nc < 2; ++nc)
#pragma unroll
                for (int r = 0; r < 16; ++r) {
                    float val = acc[nf][nc][r];
                    tsum += val; tss += val * val;
                    m[nc] = fmaxf(m[nc], val);
                }
#pragma unroll
        for (int nc = 0; nc < 2; ++nc) m[nc] = fmaxf(m[nc], __shfl_xor(m[nc], 32));
        if (lh2 == 0) {
#pragma unroll
            for (int nc = 0; nc < 2; ++nc) cmax[wv][nc][l31] = m[nc];
        }
        __syncthreads();
        if (tid < 128) {
            const int c = tid;
            const int wn_ = (c >> 6) & 1, nc_ = (c >> 5) & 1, l_ = c & 31;
            float mm = fmaxf(cmax[wn_][nc_][l_], cmax[2 + wn_][nc_][l_]);
            colmax[b * COUT + c] = mm;
        }
    } else {
        unsigned int* yw = reinterpret_cast<unsigned int*>(yout);
#pragma unroll
        for (int nf = 0; nf < 2; ++nf)
#pragma unroll
            for (int r = 0; r < 16; ++r) {
                float v0_ = acc[nf][0][r], v1_ = acc[nf][1][r];
                tsum += v0_ + v1_;
                tss  += v0_ * v0_ + v1_ * v1_;
                unsigned int pk;
                asm("v_cvt_pk_bf16_f32 %0, %1, %2" : "=v"(pk) : "v"(v0_), "v"(v1_));
                int row = wm * 64 + nf * 32 + (r & 3) + 8 * (r >> 2) + 4 * lh2;
                yw[((size_t)b * NN + row) * (COUT / 2) + oy * 64 + wn * 32 + l31] = pk;
            }
    }

#pragma unroll
    for (int ss = 32; ss; ss >>= 1) { tsum += __shfl_down(tsum, ss); tss += __shfl_down(tss, ss); }
    __syncthreads();
    if (lane == 0) { rbuf[wv * 2] = tsum; rbuf[wv * 2 + 1] = tss; }
    __syncthreads();
    if (tid == 0) {
        float sm = rbuf[0] + rbuf[2] + rbuf[4] + rbuf[6];
        float q = rbuf[1] + rbuf[3] + rbuf[5] + rbuf[7];
        int gid = oy * B + b;
        partials[2 * gid] = sm;
        partials[2 * gid + 1] = q;
    }
}

// ---------- finalize global layernorm stats ----------
__global__ __launch_bounds__(256) void stats_kernel(const float* __restrict__ partials,
                                                    float* __restrict__ stats,
                                                    int npart, double ntot)
{
    __shared__ double sd[256], sd2[256];
    double s = 0.0, s2 = 0.0;
    for (int i = threadIdx.x; i < npart; i += 256) { s += (double)partials[2 * i]; s2 += (double)partials[2 * i + 1]; }
    sd[threadIdx.x] = s; sd2[threadIdx.x] = s2;
    __syncthreads();
    for (int k = 128; k > 0; k >>= 1) {
        if (threadIdx.x < k) { sd[threadIdx.x] += sd[threadIdx.x + k]; sd2[threadIdx.x] += sd2[threadIdx.x + k]; }
        __syncthreads();
    }
    if (threadIdx.x == 0) {
        double mu = sd[0] / ntot;
        double var = (sd2[0] - sd[0] * sd[0] / ntot) / (ntot - 1.0);
        double sdv = sqrt(var > 0.0 ? var : 0.0);
        stats[0] = (float)mu;
        stats[1] = (float)(1.0 / (sdv + 1e-5));
    }
}

// ---------- pool + heads WITH fused conv3-stats (per-block redundant reduce) ----------
__global__ __launch_bounds__(256) void pool_head_kernel(const float* __restrict__ partials, // conv3 partials [1024][2]
                                                        const float* __restrict__ colmax,   // [B][128]
                                                        const float* __restrict__ latw,
                                                        const float* __restrict__ latb,
                                                        const float* __restrict__ costw,
                                                        const float* __restrict__ costb,
                                                        float* __restrict__ out)
{
    __shared__ double sd[256], sd2[256];
    __shared__ float pl[128];
    __shared__ float st[2];
    const int b = blockIdx.x, t = threadIdx.x;

    double s = 0.0, s2 = 0.0;
#pragma unroll
    for (int i = 0; i < 4; ++i) {
        int p = t + i * 256;
        s  += (double)partials[2 * p];
        s2 += (double)partials[2 * p + 1];
    }
    sd[t] = s; sd2[t] = s2;
    __syncthreads();
    for (int k = 128; k > 0; k >>= 1) {
        if (t < k) { sd[t] += sd[t + k]; sd2[t] += sd2[t + k]; }
        __syncthreads();
    }
    if (t == 0) {
        const double ntot = 16777216.0;   // B*128*NN
        double mu = sd[0] / ntot;
        double var = (sd2[0] - sd[0] * sd[0] / ntot) / (ntot - 1.0);
        double sdv = sqrt(var > 0.0 ? var : 0.0);
        st[0] = (float)mu;
        st[1] = (float)(1.0 / (sdv + 1e-5));
    }
    __syncthreads();
    const float mu = st[0], inv = st[1];

    if (t < 128) pl[t] = fmaxf((colmax[b * 128 + t] - mu) * inv, 0.f);
    __syncthreads();
    if (t < 128) {
        const float* w = (t < 64) ? latw : costw;
        const int l = t & 63;
        float v = pl[l] * w[l] + pl[l + 64] * w[l + 64];
#pragma unroll
        for (int s_ = 32; s_ > 0; s_ >>= 1) v += __shfl_down(v, s_);
        if (l == 0) {
            const float bb = (t < 64) ? latb[0] : costb[0];
            out[(t < 64 ? 0 : B) + b] = 1.f / (1.f + expf(-(v + bb)));
        }
    }
}

// ---------- launch ----------
extern "C" void kernel_launch(void* const* d_in, const int* in_sizes, int n_in,
                              void* d_out, int out_size, void* d_ws, size_t ws_size,
                              hipStream_t stream)
{
    (void)in_sizes; (void)n_in; (void)out_size; (void)ws_size;
    const float* trees   = (const float*)d_in[0];
    const int*   indexes = (const int*)  d_in[1];
    const float* enc_w   = (const float*)d_in[2];
    const float* enc_b   = (const float*)d_in[3];
    const float* w1 = (const float*)d_in[4];
    const float* b1 = (const float*)d_in[5];
    const float* w2 = (const float*)d_in[6];
    const float* b2 = (const float*)d_in[7];
    const float* w3 = (const float*)d_in[8];
    const float* b3 = (const float*)d_in[9];
    const float* lat_w  = (const float*)d_in[10];
    const float* lat_b  = (const float*)d_in[11];
    const float* cost_w = (const float*)d_in[12];
    const float* cost_b = (const float*)d_in[13];
    float* out = (float*)d_out;

    char* ws = (char*)d_ws;
    size_t off = 0;
    auto alloc = [&](size_t bytes) -> char* {
        char* p = ws + off;
        off += (bytes + 255) & ~(size_t)255;
        return p;
    };
    unsigned short* wpe  = (unsigned short*)alloc((size_t)40960 * 2);
    unsigned short* wp1f = (unsigned short*)alloc((size_t)196608 * 2);
    unsigned short* wp2  = (unsigned short*)alloc((size_t)393216 * 2);
    unsigned short* wp3  = (unsigned short*)alloc((size_t)98304 * 2);
    unsigned short* y1   = (unsigned short*)alloc((size_t)B * NN * 512 * 2);
    unsigned short* y2   = (unsigned short*)alloc((size_t)B * NN * 256 * 2);
    float* colmax   = (float*)alloc((size_t)B * 128 * 4);
    float* partials = (float*)alloc((size_t)8192 * 2 * 4);
    float* stats    = (float*)alloc(8 * 4);

    float* part1 = partials;              // enc_conv1: 1024 pairs
    float* part2 = partials + 2048 * 2;   // conv2: 2048 pairs
    float* part3 = partials + 6144 * 2;   // conv3: 1024 pairs

    prepack_all<<<dim3(2848), dim3(256), 0, stream>>>(enc_w, w1, w2, w3, wpe, wp1f, wp2, wp3);

    // FUSED encoder + conv1 (permuted y1; x0 never leaves LDS)
    enc_conv1<<<dim3(B), dim3(256), 0, stream>>>(trees, indexes, wpe, enc_b, wp1f, b1, y1, part1);
    stats_kernel<<<dim3(1), dim3(256), 0, stream>>>(part1, stats + 0, 1024, (double)((size_t)B * 512 * NN));

    // conv2: output-stationary, OT=128, 2 o-tiles; permuted in/out
    conv_gemm<512, 2, 256, false>
        <<<dim3(B * 2), dim3(256), 0, stream>>>(y1, indexes, wp2, b2, stats + 0, y2, colmax, part2);
    stats_kernel<<<dim3(1), dim3(256), 0, stream>>>(part2, stats + 2, 2048, (double)((size_t)B * 256 * NN));

    // conv3: output-stationary, OT=128, colmax fused; permuted in
    conv_gemm<256, 1, 128, true>
        <<<dim3(B), dim3(256), 0, stream>>>(y2, indexes, wp3, b3, stats + 2, nullptr, colmax, part3);

    // pool + heads with fused conv3 stats
    pool_head_kernel<<<dim3(B), dim3(256), 0, stream>>>(part3, colmax, lat_w, lat_b, cost_w, cost_b, out);
}

// Round 19
// 270.996 us; speedup vs baseline: 1.5023x; 1.0864x over previous
//
#include <hip/hip_runtime.h>
#include <hip/hip_bf16.h>
#include <math.h>

using short8 = __attribute__((ext_vector_type(8))) short;
using f32x16 = __attribute__((ext_vector_type(16))) float;
using f32x2  = __attribute__((ext_vector_type(2))) float;

#define AS3 __attribute__((address_space(3)))
#define AS1 __attribute__((address_space(1)))

constexpr int B  = 1024;
constexpr int NN = 128;   // nodes per tree
constexpr int F  = 318;   // raw features

__device__ inline float bf2f(unsigned short u) {
    union { unsigned int i; float f; } x; x.i = ((unsigned int)u) << 16; return x.f;
}
__device__ inline unsigned short f2bf(float f) {
    union { float f; unsigned int i; } x; x.f = f;
    unsigned int r = x.i + 0x7fff + ((x.i >> 16) & 1);
    return (unsigned short)(r >> 16);
}

// ---------- ONE fused prepack kernel ----------
__global__ __launch_bounds__(256) void prepack_all(const float* __restrict__ enc_w,
                                                   const float* __restrict__ w1,
                                                   const float* __restrict__ w2,
                                                   const float* __restrict__ w3,
                                                   unsigned short* __restrict__ wpe,
                                                   unsigned short* __restrict__ wp1f,
                                                   unsigned short* __restrict__ wp2,
                                                   unsigned short* __restrict__ wp3)
{
    int t = blockIdx.x * 256 + threadIdx.x;
    if (t < 40960) {
        int j = t & 7;
        int lane = (t >> 3) & 63;
        int rest = t >> 9;                 // 0..79
        int ob = rest % 4;
        int kbg = rest / 4;                // 0..19
        int ks = kbg & 3;
        int cc = kbg >> 2;                 // 0..4
        int c = cc * 64 + ks * 16 + (lane >> 5) * 8 + j;
        int o = ob * 32 + (lane & 31);
        float v = (c < 318 && o < 109) ? enc_w[(size_t)o * 318 + c] : 0.f;
        wpe[t] = f2bf(v);
        return;
    }
    t -= 40960;
    if (t < 196608) {
        int j = t & 7;
        int lane = (t >> 3) & 63;
        int r = t >> 9;                    // 0..383
        int fp = r % 48;
        int oy = r / 48;
        int h   = fp / 24;
        int rem = fp % 24;
        int obp = rem & 1;
        int q   = rem >> 1;                // 0..11
        int ks2 = q & 3;
        int k   = q >> 2;
        int ks  = h * 4 + ks2;
        int p = ks * 16 + (lane >> 5) * 8 + j;                       // position 0..127
        int c = (p & 64) + ((p & 63) >> 1) + ((p & 1) << 5);         // permuted channel
        int o = oy * 64 + obp * 32 + (lane & 31);
        float v = (c < 109) ? w1[((size_t)o * 109 + c) * 3 + k] : 0.f;
        wp1f[t] = f2bf(v);
        return;
    }
    t -= 196608;
    if (t < 393216) {
        const int NCC = 16;                // 512/32
        int j = t & 7;
        int lane = (t >> 3) & 63;
        int r = t >> 9;
        int cb = r & 3; r >>= 2;
        int ks = r & 1; r >>= 1;
        int k = r % 3; r /= 3;
        int ci = r % NCC;
        int oy = r / NCC;
        int pos = ci * 32 + ks * 16 + (lane >> 5) * 8 + j;
        int c = (pos & ~63) | ((pos & 1) << 5) | ((pos >> 1) & 31);
        int o = oy * 128 + cb * 32 + (lane & 31);
        float v = (c < 512 && o < 256) ? w2[((size_t)o * 512 + c) * 3 + k] : 0.f;
        wp2[t] = f2bf(v);
        return;
    }
    t -= 393216;
    if (t < 98304) {
        const int NCC = 8;                 // 256/32
        int j = t & 7;
        int lane = (t >> 3) & 63;
        int r = t >> 9;
        int cb = r & 3; r >>= 2;
        int ks = r & 1; r >>= 1;
        int k = r % 3; r /= 3;
        int ci = r % NCC;
        int oy = r / NCC;
        int pos = ci * 32 + ks * 16 + (lane >> 5) * 8 + j;
        int c = (pos & ~63) | ((pos & 1) << 5) | ((pos >> 1) & 31);
        int o = oy * 128 + cb * 32 + (lane & 31);
        float v = (c < 256 && o < 128) ? w3[((size_t)o * 256 + c) * 3 + k] : 0.f;
        wp3[t] = f2bf(v);
    }
}

// ---------- FUSED encoder + conv1 ----------
// Phase 1: x0[b] -> Xt (32KB, permuted pair layout). Phase 2: conv1 output-stationary,
// ALL 24 gathered A-frags hoisted to registers (read once), B in 24KB half-tiles,
// stores decoupled from load-waits (issued after barrier, behind awaited loads in FIFO).
__global__ __launch_bounds__(256, 2) void enc_conv1(const float* __restrict__ trees,
                                                    const int* __restrict__ idx,
                                                    const unsigned short* __restrict__ wpe,
                                                    const float* __restrict__ encb,
                                                    const unsigned short* __restrict__ wp1,
                                                    const float* __restrict__ b1,
                                                    unsigned short* __restrict__ y1,   // [B][NN][512] permuted
                                                    float* __restrict__ partials)
{
    __shared__ __align__(16) char gbuf[81920];
    char* Xt = gbuf;               // 32KB x0 tile, PERMUTED positions
    char* W  = gbuf + 32768;       // 48KB: enc staging dbuf / conv1 B halves

    const int b = blockIdx.x;
    const int tid = threadIdx.x;
    const int lane = tid & 63;
    const int wv = tid >> 6;
    const int l31 = lane & 31, lh2 = lane >> 5;

    // ---------------- phase 1: encoder ----------------
    {
        constexpr int CC = 64, NCH = 5, KS = 4, NB = 4;
        constexpr int BUFB = NN * CC * 2;   // 16 KB
        const int cp = tid >> 3;            // channel pair 0..31
        const int ng = tid & 7;             // node group of 16

        float4 va[4], vb[4];
        auto load = [&](int ch) {
            const int c0 = ch * CC + 2 * cp, c1 = c0 + 1;
            const bool k0 = (c0 < F), k1 = (c1 < F);
            const float* s0 = trees + ((size_t)b * F + c0) * NN + ng * 16;
            const float* s1 = s0 + NN;
#pragma unroll
            for (int j = 0; j < 4; ++j) {
                va[j] = k0 ? *reinterpret_cast<const float4*>(s0 + j * 4) : make_float4(0.f, 0.f, 0.f, 0.f);
                vb[j] = k1 ? *reinterpret_cast<const float4*>(s1 + j * 4) : make_float4(0.f, 0.f, 0.f, 0.f);
            }
        };
        const int gsw = cp >> 2;
        const int cby = (cp & 3) * 4;
        auto stor = [&](char* wb) {
            const float* fa = reinterpret_cast<const float*>(va);
            const float* fb = reinterpret_cast<const float*>(vb);
#pragma unroll
            for (int i = 0; i < 16; ++i) {
                const int n = ng * 16 + i;
                unsigned int pk;
                asm("v_cvt_pk_bf16_f32 %0, %1, %2" : "=v"(pk) : "v"(fa[i]), "v"(fb[i]));
                int byte = n * 128 + (((gsw ^ (n & 7) ^ ng) << 4) + cby);
                *reinterpret_cast<unsigned int*>(wb + byte) = pk;
            }
        };

        f32x16 acc[NB];
#pragma unroll
        for (int ob = 0; ob < NB; ++ob) acc[ob] = (f32x16)0.f;

        const int nrow = wv * 32 + l31;
        const unsigned abyte = (unsigned)(nrow * 128);
        const unsigned axor = (unsigned)(((nrow & 7) ^ ((nrow >> 4) & 7)) << 4);

        load(0); stor(W);
        __syncthreads();

        int p = 0;
#pragma unroll
        for (int ch = 0; ch < NCH; ++ch) {
            if (ch + 1 < NCH) load(ch + 1);
            const char* base = W + p * BUFB;
            __builtin_amdgcn_s_setprio(1);
#pragma unroll
            for (int ks = 0; ks < KS; ++ks) {
                const int kbg = ch * KS + ks;
                short8 a = *reinterpret_cast<const short8*>(
                    base + abyte + (((unsigned)((ks * 2 + lh2) << 4)) ^ axor));
                const unsigned short* wb_ = wpe + ((size_t)(kbg * 4) * 64 + lane) * 8;
#pragma unroll
                for (int ob = 0; ob < NB; ++ob) {
                    short8 bf_ = *reinterpret_cast<const short8*>(wb_ + ob * 512);
                    acc[ob] = __builtin_amdgcn_mfma_f32_32x32x16_bf16(a, bf_, acc[ob], 0, 0, 0);
                }
            }
            __builtin_amdgcn_s_setprio(0);
            if (ch + 1 < NCH) stor(W + (p ^ 1) * BUFB);
            __syncthreads();
            p ^= 1;
        }

        // epilogue -> Xt, PERMUTED pair writes (b32, conflict-free)
        float bs[NB];
#pragma unroll
        for (int ob = 0; ob < NB; ++ob) {
            int c = ob * 32 + l31;
            bs[ob] = (c < 109) ? encb[c] : 0.f;
        }
#pragma unroll
        for (int r = 0; r < 16; ++r) {
            const int row = wv * 32 + (r & 3) + 8 * (r >> 2) + 4 * lh2;
            unsigned int pk0, pk1;
            float a0 = acc[0][r] + bs[0], a1 = acc[1][r] + bs[1];
            float a2 = acc[2][r] + bs[2], a3 = acc[3][r] + bs[3];
            asm("v_cvt_pk_bf16_f32 %0, %1, %2" : "=v"(pk0) : "v"(a0), "v"(a1));
            asm("v_cvt_pk_bf16_f32 %0, %1, %2" : "=v"(pk1) : "v"(a2), "v"(a3));
            int by0 = row * 256 + ((((l31 >> 2) ^ (row & 15)) << 4) | ((l31 & 3) * 4));
            int by1 = row * 256 + ((((8 + (l31 >> 2)) ^ (row & 15)) << 4) | ((l31 & 3) * 4));
            *reinterpret_cast<unsigned int*>(Xt + by0) = pk0;
            *reinterpret_cast<unsigned int*>(Xt + by1) = pk1;
        }
        __syncthreads();
    }

    // ---------------- phase 2: conv1 ----------------
    const int nrowA = wv * 32 + l31;
    unsigned aab[3], axm[3];
#pragma unroll
    for (int k = 0; k < 3; ++k) {
        int s_ = idx[b * 3 * NN + 3 * nrowA + k];
        aab[k] = (unsigned)(s_ * 256);
        axm[k] = (unsigned)(s_ & 15);
    }

    // hoist ALL 24 gathered A-frags into registers (read each once)
    short8 areg[24];
#pragma unroll
    for (int h = 0; h < 2; ++h)
#pragma unroll
        for (int ks2 = 0; ks2 < 4; ++ks2)
#pragma unroll
            for (int k = 0; k < 3; ++k) {
                const unsigned slot = ((unsigned)((h * 4 + ks2) * 2 + lh2)) ^ axm[k];
                areg[(h * 4 + ks2) * 3 + k] =
                    *reinterpret_cast<const short8*>(Xt + aab[k] + (slot << 4));
            }

    char* bufs[2] = {W, W + 24576};
    auto issueBh = [&](int ht) {
        const unsigned short* src = wp1 + (size_t)ht * 24 * 512;
        char* dst = bufs[ht & 1];
#pragma unroll
        for (int i = 0; i < 6; ++i)
            __builtin_amdgcn_global_load_lds(
                (const AS1 void*)(src + (i * 256 + tid) * 8),
                (AS3 void*)(dst + (i * 256 + wv * 64) * 16),
                16, 0, 0);
    };

    unsigned int* y1w = reinterpret_cast<unsigned int*>(y1);
    float tsum = 0.f, tss = 0.f;

    issueBh(0);
    issueBh(1);
    asm volatile("s_waitcnt vmcnt(6)" ::: "memory");   // chunk0 ready, chunk1 in flight
    __builtin_amdgcn_s_barrier();
    __builtin_amdgcn_sched_barrier(0);

    f32x16 acc[2];
#pragma unroll
    for (int ht = 0; ht < 16; ++ht) {
        const int h = ht & 1, oy = ht >> 1;
        const char* bp = bufs[h];
        if (h == 0) {
#pragma unroll
            for (int obp = 0; obp < 2; ++obp) {
                const float bv = b1[oy * 64 + obp * 32 + l31];
#pragma unroll
                for (int r = 0; r < 16; ++r) acc[obp][r] = bv;
            }
        }
        __builtin_amdgcn_s_setprio(1);
#pragma unroll
        for (int ks2 = 0; ks2 < 4; ++ks2) {
#pragma unroll
            for (int k = 0; k < 3; ++k) {
                short8 a = areg[(h * 4 + ks2) * 3 + k];
#pragma unroll
                for (int obp = 0; obp < 2; ++obp) {
                    short8 bf_ = *reinterpret_cast<const short8*>(
                        bp + (((k * 4 + ks2) * 2 + obp) << 10) + lane * 16);
                    acc[obp] = __builtin_amdgcn_mfma_f32_32x32x16_bf16(a, bf_, acc[obp], 0, 0, 0);
                }
            }
        }
        __builtin_amdgcn_s_setprio(0);

        // all waves done reading buf[h] -> safe to refill; stores go AFTER the new loads
        if (ht + 1 < 16) __builtin_amdgcn_s_barrier();
        if (ht + 2 < 16) issueBh(ht + 2);

        if (h == 1) {
            // stats + permuted dword stores (behind the awaited loads in the vmcnt FIFO)
#pragma unroll
            for (int r = 0; r < 16; ++r) {
                float v0_ = acc[0][r], v1_ = acc[1][r];
                tsum += v0_ + v1_;
                tss  += v0_ * v0_ + v1_ * v1_;
                unsigned int pk;
                asm("v_cvt_pk_bf16_f32 %0, %1, %2" : "=v"(pk) : "v"(v0_), "v"(v1_));
                int row = wv * 32 + (r & 3) + 8 * (r >> 2) + 4 * lh2;
                y1w[((size_t)b * NN + row) * 256 + oy * 32 + l31] = pk;
            }
        }

        // wait for next chunk (ht+1) to have landed; leave ht+2 loads + stores in flight
        if (ht == 0)       { asm volatile("s_waitcnt vmcnt(6)"  ::: "memory"); }
        else if (ht < 14)  { asm volatile("s_waitcnt vmcnt(22)" ::: "memory"); }
        else if (ht == 14) { asm volatile("s_waitcnt vmcnt(0)"  ::: "memory"); }
        __builtin_amdgcn_sched_barrier(0);
    }

    __syncthreads();
    float* rbuf = reinterpret_cast<float*>(W);
#pragma unroll
    for (int ss = 32; ss; ss >>= 1) { tsum += __shfl_down(tsum, ss); tss += __shfl_down(tss, ss); }
    if (lane == 0) { rbuf[wv * 2] = tsum; rbuf[wv * 2 + 1] = tss; }
    __syncthreads();
    if (tid == 0) {
        float sm = rbuf[0] + rbuf[2] + rbuf[4] + rbuf[6];
        float q = rbuf[1] + rbuf[3] + rbuf[5] + rbuf[7];
        partials[2 * b] = sm;
        partials[2 * b + 1] = q;
    }
}

// ---------- conv2/conv3: output-stationary, A-side LDS gather, OT=128, CC=32 ----------
template <int CIN, int OTN, int COUT, bool COLMAX>
__global__ __launch_bounds__(256, 2) void conv_gemm(const unsigned short* __restrict__ xin,
                                                    const int* __restrict__ idx,
                                                    const unsigned short* __restrict__ wp,
                                                    const float* __restrict__ bias,
                                                    const float* __restrict__ stats,
                                                    unsigned short* __restrict__ yout,
                                                    float* __restrict__ colmax,
                                                    float* __restrict__ partials)
{
    constexpr int CC    = 32;
    constexpr int NCC   = CIN / CC;
    constexpr int AIT   = 2;
    constexpr int ABUF  = NN * 128;
    constexpr int BFR   = 2 * 3 * 4;
    constexpr int BBUF  = BFR * 1024;
    constexpr int BIT   = 6;
    constexpr int BUFB  = ABUF + BBUF;

    __shared__ __align__(16) char gbuf[81920];
    float (*cmax)[2][32] = reinterpret_cast<float (*)[2][32]>(gbuf + 79872);
    float* rbuf = reinterpret_cast<float*>(gbuf + 81408);

    const int f  = blockIdx.x;
    const int s  = f >> 3;
    const int b  = (f & 7) + 8 * (s / OTN);
    const int oy = s % OTN;

    const int tid = threadIdx.x;
    const int lane = tid & 63;
    const int wv = tid >> 6;
    const int wm = wv >> 1, wn = wv & 1;
    const int l31 = lane & 31, lh2 = lane >> 5;

    const float mu = stats[0], inv = stats[1];
    const float nmi = -mu * inv;

    const unsigned short* xb = xin + (size_t)b * NN * CIN;

    unsigned aab[2][3], axm[2][3];
#pragma unroll
    for (int nf = 0; nf < 2; ++nf) {
        const int n = wm * 64 + nf * 32 + l31;
#pragma unroll
        for (int k = 0; k < 3; ++k) {
            int s_ = idx[b * 3 * NN + 3 * n + k];
            aab[nf][k] = (unsigned)(s_ * 128);
            axm[nf][k] = (unsigned)(s_ & 7);
        }
    }

    f32x16 acc[2][2];
#pragma unroll
    for (int nf = 0; nf < 2; ++nf)
#pragma unroll
        for (int nc = 0; nc < 2; ++nc) {
            const float bv = bias[oy * 128 + wn * 64 + nc * 32 + l31];
#pragma unroll
            for (int r = 0; r < 16; ++r) acc[nf][nc][r] = bv;
        }

    auto issueB = [&](int ci, char* dst) {
        const unsigned short* src = wp + ((size_t)(oy * NCC + ci)) * (BFR * 512);
#pragma unroll
        for (int i = 0; i < BIT; ++i)
            __builtin_amdgcn_global_load_lds(
                (const AS1 void*)(src + (i * 256 + tid) * 8),
                (AS3 void*)(dst + (i * 256 + wv * 64) * 16),
                16, 0, 0);
    };
    unsigned ngoff[AIT], lby[AIT];
#pragma unroll
    for (int i = 0; i < AIT; ++i) {
        int it = i * 256 + tid;
        int n = it >> 2, g = it & 3;
        ngoff[i] = (unsigned)(n * CIN + g * 8);
        lby[i]   = (unsigned)(n * 128 + ((g ^ (n & 7)) << 4));
    }
    auto loadA = [&](int cc, uint4* vv) {
#pragma unroll
        for (int i = 0; i < AIT; ++i)
            vv[i] = *reinterpret_cast<const uint4*>(xb + cc * CC + ngoff[i]);
    };
    const f32x2 iv2 = {inv, inv}, nm2 = {nmi, nmi};
    auto storA = [&](char* wb, const uint4* vv) {
#pragma unroll
        for (int i = 0; i < AIT; ++i) {
            uint4 t = vv[i];
            unsigned int* pw = reinterpret_cast<unsigned int*>(&t);
#pragma unroll
            for (int q = 0; q < 4; ++q) {
                unsigned int u = pw[q];
                f32x2 sv, d;
                sv[0] = __uint_as_float(u << 16);
                sv[1] = __uint_as_float(u & 0xffff0000u);
                asm("v_pk_fma_f32 %0, %1, %2, %3" : "=v"(d) : "v"(sv), "v"(iv2), "v"(nm2));
                float f0 = fmaxf(d[0], 0.f);
                float f1 = fmaxf(d[1], 0.f);
                unsigned int r;
                asm("v_cvt_pk_bf16_f32 %0, %1, %2" : "=v"(r) : "v"(f0), "v"(f1));
                pw[q] = r;
            }
            *reinterpret_cast<uint4*>(wb + lby[i]) = t;
        }
    };

    uint4 v0[AIT], v1[AIT];

    issueB(0, gbuf + ABUF);
    loadA(0, v0);
    loadA(1, v1);
    storA(gbuf, v0);
    asm volatile("s_waitcnt lgkmcnt(0)" ::: "memory");
    __builtin_amdgcn_s_barrier();
    __builtin_amdgcn_sched_barrier(0);

#pragma unroll
    for (int cc = 0; cc < NCC; ++cc) {
        const int p = cc & 1;
        if (cc + 1 < NCC) {
            issueB(cc + 1, gbuf + (p ^ 1) * BUFB + ABUF);
            if (cc + 2 < NCC) loadA(cc + 2, (cc & 1) ? v1 : v0);
        }
        const char* ab = gbuf + p * BUFB;
        const char* bb = ab + ABUF;
        __builtin_amdgcn_s_setprio(1);
#pragma unroll
        for (int ks = 0; ks < 2; ++ks) {
            const unsigned s0 = (unsigned)(ks * 2 + lh2);
#pragma unroll
            for (int k = 0; k < 3; ++k) {
                short8 a0 = *reinterpret_cast<const short8*>(ab + aab[0][k] + ((s0 ^ axm[0][k]) << 4));
                short8 a1 = *reinterpret_cast<const short8*>(ab + aab[1][k] + ((s0 ^ axm[1][k]) << 4));
#pragma unroll
                for (int nc = 0; nc < 2; ++nc) {
                    short8 bf_ = *reinterpret_cast<const short8*>(
                        bb + (((k * 2 + ks) * 4 + wn * 2 + nc) << 10) + lane * 16);
                    acc[0][nc] = __builtin_amdgcn_mfma_f32_32x32x16_bf16(a0, bf_, acc[0][nc], 0, 0, 0);
                    acc[1][nc] = __builtin_amdgcn_mfma_f32_32x32x16_bf16(a1, bf_, acc[1][nc], 0, 0, 0);
                }
            }
        }
        __builtin_amdgcn_s_setprio(0);
        if (cc + 1 < NCC) storA(gbuf + (p ^ 1) * BUFB, (cc & 1) ? v0 : v1);

        if (cc + 1 < NCC) {
            if (cc + 2 < NCC) {
                asm volatile("s_waitcnt vmcnt(2) lgkmcnt(0)" ::: "memory");
            } else {
                asm volatile("s_waitcnt vmcnt(0) lgkmcnt(0)" ::: "memory");
            }
            __builtin_amdgcn_s_barrier();
            __builtin_amdgcn_sched_barrier(0);
        } else {
            asm volatile("s_waitcnt lgkmcnt(0)" ::: "memory");
            __builtin_amdgcn_s_barrier();
            __builtin_amdgcn_sched_barrier(0);
        }
    }

    float tsum = 0.f, tss = 0.f;

    if (COLMAX) {
        float m[2] = {-1e30f, -1e30f};
#pragma unroll
        for (int nf = 0; nf < 2; ++nf)
#pragma unroll
            for (int nc = 0; nc < 2; ++nc)
#pragma unroll
                for (int r = 0; r < 16; ++r) {
                    float val = acc[nf][nc][r];
                    tsum += val; tss += val * val;
                    m[nc] = fmaxf(m[nc], val);
                }
#pragma unroll
        for (int nc = 0; nc < 2; ++nc) m[nc] = fmaxf(m[nc], __shfl_xor(m[nc], 32));
        if (lh2 == 0) {
#pragma unroll
            for (int nc = 0; nc < 2; ++nc) cmax[wv][nc][l31] = m[nc];
        }
        __syncthreads();
        if (tid < 128) {
            const int c = tid;
            const int wn_ = (c >> 6) & 1, nc_ = (c >> 5) & 1, l_ = c & 31;
            float mm = fmaxf(cmax[wn_][nc_][l_], cmax[2 + wn_][nc_][l_]);
            colmax[b * COUT + c] = mm;
        }
    } else {
        unsigned int* yw = reinterpret_cast<unsigned int*>(yout);
#pragma unroll
        for (int nf = 0; nf < 2; ++nf)
#pragma unroll
            for (int r = 0; r < 16; ++r) {
                float v0_ = acc[nf][0][r], v1_ = acc[nf][1][r];
                tsum += v0_ + v1_;
                tss  += v0_ * v0_ + v1_ * v1_;
                unsigned int pk;
                asm("v_cvt_pk_bf16_f32 %0, %1, %2" : "=v"(pk) : "v"(v0_), "v"(v1_));
                int row = wm * 64 + nf * 32 + (r & 3) + 8 * (r >> 2) + 4 * lh2;
                yw[((size_t)b * NN + row) * (COUT / 2) + oy * 64 + wn * 32 + l31] = pk;
            }
    }

#pragma unroll
    for (int ss = 32; ss; ss >>= 1) { tsum += __shfl_down(tsum, ss); tss += __shfl_down(tss, ss); }
    __syncthreads();
    if (lane == 0) { rbuf[wv * 2] = tsum; rbuf[wv * 2 + 1] = tss; }
    __syncthreads();
    if (tid == 0) {
        float sm = rbuf[0] + rbuf[2] + rbuf[4] + rbuf[6];
        float q = rbuf[1] + rbuf[3] + rbuf[5] + rbuf[7];
        int gid = oy * B + b;
        partials[2 * gid] = sm;
        partials[2 * gid + 1] = q;
    }
}

// ---------- finalize global layernorm stats ----------
__global__ __launch_bounds__(256) void stats_kernel(const float* __restrict__ partials,
                                                    float* __restrict__ stats,
                                                    int npart, double ntot)
{
    __shared__ double sd[256], sd2[256];
    double s = 0.0, s2 = 0.0;
    for (int i = threadIdx.x; i < npart; i += 256) { s += (double)partials[2 * i]; s2 += (double)partials[2 * i + 1]; }
    sd[threadIdx.x] = s; sd2[threadIdx.x] = s2;
    __syncthreads();
    for (int k = 128; k > 0; k >>= 1) {
        if (threadIdx.x < k) { sd[threadIdx.x] += sd[threadIdx.x + k]; sd2[threadIdx.x] += sd2[threadIdx.x + k]; }
        __syncthreads();
    }
    if (threadIdx.x == 0) {
        double mu = sd[0] / ntot;
        double var = (sd2[0] - sd[0] * sd[0] / ntot) / (ntot - 1.0);
        double sdv = sqrt(var > 0.0 ? var : 0.0);
        stats[0] = (float)mu;
        stats[1] = (float)(1.0 / (sdv + 1e-5));
    }
}

// ---------- pool + heads WITH fused conv3-stats (per-block redundant reduce) ----------
__global__ __launch_bounds__(256) void pool_head_kernel(const float* __restrict__ partials, // conv3 partials [1024][2]
                                                        const float* __restrict__ colmax,   // [B][128]
                                                        const float* __restrict__ latw,
                                                        const float* __restrict__ latb,
                                                        const float* __restrict__ costw,
                                                        const float* __restrict__ costb,
                                                        float* __restrict__ out)
{
    __shared__ double sd[256], sd2[256];
    __shared__ float pl[128];
    __shared__ float st[2];
    const int b = blockIdx.x, t = threadIdx.x;

    double s = 0.0, s2 = 0.0;
#pragma unroll
    for (int i = 0; i < 4; ++i) {
        int p = t + i * 256;
        s  += (double)partials[2 * p];
        s2 += (double)partials[2 * p + 1];
    }
    sd[t] = s; sd2[t] = s2;
    __syncthreads();
    for (int k = 128; k > 0; k >>= 1) {
        if (t < k) { sd[t] += sd[t + k]; sd2[t] += sd2[t + k]; }
        __syncthreads();
    }
    if (t == 0) {
        const double ntot = 16777216.0;   // B*128*NN
        double mu = sd[0] / ntot;
        double var = (sd2[0] - sd[0] * sd[0] / ntot) / (ntot - 1.0);
        double sdv = sqrt(var > 0.0 ? var : 0.0);
        st[0] = (float)mu;
        st[1] = (float)(1.0 / (sdv + 1e-5));
    }
    __syncthreads();
    const float mu = st[0], inv = st[1];

    if (t < 128) pl[t] = fmaxf((colmax[b * 128 + t] - mu) * inv, 0.f);
    __syncthreads();
    if (t < 128) {
        const float* w = (t < 64) ? latw : costw;
        const int l = t & 63;
        float v = pl[l] * w[l] + pl[l + 64] * w[l + 64];
#pragma unroll
        for (int s_ = 32; s_ > 0; s_ >>= 1) v += __shfl_down(v, s_);
        if (l == 0) {
            const float bb = (t < 64) ? latb[0] : costb[0];
            out[(t < 64 ? 0 : B) + b] = 1.f / (1.f + expf(-(v + bb)));
        }
    }
}

// ---------- launch ----------
extern "C" void kernel_launch(void* const* d_in, const int* in_sizes, int n_in,
                              void* d_out, int out_size, void* d_ws, size_t ws_size,
                              hipStream_t stream)
{
    (void)in_sizes; (void)n_in; (void)out_size; (void)ws_size;
    const float* trees   = (const float*)d_in[0];
    const int*   indexes = (const int*)  d_in[1];
    const float* enc_w   = (const float*)d_in[2];
    const float* enc_b   = (const float*)d_in[3];
    const float* w1 = (const float*)d_in[4];
    const float* b1 = (const float*)d_in[5];
    const float* w2 = (const float*)d_in[6];
    const float* b2 = (const float*)d_in[7];
    const float* w3 = (const float*)d_in[8];
    const float* b3 = (const float*)d_in[9];
    const float* lat_w  = (const float*)d_in[10];
    const float* lat_b  = (const float*)d_in[11];
    const float* cost_w = (const float*)d_in[12];
    const float* cost_b = (const float*)d_in[13];
    float* out = (float*)d_out;

    char* ws = (char*)d_ws;
    size_t off = 0;
    auto alloc = [&](size_t bytes) -> char* {
        char* p = ws + off;
        off += (bytes + 255) & ~(size_t)255;
        return p;
    };
    unsigned short* wpe  = (unsigned short*)alloc((size_t)40960 * 2);
    unsigned short* wp1f = (unsigned short*)alloc((size_t)196608 * 2);
    unsigned short* wp2  = (unsigned short*)alloc((size_t)393216 * 2);
    unsigned short* wp3  = (unsigned short*)alloc((size_t)98304 * 2);
    unsigned short* y1   = (unsigned short*)alloc((size_t)B * NN * 512 * 2);
    unsigned short* y2   = (unsigned short*)alloc((size_t)B * NN * 256 * 2);
    float* colmax   = (float*)alloc((size_t)B * 128 * 4);
    float* partials = (float*)alloc((size_t)8192 * 2 * 4);
    float* stats    = (float*)alloc(8 * 4);

    float* part1 = partials;              // enc_conv1: 1024 pairs
    float* part2 = partials + 2048 * 2;   // conv2: 2048 pairs
    float* part3 = partials + 6144 * 2;   // conv3: 1024 pairs

    prepack_all<<<dim3(2848), dim3(256), 0, stream>>>(enc_w, w1, w2, w3, wpe, wp1f, wp2, wp3);

    // FUSED encoder + conv1 (permuted y1; x0 never leaves LDS; A hoisted to registers)
    enc_conv1<<<dim3(B), dim3(256), 0, stream>>>(trees, indexes, wpe, enc_b, wp1f, b1, y1, part1);
    stats_kernel<<<dim3(1), dim3(256), 0, stream>>>(part1, stats + 0, 1024, (double)((size_t)B * 512 * NN));

    // conv2: output-stationary, OT=128, 2 o-tiles; permuted in/out
    conv_gemm<512, 2, 256, false>
        <<<dim3(B * 2), dim3(256), 0, stream>>>(y1, indexes, wp2, b2, stats + 0, y2, colmax, part2);
    stats_kernel<<<dim3(1), dim3(256), 0, stream>>>(part2, stats + 2, 2048, (double)((size_t)B * 256 * NN));

    // conv3: output-stationary, OT=128, colmax fused; permuted in
    conv_gemm<256, 1, 128, true>
        <<<dim3(B), dim3(256), 0, stream>>>(y2, indexes, wp3, b3, stats + 2, nullptr, colmax, part3);

    // pool + heads with fused conv3 stats
    pool_head_kernel<<<dim3(B), dim3(256), 0, stream>>>(part3, colmax, lat_w, lat_b, cost_w, cost_b, out);
}